// Round 1
// 3348.447 us; speedup vs baseline: 1.0072x; 1.0072x over previous
//
#include <hip/hip_runtime.h>
#include <hip/hip_bf16.h>
#include <cstddef>

// DeepSeekBlock: B=2 T=1024 D=2048 H=16 NOPE=128 ROPE=64 QKD=192
// QLORA=1536 KVLORA=512 VHD=128 INTER=8192
// Round 6: score-path GEMMs (wq_a/wq_b/wkv_a/wkv_b) moved from f32 VALU tiles to
// split-bf16 MFMA (A=Ah+Al, W=Wh+Wl; C ~= AhWh + AhWl + AlWh, f32 accum).
// Dropped Al*Wl term is ~2^-18 relative -> logit jitter ~0.002 with SOFTSCALE=-96,
// negligible. RMSNorm kernels emit hi/lo bf16 pairs directly; W converted in staging.
// attn_k unchanged except heavy-first s-tile order (causal tail reduction).
// ws peak 14M floats + 256 B = 56.0 MiB (same as round 5).

#define TT 1024
#define DD 2048
#define QT 8

using bf16 = __hip_bfloat16;
typedef __attribute__((ext_vector_type(8))) short short8;
typedef __attribute__((ext_vector_type(8))) unsigned short ushort8v;
typedef __attribute__((ext_vector_type(4))) float f32x4;

__device__ __forceinline__ float us2f(unsigned short u) {
    return __uint_as_float(((unsigned int)u) << 16);
}
__device__ __forceinline__ float ldf(const void* p, size_t i, int isbf) {
    return isbf ? us2f(((const unsigned short*)p)[i]) : ((const float*)p)[i];
}
__device__ __forceinline__ unsigned short f2bf(float f) {
    __hip_bfloat16 b = __float2bfloat16(f);
    return *reinterpret_cast<unsigned short*>(&b);
}

// ---------------- input dtype detection ----------------
__global__ __launch_bounds__(64) void detect_k(const void* __restrict__ x,
                                               int* __restrict__ flag)
{
    __shared__ int cnt;
    if (threadIdx.x == 0) cnt = 0;
    __syncthreads();
    const unsigned short* u = (const unsigned short*)x;
    int bad = 0;
    for (int i = threadIdx.x; i < 512; i += 64) {
        const float v = us2f(u[i]);
        const float a = fabsf(v);
        if (!(a < 1e6f) || (v != 0.0f && a < 1e-30f)) bad++;
    }
    atomicAdd(&cnt, bad);
    __syncthreads();
    if (threadIdx.x == 0) *flag = (cnt > 32) ? 0 : 1;   // 0 = f32, 1 = bf16
}

// ---------------- rmsnorm f32 -> hi/lo bf16 pair ----------------
// out_hi/out_lo row stride = L; input row stride = istride.
__global__ __launch_bounds__(256) void rmsnorm_hl_k(
    const float* __restrict__ in, const void* __restrict__ w,
    unsigned short* __restrict__ oh, unsigned short* __restrict__ ol,
    int L, int istride, const int* __restrict__ flag)
{
    const int isbf = *flag;
    const int m = blockIdx.x, tid = threadIdx.x;
    const float* row = in + (size_t)m * istride;
    float ss = 0.f;
    for (int i = tid; i < L; i += 256) { float v = row[i]; ss += v * v; }
    __shared__ float red[256];
    red[tid] = ss; __syncthreads();
    for (int s = 128; s > 0; s >>= 1) {
        if (tid < s) red[tid] += red[tid + s];
        __syncthreads();
    }
    const float scale = 1.0f / sqrtf(red[0] / (float)L + 1e-6f);
    unsigned short* hrow = oh + (size_t)m * L;
    unsigned short* lrow = ol + (size_t)m * L;
    for (int i = tid; i < L; i += 256) {
        const float v = row[i] * scale * ldf(w, i, isbf);
        const unsigned short hi = f2bf(v);
        hrow[i] = hi;
        lrow[i] = f2bf(v - us2f(hi));
    }
}

// ---------------- rmsnorm f32->bf16 (FFN input; feeds bf16 MFMA GEMMs) ----------------
__global__ __launch_bounds__(256) void rmsnorm_bf_k(
    const float* __restrict__ in, const void* __restrict__ w,
    unsigned short* __restrict__ out, int L,
    const int* __restrict__ flag)
{
    const int isbf = *flag;
    const int m = blockIdx.x, tid = threadIdx.x;
    const float* row = in + (size_t)m * L;
    float ss = 0.f;
    for (int i = tid; i < L; i += 256) { float v = row[i]; ss += v * v; }
    __shared__ float red[256];
    red[tid] = ss; __syncthreads();
    for (int s = 128; s > 0; s >>= 1) {
        if (tid < s) red[tid] += red[tid + s];
        __syncthreads();
    }
    const float scale = 1.0f / sqrtf(red[0] / (float)L + 1e-6f);
    unsigned short* orow = out + (size_t)m * L;
    for (int i = tid; i < L; i += 256)
        orow[i] = f2bf(row[i] * scale * ldf(w, i, isbf));
}

// rmsnorm on input x: writes hi/lo bf16 h and f32 residual copy
__global__ __launch_bounds__(256) void rmsnorm_x_hl_k(
    const void* __restrict__ x, size_t eoff, const void* __restrict__ w,
    unsigned short* __restrict__ hh, unsigned short* __restrict__ hl,
    float* __restrict__ xf, const int* __restrict__ flag)
{
    const int isbf = *flag;
    const int m = blockIdx.x, tid = threadIdx.x;
    const size_t base = eoff + (size_t)m * DD;
    float* xrow = xf + (size_t)m * DD;
    float ss = 0.f;
    float vals[8];
    for (int i = 0; i < 8; ++i) {
        float v = ldf(x, base + tid + 256 * i, isbf);
        vals[i] = v; ss += v * v;
        xrow[tid + 256 * i] = v;
    }
    __shared__ float red[256];
    red[tid] = ss; __syncthreads();
    for (int s = 128; s > 0; s >>= 1) {
        if (tid < s) red[tid] += red[tid + s];
        __syncthreads();
    }
    const float scale = 1.0f / sqrtf(red[0] / (float)DD + 1e-6f);
    unsigned short* hrow = hh + (size_t)m * DD;
    unsigned short* lrow = hl + (size_t)m * DD;
    for (int i = 0; i < 8; ++i) {
        const float v = vals[i] * scale * ldf(w, tid + 256 * i, isbf);
        const unsigned short hi = f2bf(v);
        hrow[tid + 256 * i] = hi;
        lrow[tid + 256 * i] = f2bf(v - us2f(hi));
    }
}

// ---------------- split-bf16 MFMA GEMM: C(M,N) f32 = (Ah+Al)(Wh+Wl)^T ----------------
// A hi/lo bf16 row-major (precomputed); W = input weights (f32 or bf16 per flag),
// converted to hi/lo in staging. 3 MFMAs per fragment pair: AhWh + AhWl + AlWh.
// 128x128 tile, BK=32, 256 thr = 4 waves (2x2), each wave 64x64 via 4x4 MFMAs.
// Column guard supports N not divisible by 128 (wkv_a: N=576).
__global__ __launch_bounds__(256) void gemm_mfma3_k(
    const unsigned short* __restrict__ Ah, const unsigned short* __restrict__ Al,
    const void* __restrict__ Wv, float* __restrict__ C,
    int N, int K, const int* __restrict__ flag)
{
    const int isbf = *flag;
    __shared__ unsigned short Ash[128 * 40];
    __shared__ unsigned short Asl[128 * 40];
    __shared__ unsigned short Wsh[128 * 40];
    __shared__ unsigned short Wsl[128 * 40];
    const int tid = threadIdx.x;
    const int lane = tid & 63;
    const int wave = tid >> 6;
    const int wm = (wave >> 1) << 6, wn = (wave & 1) << 6;
    const int bm = blockIdx.y << 7, bn = blockIdx.x << 7;
    const int srow = tid >> 1, scol = (tid & 1) << 4;
    const unsigned short* Ahld = Ah + (size_t)(bm + srow) * K + scol;
    const unsigned short* Alld = Al + (size_t)(bm + srow) * K + scol;
    const int wrow = bn + srow;
    const size_t wldbase = (size_t)((wrow < N) ? wrow : (N - 1)) * K + scol;
    unsigned short* Ahdst = &Ash[srow * 40 + scol];
    unsigned short* Aldst = &Asl[srow * 40 + scol];
    unsigned short* Whdst = &Wsh[srow * 40 + scol];
    unsigned short* Wldst = &Wsl[srow * 40 + scol];
    const int frow = lane & 15;
    const int fk = (lane >> 4) << 3;    // 0,8,16,24

    f32x4 acc[4][4] = {};

    for (int kt = 0; kt < K; kt += 32) {
        ushort8v a0h = *(const ushort8v*)(Ahld + kt);
        ushort8v a1h = *(const ushort8v*)(Ahld + kt + 8);
        ushort8v a0l = *(const ushort8v*)(Alld + kt);
        ushort8v a1l = *(const ushort8v*)(Alld + kt + 8);
        ushort8v w0h, w1h, w0l, w1l;
        if (isbf) {
            const unsigned short* Wp = (const unsigned short*)Wv + wldbase + kt;
            w0h = *(const ushort8v*)(Wp);
            w1h = *(const ushort8v*)(Wp + 8);
            w0l = w0h ^ w0h;   // zero: bf16 weights have no low part
            w1l = w0l;
        } else {
            const float* Wp = (const float*)Wv + wldbase + kt;
            unsigned short th[16], tl[16];
#pragma unroll
            for (int t4 = 0; t4 < 4; ++t4) {
                float4 f = *(const float4*)(Wp + 4 * t4);
                float fv[4] = {f.x, f.y, f.z, f.w};
#pragma unroll
                for (int u = 0; u < 4; ++u) {
                    const unsigned short hi = f2bf(fv[u]);
                    th[4 * t4 + u] = hi;
                    tl[4 * t4 + u] = f2bf(fv[u] - us2f(hi));
                }
            }
            w0h = *(ushort8v*)&th[0]; w1h = *(ushort8v*)&th[8];
            w0l = *(ushort8v*)&tl[0]; w1l = *(ushort8v*)&tl[8];
        }
        __syncthreads();
        *(ushort8v*)Ahdst = a0h;
        *(ushort8v*)(Ahdst + 8) = a1h;
        *(ushort8v*)Aldst = a0l;
        *(ushort8v*)(Aldst + 8) = a1l;
        *(ushort8v*)Whdst = w0h;
        *(ushort8v*)(Whdst + 8) = w1h;
        *(ushort8v*)Wldst = w0l;
        *(ushort8v*)(Wldst + 8) = w1l;
        __syncthreads();

        short8 afh[4], afl[4], bfh[4], bfl[4];
#pragma unroll
        for (int i = 0; i < 4; ++i) {
            afh[i] = *(const short8*)&Ash[(wm + i * 16 + frow) * 40 + fk];
            afl[i] = *(const short8*)&Asl[(wm + i * 16 + frow) * 40 + fk];
        }
#pragma unroll
        for (int j = 0; j < 4; ++j) {
            bfh[j] = *(const short8*)&Wsh[(wn + j * 16 + frow) * 40 + fk];
            bfl[j] = *(const short8*)&Wsl[(wn + j * 16 + frow) * 40 + fk];
        }
#pragma unroll
        for (int i = 0; i < 4; ++i)
#pragma unroll
            for (int j = 0; j < 4; ++j) {
                acc[i][j] = __builtin_amdgcn_mfma_f32_16x16x32_bf16(
                    afh[i], bfh[j], acc[i][j], 0, 0, 0);
                acc[i][j] = __builtin_amdgcn_mfma_f32_16x16x32_bf16(
                    afh[i], bfl[j], acc[i][j], 0, 0, 0);
                acc[i][j] = __builtin_amdgcn_mfma_f32_16x16x32_bf16(
                    afl[i], bfh[j], acc[i][j], 0, 0, 0);
            }
    }

    // C/D layout (verified m89/m91): col = lane&15, row = (lane>>4)*4 + reg
#pragma unroll
    for (int i = 0; i < 4; ++i) {
        const int r0 = bm + wm + i * 16 + ((lane >> 4) << 2);
#pragma unroll
        for (int j = 0; j < 4; ++j) {
            const int c = bn + wn + j * 16 + (lane & 15);
            if (c < N) {
#pragma unroll
                for (int g = 0; g < 4; ++g)
                    C[(size_t)(r0 + g) * N + c] = acc[i][j][g];
            }
        }
    }
}

// ---------------- bf16 MFMA GEMM: C(M,N) = A(M,K) @ W(N,K)^T ----------------
// A bf16 row-major; W = input weights (f32 or bf16 per flag), converted in staging.
// 128x128 tile, BK=32, 256 thr = 4 waves (2x2), each wave 64x64 via 4x4 MFMAs.
// EPI 0: f32 C = acc;  EPI 1: f32 C = R + acc (R may alias C);
// EPI 3: bf16 C = bf16(silu(R) * acc).
template <int EPI>
__global__ __launch_bounds__(256) void gemm_mfma_k(
    const unsigned short* __restrict__ A, const void* __restrict__ Wv,
    const float* __restrict__ R, void* __restrict__ outp,
    int N, int K, const int* __restrict__ flag)
{
    const int isbf = *flag;
    __shared__ unsigned short As[128 * 40];
    __shared__ unsigned short Ws[128 * 40];
    const int tid = threadIdx.x;
    const int lane = tid & 63;
    const int wave = tid >> 6;
    const int wm = (wave >> 1) << 6, wn = (wave & 1) << 6;
    const int bm = blockIdx.y << 7, bn = blockIdx.x << 7;
    const int srow = tid >> 1, scol = (tid & 1) << 4;
    const unsigned short* Ald = A + (size_t)(bm + srow) * K + scol;
    const size_t wldbase = (size_t)(bn + srow) * K + scol;
    unsigned short* Adst = &As[srow * 40 + scol];
    unsigned short* Wdst = &Ws[srow * 40 + scol];
    const int frow = lane & 15;
    const int fk = (lane >> 4) << 3;    // 0,8,16,24

    f32x4 acc[4][4] = {};

    for (int kt = 0; kt < K; kt += 32) {
        ushort8v a0 = *(const ushort8v*)(Ald + kt);
        ushort8v a1 = *(const ushort8v*)(Ald + kt + 8);
        ushort8v w0, w1;
        if (isbf) {
            const unsigned short* Wp = (const unsigned short*)Wv + wldbase + kt;
            w0 = *(const ushort8v*)(Wp);
            w1 = *(const ushort8v*)(Wp + 8);
        } else {
            const float* Wp = (const float*)Wv + wldbase + kt;
            float4 f0 = *(const float4*)(Wp);
            float4 f1 = *(const float4*)(Wp + 4);
            float4 f2 = *(const float4*)(Wp + 8);
            float4 f3 = *(const float4*)(Wp + 12);
            unsigned short wt[16];
            wt[0] = f2bf(f0.x); wt[1] = f2bf(f0.y); wt[2]  = f2bf(f0.z); wt[3]  = f2bf(f0.w);
            wt[4] = f2bf(f1.x); wt[5] = f2bf(f1.y); wt[6]  = f2bf(f1.z); wt[7]  = f2bf(f1.w);
            wt[8] = f2bf(f2.x); wt[9] = f2bf(f2.y); wt[10] = f2bf(f2.z); wt[11] = f2bf(f2.w);
            wt[12] = f2bf(f3.x); wt[13] = f2bf(f3.y); wt[14] = f2bf(f3.z); wt[15] = f2bf(f3.w);
            w0 = *(const ushort8v*)&wt[0];
            w1 = *(const ushort8v*)&wt[8];
        }
        __syncthreads();
        *(ushort8v*)Adst = a0;
        *(ushort8v*)(Adst + 8) = a1;
        *(ushort8v*)Wdst = w0;
        *(ushort8v*)(Wdst + 8) = w1;
        __syncthreads();

        short8 af[4], bfr[4];
#pragma unroll
        for (int i = 0; i < 4; ++i)
            af[i] = *(const short8*)&As[(wm + i * 16 + frow) * 40 + fk];
#pragma unroll
        for (int j = 0; j < 4; ++j)
            bfr[j] = *(const short8*)&Ws[(wn + j * 16 + frow) * 40 + fk];
#pragma unroll
        for (int i = 0; i < 4; ++i)
#pragma unroll
            for (int j = 0; j < 4; ++j)
                acc[i][j] = __builtin_amdgcn_mfma_f32_16x16x32_bf16(
                    af[i], bfr[j], acc[i][j], 0, 0, 0);
    }

    // C/D layout (verified m89/m91): col = lane&15, row = (lane>>4)*4 + reg
#pragma unroll
    for (int i = 0; i < 4; ++i) {
        const int r0 = bm + wm + i * 16 + ((lane >> 4) << 2);
#pragma unroll
        for (int j = 0; j < 4; ++j) {
            const int c = bn + wn + j * 16 + (lane & 15);
#pragma unroll
            for (int g = 0; g < 4; ++g) {
                const size_t idx = (size_t)(r0 + g) * N + c;
                const float v = acc[i][j][g];
                if (EPI == 0) {
                    ((float*)outp)[idx] = v;
                } else if (EPI == 1) {
                    ((float*)outp)[idx] = v + R[idx];
                } else {  // EPI == 3: silu(R) * acc -> bf16
                    const float gv = R[idx];
                    const float sg = 1.0f / (1.0f + __expf(-gv));
                    ((unsigned short*)outp)[idx] = f2bf(gv * sg * v);
                }
            }
        }
    }
}

// ---------------- RoPE (interleaved pairs), in-place on q and k_pe ----------------
__global__ __launch_bounds__(256) void rope_k(
    float* __restrict__ qb, float* __restrict__ kva,
    const void* __restrict__ fc, const void* __restrict__ fs,
    const int* __restrict__ flag)
{
    const int isbf = *flag;
    const int t = blockIdx.x;
    const int tid = threadIdx.x;
    __shared__ float c[32], s[32];
    if (tid < 32) {
        c[tid] = ldf(fc, t * 32 + tid, isbf);
        s[tid] = ldf(fs, t * 32 + tid, isbf);
    }
    __syncthreads();
    for (int p = tid; p < 512; p += 256) {
        const int h = p >> 5, i = p & 31;
        float* base = qb + (size_t)t * 3072 + h * 192 + 128 + 2 * i;
        const float x0 = base[0], x1 = base[1];
        base[0] = x0 * c[i] - x1 * s[i];
        base[1] = x0 * s[i] + x1 * c[i];
    }
    if (tid < 32) {
        float* base = kva + (size_t)t * 576 + 512 + 2 * tid;
        const float x0 = base[0], x1 = base[1];
        base[0] = x0 * c[tid] - x1 * s[tid];
        base[1] = x0 * s[tid] + x1 * c[tid];
    }
}

// ---------------- causal attention, Q-tile=8, one block per (s-tile, head) ----------------
// f32 score path; output written as bf16 (feeds the wo MFMA GEMM).
// s-tiles reversed: heavy (large-smax) blocks dispatch first to shrink the tail.
__global__ __launch_bounds__(256) void attn_k(
    const float* __restrict__ q, const float* __restrict__ kv,
    const float* __restrict__ kva, unsigned short* __restrict__ y)
{
    const int s0 = (gridDim.x - 1 - blockIdx.x) * QT, h = blockIdx.y;
    const int tid = threadIdx.x;
    __shared__ __align__(16) float qv[QT][192];
    __shared__ float p[QT][TT];
    __shared__ float red[QT][32];
    __shared__ float inv[QT];

    for (int i = tid; i < QT * 192; i += 256) {
        const int r = i / 192, cpos = i % 192;
        qv[r][cpos] = q[(size_t)(s0 + r) * 3072 + h * 192 + cpos];
    }
    __syncthreads();

    const int smax = s0 + QT - 1;
    // QK: each thread computes one t-column for all 8 q-rows
    for (int t = tid; t <= smax; t += 256) {
        const float4* k4 = (const float4*)(kv + (size_t)t * 4096 + h * 256);
        const float4* pe4 = (const float4*)(kva + (size_t)t * 576 + 512);
        float d[QT] = {};
        for (int kk = 0; kk < 32; ++kk) {
            const float4 kkv = k4[kk];
#pragma unroll
            for (int r = 0; r < QT; ++r) {
                const float4 qq = *(const float4*)&qv[r][kk * 4];
                d[r] += qq.x * kkv.x + qq.y * kkv.y + qq.z * kkv.z + qq.w * kkv.w;
            }
        }
        for (int kk = 0; kk < 16; ++kk) {
            const float4 kkv = pe4[kk];
#pragma unroll
            for (int r = 0; r < QT; ++r) {
                const float4 qq = *(const float4*)&qv[r][128 + kk * 4];
                d[r] += qq.x * kkv.x + qq.y * kkv.y + qq.z * kkv.z + qq.w * kkv.w;
            }
        }
#pragma unroll
        for (int r = 0; r < QT; ++r)
            p[r][t] = (t <= s0 + r) ? d[r] * -96.0f : -1e30f;   // SOFTSCALE
    }
    __syncthreads();

    // softmax: 32 threads per row
    {
        const int r = tid >> 5, l = tid & 31;
        float mx = -1e30f;
        for (int t = l; t <= s0 + r; t += 32) mx = fmaxf(mx, p[r][t]);
        red[r][l] = mx; __syncthreads();
        if (l == 0) {
            float m2 = -1e30f;
            for (int i = 0; i < 32; ++i) m2 = fmaxf(m2, red[r][i]);
            inv[r] = m2;          // stash row max temporarily
        }
        __syncthreads();
        const float m = inv[r];
        float sum = 0.f;
        for (int t = l; t <= smax; t += 32) {
            const float e = __expf(p[r][t] - m);
            p[r][t] = e; sum += e;
        }
        __syncthreads();          // all p writes done before sum finalize/PV
        red[r][l] = sum; __syncthreads();
        if (l == 0) {
            float s2 = 0.f;
            for (int i = 0; i < 32; ++i) s2 += red[r][i];
            inv[r] = 1.0f / s2;
        }
        __syncthreads();
    }

    // PV: thread = (dim d, row-half rh); 4 independent accumulators
    {
        const int d = tid & 127, rh = (tid >> 7) << 2;
        float a0 = 0.f, a1 = 0.f, a2 = 0.f, a3 = 0.f;
        const float* vb = kv + h * 256 + 128 + d;
#pragma unroll 4
        for (int t = 0; t <= smax; ++t) {
            const float v = vb[(size_t)t * 4096];
            a0 += p[rh + 0][t] * v;
            a1 += p[rh + 1][t] * v;
            a2 += p[rh + 2][t] * v;
            a3 += p[rh + 3][t] * v;
        }
        unsigned short* yo = y + (size_t)(s0 + rh) * 2048 + h * 128 + d;
        yo[0 * 2048] = f2bf(a0 * inv[rh + 0]);
        yo[1 * 2048] = f2bf(a1 * inv[rh + 1]);
        yo[2 * 2048] = f2bf(a2 * inv[rh + 2]);
        yo[3 * 2048] = f2bf(a3 * inv[rh + 3]);
    }
}

extern "C" void kernel_launch(void* const* d_in, const int* in_sizes, int n_in,
                              void* d_out, int out_size, void* d_ws, size_t ws_size,
                              hipStream_t stream) {
    (void)in_sizes; (void)n_in; (void)out_size; (void)ws_size;
    const void* x       = d_in[0];
    const void* fcos    = d_in[2];
    const void* fsin    = d_in[3];
    const void* attn_nw = d_in[4];
    const void* wq_a    = d_in[5];
    const void* q_nw    = d_in[6];
    const void* wq_b    = d_in[7];
    const void* wkv_a   = d_in[8];
    const void* kv_nw   = d_in[9];
    const void* wkv_b   = d_in[10];
    const void* wo      = d_in[11];
    const void* ffn_nw  = d_in[12];
    const void* w1      = d_in[13];
    const void* w2      = d_in[14];
    const void* w3      = d_in[15];

    int* flag = (int*)d_ws;
    float* a  = (float*)d_ws + 64;
    const size_t M1 = 1048576;
    // Per-batch arena (float units). Peak = 14M floats + 256 B = 56.0 MiB.
    // Attention phase:
    float* xf  = a;                                            // [0,2M)   f32 residual
    unsigned short* hh = (unsigned short*)(a + 2 * M1);        // [2M,3M)  h hi
    unsigned short* hl = (unsigned short*)(a + 3 * M1);        // [3M,4M)  h lo
    float* qa  = a + 4 * M1;                                   // [4M,5.5M) f32; dead after q-norm
    float* kva = a + 4 * M1;                                   // [4M,4.5625M) (qa dead)
    unsigned short* kvnh = (unsigned short*)(a + 4 * M1 + 589824);            // 1MB
    unsigned short* kvnl = (unsigned short*)(a + 4 * M1 + 589824 + 262144);   // 1MB
    unsigned short* qah = (unsigned short*)(a + 5 * M1 + 524288);  // [5.5M,6.25M)
    unsigned short* qal = (unsigned short*)(a + 6 * M1 + 262144);  // [6.25M,7M)
    unsigned short* yb  = (unsigned short*)(a + 5 * M1 + 524288);  // [5.5M,6.5M) (qah/qal dead)
    float* qb  = a + 7 * M1;                                   // [7M,10M)
    float* kvb = a + 10 * M1;                                  // [10M,14M)
    // FFN phase (attention buffers dead):
    unsigned short* hb  = (unsigned short*)(a + 2 * M1);       // [2M,2.5M) bf16 h2
    float* gb  = a + 4 * M1;                                   // [4M,12M)  f32 w1-out
    unsigned short* gb2 = (unsigned short*)(a + 12 * M1);      // [12M,13M) bf16 swiglu out
    float* x2  = xf;

    detect_k<<<1, 64, 0, stream>>>(x, flag);

    for (int b = 0; b < 2; ++b) {
        const size_t eoff = (size_t)b * TT * DD;
        float* outb = (float*)d_out + eoff;

        // --- attention path (split-bf16 MFMA score chain) ---
        rmsnorm_x_hl_k<<<TT, 256, 0, stream>>>(x, eoff, attn_nw, hh, hl, xf, flag);
        gemm_mfma3_k<<<dim3(12, 8), 256, 0, stream>>>(hh, hl, wq_a, qa, 1536, 2048, flag);
        rmsnorm_hl_k<<<TT, 256, 0, stream>>>(qa, q_nw, qah, qal, 1536, 1536, flag);
        gemm_mfma3_k<<<dim3(24, 8), 256, 0, stream>>>(qah, qal, wq_b, qb, 3072, 1536, flag);
        gemm_mfma3_k<<<dim3(5, 8), 256, 0, stream>>>(hh, hl, wkv_a, kva, 576, 2048, flag);
        rmsnorm_hl_k<<<TT, 256, 0, stream>>>(kva, kv_nw, kvnh, kvnl, 512, 576, flag);
        rope_k<<<TT, 256, 0, stream>>>(qb, kva, fcos, fsin, flag);
        gemm_mfma3_k<<<dim3(32, 8), 256, 0, stream>>>(kvnh, kvnl, wkv_b, kvb, 4096, 512, flag);
        attn_k<<<dim3(TT / QT, 16), 256, 0, stream>>>(qb, kvb, kva, yb);

        // --- MFMA bf16 GEMMs ---
        // x2 = xf + yb @ wo^T   (N=2048, K=2048)
        gemm_mfma_k<1><<<dim3(2048 / 128, TT / 128), 256, 0, stream>>>(
            yb, wo, xf, x2, 2048, 2048, flag);
        // hb = bf16(rmsnorm(x2))
        rmsnorm_bf_k<<<TT, 256, 0, stream>>>(x2, ffn_nw, hb, 2048, flag);
        // gb = hb @ w1^T   (N=8192, K=2048)
        gemm_mfma_k<0><<<dim3(8192 / 128, TT / 128), 256, 0, stream>>>(
            hb, w1, nullptr, gb, 8192, 2048, flag);
        // gb2 = bf16(silu(gb) * (hb @ w3^T))
        gemm_mfma_k<3><<<dim3(8192 / 128, TT / 128), 256, 0, stream>>>(
            hb, w3, gb, gb2, 8192, 2048, flag);
        // outb = x2 + gb2 @ w2^T   (N=2048, K=8192)
        gemm_mfma_k<1><<<dim3(2048 / 128, TT / 128), 256, 0, stream>>>(
            gb2, w2, x2, outb, 2048, 8192, flag);
    }
}

// Round 2
// 2397.386 us; speedup vs baseline: 1.4068x; 1.3967x over previous
//
#include <hip/hip_runtime.h>
#include <hip/hip_bf16.h>
#include <cstddef>

// DeepSeekBlock: B=2 T=1024 D=2048 H=16 NOPE=128 ROPE=64 QKD=192
// QLORA=1536 KVLORA=512 VHD=128 INTER=8192
// Round 7: attention rewritten as MFMA flash attention.
//  - K pre-split to bf16 hi/lo [h][t][192] + V transposed to bf16 [h][d][t] (kvprep_k).
//  - attn_mfma_k: block = (64-row q-tile, head), 4 waves x 16 rows, KVBLK=32 flash
//    loop. S = QhKh + QhKl + QlKh (split-bf16, f32 MFMA accum; ~2^-18 rel err ->
//    ~3e-3 logit err at SOFTSCALE=-96). Online softmax per row via 16-lane shfl_xor
//    butterflies (rows of the 16x16x32 C-layout live in one 16-lane group).
//    P -> bf16 -> per-wave LDS bounce (C-layout -> A-layout) -> PV MFMA.
//  - Q converted to hi/lo in-register per block (no q prep pass).
// Score-path GEMMs stay split-bf16 MFMA (round 6). ws peak 16M floats + 256 B (as r5).

#define TT 1024
#define DD 2048
#define QBLK 64
#define KVB 32

using bf16 = __hip_bfloat16;
typedef __attribute__((ext_vector_type(8))) short short8;
typedef __attribute__((ext_vector_type(8))) unsigned short ushort8v;
typedef __attribute__((ext_vector_type(4))) float f32x4;

__device__ __forceinline__ float us2f(unsigned short u) {
    return __uint_as_float(((unsigned int)u) << 16);
}
__device__ __forceinline__ float ldf(const void* p, size_t i, int isbf) {
    return isbf ? us2f(((const unsigned short*)p)[i]) : ((const float*)p)[i];
}
__device__ __forceinline__ unsigned short f2bf(float f) {
    __hip_bfloat16 b = __float2bfloat16(f);
    return *reinterpret_cast<unsigned short*>(&b);
}

// ---------------- input dtype detection ----------------
__global__ __launch_bounds__(64) void detect_k(const void* __restrict__ x,
                                               int* __restrict__ flag)
{
    __shared__ int cnt;
    if (threadIdx.x == 0) cnt = 0;
    __syncthreads();
    const unsigned short* u = (const unsigned short*)x;
    int bad = 0;
    for (int i = threadIdx.x; i < 512; i += 64) {
        const float v = us2f(u[i]);
        const float a = fabsf(v);
        if (!(a < 1e6f) || (v != 0.0f && a < 1e-30f)) bad++;
    }
    atomicAdd(&cnt, bad);
    __syncthreads();
    if (threadIdx.x == 0) *flag = (cnt > 32) ? 0 : 1;   // 0 = f32, 1 = bf16
}

// ---------------- rmsnorm f32 -> hi/lo bf16 pair ----------------
__global__ __launch_bounds__(256) void rmsnorm_hl_k(
    const float* __restrict__ in, const void* __restrict__ w,
    unsigned short* __restrict__ oh, unsigned short* __restrict__ ol,
    int L, int istride, const int* __restrict__ flag)
{
    const int isbf = *flag;
    const int m = blockIdx.x, tid = threadIdx.x;
    const float* row = in + (size_t)m * istride;
    float ss = 0.f;
    for (int i = tid; i < L; i += 256) { float v = row[i]; ss += v * v; }
    __shared__ float red[256];
    red[tid] = ss; __syncthreads();
    for (int s = 128; s > 0; s >>= 1) {
        if (tid < s) red[tid] += red[tid + s];
        __syncthreads();
    }
    const float scale = 1.0f / sqrtf(red[0] / (float)L + 1e-6f);
    unsigned short* hrow = oh + (size_t)m * L;
    unsigned short* lrow = ol + (size_t)m * L;
    for (int i = tid; i < L; i += 256) {
        const float v = row[i] * scale * ldf(w, i, isbf);
        const unsigned short hi = f2bf(v);
        hrow[i] = hi;
        lrow[i] = f2bf(v - us2f(hi));
    }
}

// ---------------- rmsnorm f32->bf16 (FFN input) ----------------
__global__ __launch_bounds__(256) void rmsnorm_bf_k(
    const float* __restrict__ in, const void* __restrict__ w,
    unsigned short* __restrict__ out, int L,
    const int* __restrict__ flag)
{
    const int isbf = *flag;
    const int m = blockIdx.x, tid = threadIdx.x;
    const float* row = in + (size_t)m * L;
    float ss = 0.f;
    for (int i = tid; i < L; i += 256) { float v = row[i]; ss += v * v; }
    __shared__ float red[256];
    red[tid] = ss; __syncthreads();
    for (int s = 128; s > 0; s >>= 1) {
        if (tid < s) red[tid] += red[tid + s];
        __syncthreads();
    }
    const float scale = 1.0f / sqrtf(red[0] / (float)L + 1e-6f);
    unsigned short* orow = out + (size_t)m * L;
    for (int i = tid; i < L; i += 256)
        orow[i] = f2bf(row[i] * scale * ldf(w, i, isbf));
}

// rmsnorm on input x: writes hi/lo bf16 h and f32 residual copy
__global__ __launch_bounds__(256) void rmsnorm_x_hl_k(
    const void* __restrict__ x, size_t eoff, const void* __restrict__ w,
    unsigned short* __restrict__ hh, unsigned short* __restrict__ hl,
    float* __restrict__ xf, const int* __restrict__ flag)
{
    const int isbf = *flag;
    const int m = blockIdx.x, tid = threadIdx.x;
    const size_t base = eoff + (size_t)m * DD;
    float* xrow = xf + (size_t)m * DD;
    float ss = 0.f;
    float vals[8];
    for (int i = 0; i < 8; ++i) {
        float v = ldf(x, base + tid + 256 * i, isbf);
        vals[i] = v; ss += v * v;
        xrow[tid + 256 * i] = v;
    }
    __shared__ float red[256];
    red[tid] = ss; __syncthreads();
    for (int s = 128; s > 0; s >>= 1) {
        if (tid < s) red[tid] += red[tid + s];
        __syncthreads();
    }
    const float scale = 1.0f / sqrtf(red[0] / (float)DD + 1e-6f);
    unsigned short* hrow = hh + (size_t)m * DD;
    unsigned short* lrow = hl + (size_t)m * DD;
    for (int i = 0; i < 8; ++i) {
        const float v = vals[i] * scale * ldf(w, tid + 256 * i, isbf);
        const unsigned short hi = f2bf(v);
        hrow[tid + 256 * i] = hi;
        lrow[tid + 256 * i] = f2bf(v - us2f(hi));
    }
}

// ---------------- split-bf16 MFMA GEMM: C(M,N) f32 = (Ah+Al)(Wh+Wl)^T ----------------
__global__ __launch_bounds__(256) void gemm_mfma3_k(
    const unsigned short* __restrict__ Ah, const unsigned short* __restrict__ Al,
    const void* __restrict__ Wv, float* __restrict__ C,
    int N, int K, const int* __restrict__ flag)
{
    const int isbf = *flag;
    __shared__ unsigned short Ash[128 * 40];
    __shared__ unsigned short Asl[128 * 40];
    __shared__ unsigned short Wsh[128 * 40];
    __shared__ unsigned short Wsl[128 * 40];
    const int tid = threadIdx.x;
    const int lane = tid & 63;
    const int wave = tid >> 6;
    const int wm = (wave >> 1) << 6, wn = (wave & 1) << 6;
    const int bm = blockIdx.y << 7, bn = blockIdx.x << 7;
    const int srow = tid >> 1, scol = (tid & 1) << 4;
    const unsigned short* Ahld = Ah + (size_t)(bm + srow) * K + scol;
    const unsigned short* Alld = Al + (size_t)(bm + srow) * K + scol;
    const int wrow = bn + srow;
    const size_t wldbase = (size_t)((wrow < N) ? wrow : (N - 1)) * K + scol;
    unsigned short* Ahdst = &Ash[srow * 40 + scol];
    unsigned short* Aldst = &Asl[srow * 40 + scol];
    unsigned short* Whdst = &Wsh[srow * 40 + scol];
    unsigned short* Wldst = &Wsl[srow * 40 + scol];
    const int frow = lane & 15;
    const int fk = (lane >> 4) << 3;

    f32x4 acc[4][4] = {};

    for (int kt = 0; kt < K; kt += 32) {
        ushort8v a0h = *(const ushort8v*)(Ahld + kt);
        ushort8v a1h = *(const ushort8v*)(Ahld + kt + 8);
        ushort8v a0l = *(const ushort8v*)(Alld + kt);
        ushort8v a1l = *(const ushort8v*)(Alld + kt + 8);
        ushort8v w0h, w1h, w0l, w1l;
        if (isbf) {
            const unsigned short* Wp = (const unsigned short*)Wv + wldbase + kt;
            w0h = *(const ushort8v*)(Wp);
            w1h = *(const ushort8v*)(Wp + 8);
            w0l = w0h ^ w0h;
            w1l = w0l;
        } else {
            const float* Wp = (const float*)Wv + wldbase + kt;
            unsigned short th[16], tl[16];
#pragma unroll
            for (int t4 = 0; t4 < 4; ++t4) {
                float4 f = *(const float4*)(Wp + 4 * t4);
                float fv[4] = {f.x, f.y, f.z, f.w};
#pragma unroll
                for (int u = 0; u < 4; ++u) {
                    const unsigned short hi = f2bf(fv[u]);
                    th[4 * t4 + u] = hi;
                    tl[4 * t4 + u] = f2bf(fv[u] - us2f(hi));
                }
            }
            w0h = *(ushort8v*)&th[0]; w1h = *(ushort8v*)&th[8];
            w0l = *(ushort8v*)&tl[0]; w1l = *(ushort8v*)&tl[8];
        }
        __syncthreads();
        *(ushort8v*)Ahdst = a0h;
        *(ushort8v*)(Ahdst + 8) = a1h;
        *(ushort8v*)Aldst = a0l;
        *(ushort8v*)(Aldst + 8) = a1l;
        *(ushort8v*)Whdst = w0h;
        *(ushort8v*)(Whdst + 8) = w1h;
        *(ushort8v*)Wldst = w0l;
        *(ushort8v*)(Wldst + 8) = w1l;
        __syncthreads();

        short8 afh[4], afl[4], bfh[4], bfl[4];
#pragma unroll
        for (int i = 0; i < 4; ++i) {
            afh[i] = *(const short8*)&Ash[(wm + i * 16 + frow) * 40 + fk];
            afl[i] = *(const short8*)&Asl[(wm + i * 16 + frow) * 40 + fk];
        }
#pragma unroll
        for (int j = 0; j < 4; ++j) {
            bfh[j] = *(const short8*)&Wsh[(wn + j * 16 + frow) * 40 + fk];
            bfl[j] = *(const short8*)&Wsl[(wn + j * 16 + frow) * 40 + fk];
        }
#pragma unroll
        for (int i = 0; i < 4; ++i)
#pragma unroll
            for (int j = 0; j < 4; ++j) {
                acc[i][j] = __builtin_amdgcn_mfma_f32_16x16x32_bf16(
                    afh[i], bfh[j], acc[i][j], 0, 0, 0);
                acc[i][j] = __builtin_amdgcn_mfma_f32_16x16x32_bf16(
                    afh[i], bfl[j], acc[i][j], 0, 0, 0);
                acc[i][j] = __builtin_amdgcn_mfma_f32_16x16x32_bf16(
                    afl[i], bfh[j], acc[i][j], 0, 0, 0);
            }
    }

#pragma unroll
    for (int i = 0; i < 4; ++i) {
        const int r0 = bm + wm + i * 16 + ((lane >> 4) << 2);
#pragma unroll
        for (int j = 0; j < 4; ++j) {
            const int c = bn + wn + j * 16 + (lane & 15);
            if (c < N) {
#pragma unroll
                for (int g = 0; g < 4; ++g)
                    C[(size_t)(r0 + g) * N + c] = acc[i][j][g];
            }
        }
    }
}

// ---------------- bf16 MFMA GEMM (FFN path) ----------------
template <int EPI>
__global__ __launch_bounds__(256) void gemm_mfma_k(
    const unsigned short* __restrict__ A, const void* __restrict__ Wv,
    const float* __restrict__ R, void* __restrict__ outp,
    int N, int K, const int* __restrict__ flag)
{
    const int isbf = *flag;
    __shared__ unsigned short As[128 * 40];
    __shared__ unsigned short Ws[128 * 40];
    const int tid = threadIdx.x;
    const int lane = tid & 63;
    const int wave = tid >> 6;
    const int wm = (wave >> 1) << 6, wn = (wave & 1) << 6;
    const int bm = blockIdx.y << 7, bn = blockIdx.x << 7;
    const int srow = tid >> 1, scol = (tid & 1) << 4;
    const unsigned short* Ald = A + (size_t)(bm + srow) * K + scol;
    const size_t wldbase = (size_t)(bn + srow) * K + scol;
    unsigned short* Adst = &As[srow * 40 + scol];
    unsigned short* Wdst = &Ws[srow * 40 + scol];
    const int frow = lane & 15;
    const int fk = (lane >> 4) << 3;

    f32x4 acc[4][4] = {};

    for (int kt = 0; kt < K; kt += 32) {
        ushort8v a0 = *(const ushort8v*)(Ald + kt);
        ushort8v a1 = *(const ushort8v*)(Ald + kt + 8);
        ushort8v w0, w1;
        if (isbf) {
            const unsigned short* Wp = (const unsigned short*)Wv + wldbase + kt;
            w0 = *(const ushort8v*)(Wp);
            w1 = *(const ushort8v*)(Wp + 8);
        } else {
            const float* Wp = (const float*)Wv + wldbase + kt;
            float4 f0 = *(const float4*)(Wp);
            float4 f1 = *(const float4*)(Wp + 4);
            float4 f2 = *(const float4*)(Wp + 8);
            float4 f3 = *(const float4*)(Wp + 12);
            unsigned short wt[16];
            wt[0] = f2bf(f0.x); wt[1] = f2bf(f0.y); wt[2]  = f2bf(f0.z); wt[3]  = f2bf(f0.w);
            wt[4] = f2bf(f1.x); wt[5] = f2bf(f1.y); wt[6]  = f2bf(f1.z); wt[7]  = f2bf(f1.w);
            wt[8] = f2bf(f2.x); wt[9] = f2bf(f2.y); wt[10] = f2bf(f2.z); wt[11] = f2bf(f2.w);
            wt[12] = f2bf(f3.x); wt[13] = f2bf(f3.y); wt[14] = f2bf(f3.z); wt[15] = f2bf(f3.w);
            w0 = *(const ushort8v*)&wt[0];
            w1 = *(const ushort8v*)&wt[8];
        }
        __syncthreads();
        *(ushort8v*)Adst = a0;
        *(ushort8v*)(Adst + 8) = a1;
        *(ushort8v*)Wdst = w0;
        *(ushort8v*)(Wdst + 8) = w1;
        __syncthreads();

        short8 af[4], bfr[4];
#pragma unroll
        for (int i = 0; i < 4; ++i)
            af[i] = *(const short8*)&As[(wm + i * 16 + frow) * 40 + fk];
#pragma unroll
        for (int j = 0; j < 4; ++j)
            bfr[j] = *(const short8*)&Ws[(wn + j * 16 + frow) * 40 + fk];
#pragma unroll
        for (int i = 0; i < 4; ++i)
#pragma unroll
            for (int j = 0; j < 4; ++j)
                acc[i][j] = __builtin_amdgcn_mfma_f32_16x16x32_bf16(
                    af[i], bfr[j], acc[i][j], 0, 0, 0);
    }

#pragma unroll
    for (int i = 0; i < 4; ++i) {
        const int r0 = bm + wm + i * 16 + ((lane >> 4) << 2);
#pragma unroll
        for (int j = 0; j < 4; ++j) {
            const int c = bn + wn + j * 16 + (lane & 15);
#pragma unroll
            for (int g = 0; g < 4; ++g) {
                const size_t idx = (size_t)(r0 + g) * N + c;
                const float v = acc[i][j][g];
                if (EPI == 0) {
                    ((float*)outp)[idx] = v;
                } else if (EPI == 1) {
                    ((float*)outp)[idx] = v + R[idx];
                } else {
                    const float gv = R[idx];
                    const float sg = 1.0f / (1.0f + __expf(-gv));
                    ((unsigned short*)outp)[idx] = f2bf(gv * sg * v);
                }
            }
        }
    }
}

// ---------------- RoPE (interleaved pairs), in-place on q and k_pe ----------------
__global__ __launch_bounds__(256) void rope_k(
    float* __restrict__ qb, float* __restrict__ kva,
    const void* __restrict__ fc, const void* __restrict__ fs,
    const int* __restrict__ flag)
{
    const int isbf = *flag;
    const int t = blockIdx.x;
    const int tid = threadIdx.x;
    __shared__ float c[32], s[32];
    if (tid < 32) {
        c[tid] = ldf(fc, t * 32 + tid, isbf);
        s[tid] = ldf(fs, t * 32 + tid, isbf);
    }
    __syncthreads();
    for (int p = tid; p < 512; p += 256) {
        const int h = p >> 5, i = p & 31;
        float* base = qb + (size_t)t * 3072 + h * 192 + 128 + 2 * i;
        const float x0 = base[0], x1 = base[1];
        base[0] = x0 * c[i] - x1 * s[i];
        base[1] = x0 * s[i] + x1 * c[i];
    }
    if (tid < 32) {
        float* base = kva + (size_t)t * 576 + 512 + 2 * tid;
        const float x0 = base[0], x1 = base[1];
        base[0] = x0 * c[tid] - x1 * s[tid];
        base[1] = x0 * s[tid] + x1 * c[tid];
    }
}

// ---------------- KV prep: split K to hi/lo bf16 [h][t][192], transpose V ----------------
// kh/kl: K rows = [k_nope(128) | roped k_pe(64)] per (h,t). vt: [h][d][t] bf16.
__global__ __launch_bounds__(256) void kvprep_k(
    const float* __restrict__ kvb,   // [1024][4096] (16 heads x (128 nope | 128 v))
    const float* __restrict__ kva,   // [1024][576] (rope'd; [512,576) = k_pe)
    unsigned short* __restrict__ kh, unsigned short* __restrict__ kl,
    unsigned short* __restrict__ vt)
{
    const int tt = blockIdx.x, h = blockIdx.y;
    const int tid = threadIdx.x;
    const int tbase = tt * 64;
    for (int i = tid; i < 64 * 192; i += 256) {
        const int t = i / 192, k = i % 192;
        const float v = (k < 128)
            ? kvb[(size_t)(tbase + t) * 4096 + h * 256 + k]
            : kva[(size_t)(tbase + t) * 576 + 512 + (k - 128)];
        const unsigned short hi = f2bf(v);
        const size_t o = ((size_t)h * 1024 + tbase + t) * 192 + k;
        kh[o] = hi;
        kl[o] = f2bf(v - us2f(hi));
    }
    __shared__ unsigned short Vl[128][72];
    for (int i = tid; i < 64 * 128; i += 256) {
        const int t = i >> 7, d = i & 127;
        Vl[d][t] = f2bf(kvb[(size_t)(tbase + t) * 4096 + h * 256 + 128 + d]);
    }
    __syncthreads();
    for (int i = tid; i < 128 * 64; i += 256) {
        const int d = i >> 6, t = i & 63;
        vt[((size_t)h * 128 + d) * 1024 + tbase + t] = Vl[d][t];
    }
}

// ---------------- MFMA flash attention ----------------
// Block = (q-tile of 64 rows, head). 4 waves x 16 q-rows. KV tiles of 32.
// S via split-bf16 (QhKh + QhKl + QlKh), online softmax, PV via bf16 MFMA.
__global__ __launch_bounds__(256) void attn_mfma_k(
    const float* __restrict__ qb,          // [1024][3072] f32 (rope'd)
    const unsigned short* __restrict__ kh, // [16][1024][192] bf16 hi
    const unsigned short* __restrict__ kl, // lo
    const unsigned short* __restrict__ vt, // [16][128][1024] bf16
    unsigned short* __restrict__ y)        // [1024][2048] bf16
{
    const int qt = blockIdx.x, h = blockIdx.y;
    const int s0 = qt * QBLK;
    const int tid = threadIdx.x;
    const int lane = tid & 63, wave = tid >> 6;
    const int frow = lane & 15;            // A/B fragment row
    const int fk8 = (lane >> 4) << 3;      // fragment k-offset
    const int g4 = (lane >> 4) << 2;       // C-fragment row base

    __shared__ __align__(16) unsigned short Ksh[KVB][200];
    __shared__ __align__(16) unsigned short Ksl[KVB][200];
    __shared__ __align__(16) unsigned short Vs[128][40];
    __shared__ __align__(16) unsigned short Ps[4][16][40];

    // ---- Q fragments (hi/lo) for this wave's 16 rows, converted in-register ----
    const int wrow0 = s0 + wave * 16;
    short8 qhf[6], qlf[6];
    {
        const float* qrow = qb + (size_t)(wrow0 + frow) * 3072 + h * 192 + fk8;
#pragma unroll
        for (int ks = 0; ks < 6; ++ks) {
            float4 f0 = *(const float4*)(qrow + ks * 32);
            float4 f1 = *(const float4*)(qrow + ks * 32 + 4);
            float fv[8] = {f0.x, f0.y, f0.z, f0.w, f1.x, f1.y, f1.z, f1.w};
            unsigned short th[8], tl[8];
#pragma unroll
            for (int u = 0; u < 8; ++u) {
                th[u] = f2bf(fv[u]);
                tl[u] = f2bf(fv[u] - us2f(th[u]));
            }
            qhf[ks] = *(short8*)th;
            qlf[ks] = *(short8*)tl;
        }
    }

    f32x4 O[8] = {};                       // 8 d-subtiles x 4 rows (C-layout)
    float m_run[4] = {-1e30f, -1e30f, -1e30f, -1e30f};
    float l_run[4] = {};

    const int ntiles = (s0 + QBLK) / KVB;
    for (int tt = 0; tt < ntiles; ++tt) {
        const int t0 = tt * KVB;
        __syncthreads();                   // prior tile's LDS reads done
        // stage K hi/lo tile (coalesced 16B chunks)
        for (int i = tid; i < KVB * 24; i += 256) {
            const int r = i / 24, c = (i % 24) * 8;
            const size_t gof = ((size_t)h * 1024 + t0 + r) * 192 + c;
            *(ushort8v*)&Ksh[r][c] = *(const ushort8v*)(kh + gof);
            *(ushort8v*)&Ksl[r][c] = *(const ushort8v*)(kl + gof);
        }
        // stage V^T tile: 128 d x 32 t
        for (int i = tid; i < 128 * 4; i += 256) {
            const int d = i >> 2, c = (i & 3) * 8;
            *(ushort8v*)&Vs[d][c] =
                *(const ushort8v*)(vt + ((size_t)h * 128 + d) * 1024 + t0 + c);
        }
        __syncthreads();

        const bool active = (t0 <= wrow0 + 15);   // wave-uniform
        if (active) {
            // ---- QK: S(16x32) as 2 j-subtiles, 3-term split ----
            f32x4 s[2] = {};
#pragma unroll
            for (int j = 0; j < 2; ++j) {
                const unsigned short* kb = &Ksh[j * 16 + frow][fk8];
                const unsigned short* lb = &Ksl[j * 16 + frow][fk8];
#pragma unroll
                for (int ks = 0; ks < 6; ++ks) {
                    short8 bh = *(const short8*)(kb + ks * 32);
                    short8 bl = *(const short8*)(lb + ks * 32);
                    s[j] = __builtin_amdgcn_mfma_f32_16x16x32_bf16(qhf[ks], bh, s[j], 0, 0, 0);
                    s[j] = __builtin_amdgcn_mfma_f32_16x16x32_bf16(qhf[ks], bl, s[j], 0, 0, 0);
                    s[j] = __builtin_amdgcn_mfma_f32_16x16x32_bf16(qlf[ks], bh, s[j], 0, 0, 0);
                }
            }
            // scale + causal mask
            const bool edge = (t0 + KVB - 1 > wrow0);
            float sv[2][4];
#pragma unroll
            for (int j = 0; j < 2; ++j)
#pragma unroll
                for (int g = 0; g < 4; ++g) {
                    float v = s[j][g] * -96.0f;   // SOFTSCALE
                    if (edge) {
                        const int col = t0 + j * 16 + frow;
                        const int row = wrow0 + g4 + g;
                        if (col > row) v = -1e30f;
                    }
                    sv[j][g] = v;
                }
            // online softmax (row r = g4+g lives in one 16-lane group)
            float alpha[4];
#pragma unroll
            for (int g = 0; g < 4; ++g) {
                float mt = fmaxf(sv[0][g], sv[1][g]);
                mt = fmaxf(mt, __shfl_xor(mt, 1));
                mt = fmaxf(mt, __shfl_xor(mt, 2));
                mt = fmaxf(mt, __shfl_xor(mt, 4));
                mt = fmaxf(mt, __shfl_xor(mt, 8));
                const float mn = fmaxf(m_run[g], mt);
                alpha[g] = __expf(m_run[g] - mn);
                m_run[g] = mn;
                const float p0 = __expf(sv[0][g] - mn);
                const float p1 = __expf(sv[1][g] - mn);
                sv[0][g] = p0; sv[1][g] = p1;
                float ps = p0 + p1;
                ps += __shfl_xor(ps, 1);
                ps += __shfl_xor(ps, 2);
                ps += __shfl_xor(ps, 4);
                ps += __shfl_xor(ps, 8);
                l_run[g] = l_run[g] * alpha[g] + ps;
            }
            // rescale O
#pragma unroll
            for (int jt = 0; jt < 8; ++jt)
#pragma unroll
                for (int g = 0; g < 4; ++g)
                    O[jt][g] *= alpha[g];
            // P: C-layout -> A-layout via per-wave LDS bounce (bf16)
#pragma unroll
            for (int j = 0; j < 2; ++j)
#pragma unroll
                for (int g = 0; g < 4; ++g)
                    Ps[wave][g4 + g][j * 16 + frow] = f2bf(sv[j][g]);
        }
        __syncthreads();                   // (also orders Ps write->read)
        if (active) {
            short8 pa = *(const short8*)&Ps[wave][frow][fk8];
#pragma unroll
            for (int jt = 0; jt < 8; ++jt) {
                short8 vb = *(const short8*)&Vs[jt * 16 + frow][fk8];
                O[jt] = __builtin_amdgcn_mfma_f32_16x16x32_bf16(pa, vb, O[jt], 0, 0, 0);
            }
        }
    }

    // epilogue: normalize and store
#pragma unroll
    for (int g = 0; g < 4; ++g) {
        const float invl = 1.0f / l_run[g];
        const int row = wrow0 + g4 + g;
        unsigned short* yo = y + (size_t)row * 2048 + h * 128;
#pragma unroll
        for (int jt = 0; jt < 8; ++jt)
            yo[jt * 16 + frow] = f2bf(O[jt][g] * invl);
    }
}

extern "C" void kernel_launch(void* const* d_in, const int* in_sizes, int n_in,
                              void* d_out, int out_size, void* d_ws, size_t ws_size,
                              hipStream_t stream) {
    (void)in_sizes; (void)n_in; (void)out_size; (void)ws_size;
    const void* x       = d_in[0];
    const void* fcos    = d_in[2];
    const void* fsin    = d_in[3];
    const void* attn_nw = d_in[4];
    const void* wq_a    = d_in[5];
    const void* q_nw    = d_in[6];
    const void* wq_b    = d_in[7];
    const void* wkv_a   = d_in[8];
    const void* kv_nw   = d_in[9];
    const void* wkv_b   = d_in[10];
    const void* wo      = d_in[11];
    const void* ffn_nw  = d_in[12];
    const void* w1      = d_in[13];
    const void* w2      = d_in[14];
    const void* w3      = d_in[15];

    int* flag = (int*)d_ws;
    float* a  = (float*)d_ws + 64;
    const size_t M1 = 1048576;
    // Per-batch arena (float units). Peak 16M floats + 256 B (proven in r5 via gb2).
    // Attention phase:
    float* xf  = a;                                               // [0,2M) f32 residual
    unsigned short* hh = (unsigned short*)(a + 2 * M1);           // [2M,3M) h hi
    unsigned short* hl = (unsigned short*)(a + 3 * M1);           // [3M,4M) h lo
    float* qa  = a + 4 * M1;                                      // [4M,5.5M); dead after q-norm
    float* kva = a + 4 * M1;                                      // [4M,4.5625M) (qa dead)
    unsigned short* kvnh = (unsigned short*)(a + 4 * M1 + 655360);            // ~[4.625M,+)
    unsigned short* kvnl = (unsigned short*)(a + 4 * M1 + 655360 + 262144);
    unsigned short* qah = (unsigned short*)(a + 5 * M1 + 524288); // [5.5M,6.25M)
    unsigned short* qal = (unsigned short*)(a + 6 * M1 + 262144); // [6.25M,7M)
    float* qb  = a + 7 * M1;                                      // [7M,10M) f32, live thru attn
    float* kvb = a + 10 * M1;                                     // [10M,14M); dead after kvprep
    unsigned short* kh = (unsigned short*)(a + 2 * M1);           // [2M,3.5M) (hh/hl dead)
    unsigned short* kl = (unsigned short*)(a + 5 * M1 + 524288);  // [5.5M,7M) (qah/qal dead)
    unsigned short* vt = (unsigned short*)(a + 14 * M1);          // [14M,15M)
    unsigned short* yb = (unsigned short*)(a + 3 * M1 + 524288);  // [3.5M,4M)
    // FFN phase:
    unsigned short* hb  = (unsigned short*)(a + 2 * M1);          // [2M,3M)
    float* gb  = a + 4 * M1;                                      // [4M,12M)
    unsigned short* gb2 = (unsigned short*)(a + 12 * M1);         // [12M,16M)
    float* x2  = xf;

    detect_k<<<1, 64, 0, stream>>>(x, flag);

    for (int b = 0; b < 2; ++b) {
        const size_t eoff = (size_t)b * TT * DD;
        float* outb = (float*)d_out + eoff;

        // --- attention path (split-bf16 MFMA score chain) ---
        rmsnorm_x_hl_k<<<TT, 256, 0, stream>>>(x, eoff, attn_nw, hh, hl, xf, flag);
        gemm_mfma3_k<<<dim3(12, 8), 256, 0, stream>>>(hh, hl, wq_a, qa, 1536, 2048, flag);
        rmsnorm_hl_k<<<TT, 256, 0, stream>>>(qa, q_nw, qah, qal, 1536, 1536, flag);
        gemm_mfma3_k<<<dim3(24, 8), 256, 0, stream>>>(qah, qal, wq_b, qb, 3072, 1536, flag);
        gemm_mfma3_k<<<dim3(5, 8), 256, 0, stream>>>(hh, hl, wkv_a, kva, 576, 2048, flag);
        rmsnorm_hl_k<<<TT, 256, 0, stream>>>(kva, kv_nw, kvnh, kvnl, 512, 576, flag);
        rope_k<<<TT, 256, 0, stream>>>(qb, kva, fcos, fsin, flag);
        gemm_mfma3_k<<<dim3(32, 8), 256, 0, stream>>>(kvnh, kvnl, wkv_b, kvb, 4096, 512, flag);
        kvprep_k<<<dim3(16, 16), 256, 0, stream>>>(kvb, kva, kh, kl, vt);
        attn_mfma_k<<<dim3(TT / QBLK, 16), 256, 0, stream>>>(qb, kh, kl, vt, yb);

        // --- FFN MFMA bf16 GEMMs ---
        gemm_mfma_k<1><<<dim3(2048 / 128, TT / 128), 256, 0, stream>>>(
            yb, wo, xf, x2, 2048, 2048, flag);
        rmsnorm_bf_k<<<TT, 256, 0, stream>>>(x2, ffn_nw, hb, 2048, flag);
        gemm_mfma_k<0><<<dim3(8192 / 128, TT / 128), 256, 0, stream>>>(
            hb, w1, nullptr, gb, 8192, 2048, flag);
        gemm_mfma_k<3><<<dim3(8192 / 128, TT / 128), 256, 0, stream>>>(
            hb, w3, gb, gb2, 8192, 2048, flag);
        gemm_mfma_k<1><<<dim3(2048 / 128, TT / 128), 256, 0, stream>>>(
            gb2, w2, x2, outb, 2048, 8192, flag);
    }
}

// Round 4
// 1988.648 us; speedup vs baseline: 1.6959x; 1.2055x over previous
//
#include <hip/hip_runtime.h>
#include <hip/hip_bf16.h>
#include <cstddef>

// DeepSeekBlock: B=2 T=1024 D=2048 H=16 NOPE=128 ROPE=64 QKD=192
// QLORA=1536 KVLORA=512 VHD=128 INTER=8192
// Round 9 = round 8 + arena fix:
//  - yb actually spans [3.5M,4.5M) floats (1024x2048 bf16 = 1M floats). Round 8 put
//    wo's split-K partial fp0 at [4M,6M), racing the wo GEMM's own A-reads of yb
//    (write fp0 / read yb overlap in [4M,4.5M)) -> NaN. fp0/fp1 moved to [5M,9M),
//    which is dead during both the wo and w2 GEMMs.
//  - GEMM k-loops pipelined: next tile's loads issued AFTER the MFMA-phase barrier.
//  - Split-K=2 for grid-starved GEMMs (wo, w2, wq_a, wq_b, wkv_a).
//  - One-time weight prep (if ws fits): FFN weights -> bf16, score weights -> hi/lo.
// Attention (MFMA flash, round 7) unchanged.

#define TT 1024
#define DD 2048
#define QBLK 64
#define KVB 32

using bf16 = __hip_bfloat16;
typedef __attribute__((ext_vector_type(8))) short short8;
typedef __attribute__((ext_vector_type(8))) unsigned short ushort8v;
typedef __attribute__((ext_vector_type(4))) float f32x4;

__device__ __forceinline__ float us2f(unsigned short u) {
    return __uint_as_float(((unsigned int)u) << 16);
}
__device__ __forceinline__ float ldf(const void* p, size_t i, int isbf) {
    return isbf ? us2f(((const unsigned short*)p)[i]) : ((const float*)p)[i];
}
__device__ __forceinline__ unsigned short f2bf(float f) {
    __hip_bfloat16 b = __float2bfloat16(f);
    return *reinterpret_cast<unsigned short*>(&b);
}

// ---------------- input dtype detection ----------------
__global__ __launch_bounds__(64) void detect_k(const void* __restrict__ x,
                                               int* __restrict__ flag)
{
    __shared__ int cnt;
    if (threadIdx.x == 0) cnt = 0;
    __syncthreads();
    const unsigned short* u = (const unsigned short*)x;
    int bad = 0;
    for (int i = threadIdx.x; i < 512; i += 64) {
        const float v = us2f(u[i]);
        const float a = fabsf(v);
        if (!(a < 1e6f) || (v != 0.0f && a < 1e-30f)) bad++;
    }
    atomicAdd(&cnt, bad);
    __syncthreads();
    if (threadIdx.x == 0) *flag = (cnt > 32) ? 0 : 1;   // 0 = f32, 1 = bf16
}

// ---------------- weight prep: any -> bf16 ----------------
__global__ __launch_bounds__(256) void cvt_bf_k(
    const void* __restrict__ src, unsigned short* __restrict__ dst,
    size_t n, const int* __restrict__ flag)
{
    const int isbf = *flag;
    const size_t stride = (size_t)gridDim.x * 2048;
    for (size_t i = ((size_t)blockIdx.x * 256 + threadIdx.x) * 8; i < n; i += stride) {
        if (isbf) {
            *(ushort8v*)(dst + i) = *(const ushort8v*)((const unsigned short*)src + i);
        } else {
            const float* s = (const float*)src + i;
            float4 f0 = *(const float4*)s, f1 = *(const float4*)(s + 4);
            unsigned short t[8] = {f2bf(f0.x), f2bf(f0.y), f2bf(f0.z), f2bf(f0.w),
                                   f2bf(f1.x), f2bf(f1.y), f2bf(f1.z), f2bf(f1.w)};
            *(ushort8v*)(dst + i) = *(const ushort8v*)t;
        }
    }
}

// ---------------- weight prep: any -> hi/lo bf16 pair ----------------
__global__ __launch_bounds__(256) void cvt_hl_k(
    const void* __restrict__ src, unsigned short* __restrict__ dh,
    unsigned short* __restrict__ dl, size_t n, const int* __restrict__ flag)
{
    const int isbf = *flag;
    const size_t stride = (size_t)gridDim.x * 2048;
    for (size_t i = ((size_t)blockIdx.x * 256 + threadIdx.x) * 8; i < n; i += stride) {
        unsigned short th[8], tl[8];
        if (isbf) {
            const unsigned short* s = (const unsigned short*)src + i;
#pragma unroll
            for (int u = 0; u < 8; ++u) { th[u] = s[u]; tl[u] = 0; }
        } else {
            const float* s = (const float*)src + i;
#pragma unroll
            for (int u = 0; u < 8; ++u) {
                const float v = s[u];
                th[u] = f2bf(v);
                tl[u] = f2bf(v - us2f(th[u]));
            }
        }
        *(ushort8v*)(dh + i) = *(const ushort8v*)th;
        *(ushort8v*)(dl + i) = *(const ushort8v*)tl;
    }
}

// ---------------- split-K combine: out = p0 + p1 (+ R) ----------------
template <int HASR>
__global__ __launch_bounds__(256) void combine_k(
    const float* __restrict__ p0, const float* __restrict__ p1,
    const float* __restrict__ R, float* __restrict__ out, int n4)
{
    const int stride = gridDim.x * 256;
    for (int i = blockIdx.x * 256 + threadIdx.x; i < n4; i += stride) {
        const float4 a4 = ((const float4*)p0)[i];
        const float4 b4 = ((const float4*)p1)[i];
        float4 o = {a4.x + b4.x, a4.y + b4.y, a4.z + b4.z, a4.w + b4.w};
        if (HASR) {
            const float4 r4 = ((const float4*)R)[i];
            o.x += r4.x; o.y += r4.y; o.z += r4.z; o.w += r4.w;
        }
        ((float4*)out)[i] = o;
    }
}

// ---------------- rmsnorm f32 -> hi/lo bf16 pair ----------------
__global__ __launch_bounds__(256) void rmsnorm_hl_k(
    const float* __restrict__ in, const void* __restrict__ w,
    unsigned short* __restrict__ oh, unsigned short* __restrict__ ol,
    int L, int istride, const int* __restrict__ flag)
{
    const int isbf = *flag;
    const int m = blockIdx.x, tid = threadIdx.x;
    const float* row = in + (size_t)m * istride;
    float ss = 0.f;
    for (int i = tid; i < L; i += 256) { float v = row[i]; ss += v * v; }
    __shared__ float red[256];
    red[tid] = ss; __syncthreads();
    for (int s = 128; s > 0; s >>= 1) {
        if (tid < s) red[tid] += red[tid + s];
        __syncthreads();
    }
    const float scale = 1.0f / sqrtf(red[0] / (float)L + 1e-6f);
    unsigned short* hrow = oh + (size_t)m * L;
    unsigned short* lrow = ol + (size_t)m * L;
    for (int i = tid; i < L; i += 256) {
        const float v = row[i] * scale * ldf(w, i, isbf);
        const unsigned short hi = f2bf(v);
        hrow[i] = hi;
        lrow[i] = f2bf(v - us2f(hi));
    }
}

// ---------------- rmsnorm f32->bf16 (FFN input) ----------------
__global__ __launch_bounds__(256) void rmsnorm_bf_k(
    const float* __restrict__ in, const void* __restrict__ w,
    unsigned short* __restrict__ out, int L,
    const int* __restrict__ flag)
{
    const int isbf = *flag;
    const int m = blockIdx.x, tid = threadIdx.x;
    const float* row = in + (size_t)m * L;
    float ss = 0.f;
    for (int i = tid; i < L; i += 256) { float v = row[i]; ss += v * v; }
    __shared__ float red[256];
    red[tid] = ss; __syncthreads();
    for (int s = 128; s > 0; s >>= 1) {
        if (tid < s) red[tid] += red[tid + s];
        __syncthreads();
    }
    const float scale = 1.0f / sqrtf(red[0] / (float)L + 1e-6f);
    unsigned short* orow = out + (size_t)m * L;
    for (int i = tid; i < L; i += 256)
        orow[i] = f2bf(row[i] * scale * ldf(w, i, isbf));
}

// rmsnorm on input x: writes hi/lo bf16 h and f32 residual copy
__global__ __launch_bounds__(256) void rmsnorm_x_hl_k(
    const void* __restrict__ x, size_t eoff, const void* __restrict__ w,
    unsigned short* __restrict__ hh, unsigned short* __restrict__ hl,
    float* __restrict__ xf, const int* __restrict__ flag)
{
    const int isbf = *flag;
    const int m = blockIdx.x, tid = threadIdx.x;
    const size_t base = eoff + (size_t)m * DD;
    float* xrow = xf + (size_t)m * DD;
    float ss = 0.f;
    float vals[8];
    for (int i = 0; i < 8; ++i) {
        float v = ldf(x, base + tid + 256 * i, isbf);
        vals[i] = v; ss += v * v;
        xrow[tid + 256 * i] = v;
    }
    __shared__ float red[256];
    red[tid] = ss; __syncthreads();
    for (int s = 128; s > 0; s >>= 1) {
        if (tid < s) red[tid] += red[tid + s];
        __syncthreads();
    }
    const float scale = 1.0f / sqrtf(red[0] / (float)DD + 1e-6f);
    unsigned short* hrow = hh + (size_t)m * DD;
    unsigned short* lrow = hl + (size_t)m * DD;
    for (int i = 0; i < 8; ++i) {
        const float v = vals[i] * scale * ldf(w, tid + 256 * i, isbf);
        const unsigned short hi = f2bf(v);
        hrow[tid + 256 * i] = hi;
        lrow[tid + 256 * i] = f2bf(v - us2f(hi));
    }
}

// ---------------- split-bf16 MFMA GEMM: C(M,N) f32 = (Ah+Al)(Wh+Wl)^T ----------------
// presplit=1: Wv/Wlo are pre-split bf16 hi/lo; pipelined staging. presplit=0:
// round-7 behavior (W f32/bf16 per flag). Split-K via [k0, k0+klen).
__global__ __launch_bounds__(256) void gemm_mfma3_k(
    const unsigned short* __restrict__ Ah, const unsigned short* __restrict__ Al,
    const void* __restrict__ Wv, const unsigned short* __restrict__ Wlo,
    float* __restrict__ C, int N, int K, int k0, int klen,
    int presplit, const int* __restrict__ flag)
{
    __shared__ unsigned short Ash[128 * 40];
    __shared__ unsigned short Asl[128 * 40];
    __shared__ unsigned short Wsh[128 * 40];
    __shared__ unsigned short Wsl[128 * 40];
    const int tid = threadIdx.x;
    const int lane = tid & 63;
    const int wave = tid >> 6;
    const int wm = (wave >> 1) << 6, wn = (wave & 1) << 6;
    const int bm = blockIdx.y << 7, bn = blockIdx.x << 7;
    const int srow = tid >> 1, scol = (tid & 1) << 4;
    const unsigned short* Ahld = Ah + (size_t)(bm + srow) * K + scol;
    const unsigned short* Alld = Al + (size_t)(bm + srow) * K + scol;
    const int wrow = bn + srow;
    const size_t wldbase = (size_t)((wrow < N) ? wrow : (N - 1)) * K + scol;
    unsigned short* Ahdst = &Ash[srow * 40 + scol];
    unsigned short* Aldst = &Asl[srow * 40 + scol];
    unsigned short* Whdst = &Wsh[srow * 40 + scol];
    unsigned short* Wldst = &Wsl[srow * 40 + scol];
    const int frow = lane & 15;
    const int fk = (lane >> 4) << 3;
    const int kend = k0 + klen;

    f32x4 acc[4][4] = {};

    if (presplit) {
        const unsigned short* Whp = (const unsigned short*)Wv + wldbase;
        const unsigned short* Wlp = Wlo + wldbase;
        ushort8v ca0h = *(const ushort8v*)(Ahld + k0);
        ushort8v ca1h = *(const ushort8v*)(Ahld + k0 + 8);
        ushort8v ca0l = *(const ushort8v*)(Alld + k0);
        ushort8v ca1l = *(const ushort8v*)(Alld + k0 + 8);
        ushort8v cw0h = *(const ushort8v*)(Whp + k0);
        ushort8v cw1h = *(const ushort8v*)(Whp + k0 + 8);
        ushort8v cw0l = *(const ushort8v*)(Wlp + k0);
        ushort8v cw1l = *(const ushort8v*)(Wlp + k0 + 8);
        for (int kt = k0; kt < kend; kt += 32) {
            __syncthreads();
            *(ushort8v*)Ahdst = ca0h; *(ushort8v*)(Ahdst + 8) = ca1h;
            *(ushort8v*)Aldst = ca0l; *(ushort8v*)(Aldst + 8) = ca1l;
            *(ushort8v*)Whdst = cw0h; *(ushort8v*)(Whdst + 8) = cw1h;
            *(ushort8v*)Wldst = cw0l; *(ushort8v*)(Wldst + 8) = cw1l;
            __syncthreads();
            // issue next tile's loads AFTER the barrier: they fly during MFMA
            const int nk = (kt + 32 < kend) ? kt + 32 : kt;
            ca0h = *(const ushort8v*)(Ahld + nk);
            ca1h = *(const ushort8v*)(Ahld + nk + 8);
            ca0l = *(const ushort8v*)(Alld + nk);
            ca1l = *(const ushort8v*)(Alld + nk + 8);
            cw0h = *(const ushort8v*)(Whp + nk);
            cw1h = *(const ushort8v*)(Whp + nk + 8);
            cw0l = *(const ushort8v*)(Wlp + nk);
            cw1l = *(const ushort8v*)(Wlp + nk + 8);

            short8 afh[4], afl[4], bfh[4], bfl[4];
#pragma unroll
            for (int i = 0; i < 4; ++i) {
                afh[i] = *(const short8*)&Ash[(wm + i * 16 + frow) * 40 + fk];
                afl[i] = *(const short8*)&Asl[(wm + i * 16 + frow) * 40 + fk];
            }
#pragma unroll
            for (int j = 0; j < 4; ++j) {
                bfh[j] = *(const short8*)&Wsh[(wn + j * 16 + frow) * 40 + fk];
                bfl[j] = *(const short8*)&Wsl[(wn + j * 16 + frow) * 40 + fk];
            }
#pragma unroll
            for (int i = 0; i < 4; ++i)
#pragma unroll
                for (int j = 0; j < 4; ++j) {
                    acc[i][j] = __builtin_amdgcn_mfma_f32_16x16x32_bf16(
                        afh[i], bfh[j], acc[i][j], 0, 0, 0);
                    acc[i][j] = __builtin_amdgcn_mfma_f32_16x16x32_bf16(
                        afh[i], bfl[j], acc[i][j], 0, 0, 0);
                    acc[i][j] = __builtin_amdgcn_mfma_f32_16x16x32_bf16(
                        afl[i], bfh[j], acc[i][j], 0, 0, 0);
                }
        }
    } else {
        const int isbf = *flag;
        for (int kt = k0; kt < kend; kt += 32) {
            ushort8v a0h = *(const ushort8v*)(Ahld + kt);
            ushort8v a1h = *(const ushort8v*)(Ahld + kt + 8);
            ushort8v a0l = *(const ushort8v*)(Alld + kt);
            ushort8v a1l = *(const ushort8v*)(Alld + kt + 8);
            ushort8v w0h, w1h, w0l, w1l;
            if (isbf) {
                const unsigned short* Wp = (const unsigned short*)Wv + wldbase + kt;
                w0h = *(const ushort8v*)(Wp);
                w1h = *(const ushort8v*)(Wp + 8);
                w0l = w0h ^ w0h;
                w1l = w0l;
            } else {
                const float* Wp = (const float*)Wv + wldbase + kt;
                unsigned short th[16], tl[16];
#pragma unroll
                for (int t4 = 0; t4 < 4; ++t4) {
                    float4 f = *(const float4*)(Wp + 4 * t4);
                    float fv[4] = {f.x, f.y, f.z, f.w};
#pragma unroll
                    for (int u = 0; u < 4; ++u) {
                        const unsigned short hi = f2bf(fv[u]);
                        th[4 * t4 + u] = hi;
                        tl[4 * t4 + u] = f2bf(fv[u] - us2f(hi));
                    }
                }
                w0h = *(ushort8v*)&th[0]; w1h = *(ushort8v*)&th[8];
                w0l = *(ushort8v*)&tl[0]; w1l = *(ushort8v*)&tl[8];
            }
            __syncthreads();
            *(ushort8v*)Ahdst = a0h; *(ushort8v*)(Ahdst + 8) = a1h;
            *(ushort8v*)Aldst = a0l; *(ushort8v*)(Aldst + 8) = a1l;
            *(ushort8v*)Whdst = w0h; *(ushort8v*)(Whdst + 8) = w1h;
            *(ushort8v*)Wldst = w0l; *(ushort8v*)(Wldst + 8) = w1l;
            __syncthreads();

            short8 afh[4], afl[4], bfh[4], bfl[4];
#pragma unroll
            for (int i = 0; i < 4; ++i) {
                afh[i] = *(const short8*)&Ash[(wm + i * 16 + frow) * 40 + fk];
                afl[i] = *(const short8*)&Asl[(wm + i * 16 + frow) * 40 + fk];
            }
#pragma unroll
            for (int j = 0; j < 4; ++j) {
                bfh[j] = *(const short8*)&Wsh[(wn + j * 16 + frow) * 40 + fk];
                bfl[j] = *(const short8*)&Wsl[(wn + j * 16 + frow) * 40 + fk];
            }
#pragma unroll
            for (int i = 0; i < 4; ++i)
#pragma unroll
                for (int j = 0; j < 4; ++j) {
                    acc[i][j] = __builtin_amdgcn_mfma_f32_16x16x32_bf16(
                        afh[i], bfh[j], acc[i][j], 0, 0, 0);
                    acc[i][j] = __builtin_amdgcn_mfma_f32_16x16x32_bf16(
                        afh[i], bfl[j], acc[i][j], 0, 0, 0);
                    acc[i][j] = __builtin_amdgcn_mfma_f32_16x16x32_bf16(
                        afl[i], bfh[j], acc[i][j], 0, 0, 0);
                }
        }
    }

#pragma unroll
    for (int i = 0; i < 4; ++i) {
        const int r0 = bm + wm + i * 16 + ((lane >> 4) << 2);
#pragma unroll
        for (int j = 0; j < 4; ++j) {
            const int c = bn + wn + j * 16 + (lane & 15);
            if (c < N) {
#pragma unroll
                for (int g = 0; g < 4; ++g)
                    C[(size_t)(r0 + g) * N + c] = acc[i][j][g];
            }
        }
    }
}

// ---------------- bf16 MFMA GEMM (FFN path) ----------------
// wready=1: W is bf16; pipelined staging. wready=0: round-7 behavior.
// Split-K via [k0,k0+klen). EPI 0: f32 C = acc; EPI 1: f32 C = R + acc;
// EPI 3: bf16 C = bf16(silu(R) * acc).
template <int EPI>
__global__ __launch_bounds__(256) void gemm_mfma_k(
    const unsigned short* __restrict__ A, const void* __restrict__ Wv,
    const float* __restrict__ R, void* __restrict__ outp,
    int N, int K, int k0, int klen, int wready, const int* __restrict__ flag)
{
    __shared__ unsigned short As[128 * 40];
    __shared__ unsigned short Ws[128 * 40];
    const int tid = threadIdx.x;
    const int lane = tid & 63;
    const int wave = tid >> 6;
    const int wm = (wave >> 1) << 6, wn = (wave & 1) << 6;
    const int bm = blockIdx.y << 7, bn = blockIdx.x << 7;
    const int srow = tid >> 1, scol = (tid & 1) << 4;
    const unsigned short* Ald = A + (size_t)(bm + srow) * K + scol;
    const size_t wldbase = (size_t)(bn + srow) * K + scol;
    unsigned short* Adst = &As[srow * 40 + scol];
    unsigned short* Wdst = &Ws[srow * 40 + scol];
    const int frow = lane & 15;
    const int fk = (lane >> 4) << 3;
    const int kend = k0 + klen;

    f32x4 acc[4][4] = {};

    if (wready) {
        const unsigned short* Wp = (const unsigned short*)Wv + wldbase;
        ushort8v ca0 = *(const ushort8v*)(Ald + k0);
        ushort8v ca1 = *(const ushort8v*)(Ald + k0 + 8);
        ushort8v cw0 = *(const ushort8v*)(Wp + k0);
        ushort8v cw1 = *(const ushort8v*)(Wp + k0 + 8);
        for (int kt = k0; kt < kend; kt += 32) {
            __syncthreads();
            *(ushort8v*)Adst = ca0; *(ushort8v*)(Adst + 8) = ca1;
            *(ushort8v*)Wdst = cw0; *(ushort8v*)(Wdst + 8) = cw1;
            __syncthreads();
            const int nk = (kt + 32 < kend) ? kt + 32 : kt;
            ca0 = *(const ushort8v*)(Ald + nk);
            ca1 = *(const ushort8v*)(Ald + nk + 8);
            cw0 = *(const ushort8v*)(Wp + nk);
            cw1 = *(const ushort8v*)(Wp + nk + 8);

            short8 af[4], bfr[4];
#pragma unroll
            for (int i = 0; i < 4; ++i)
                af[i] = *(const short8*)&As[(wm + i * 16 + frow) * 40 + fk];
#pragma unroll
            for (int j = 0; j < 4; ++j)
                bfr[j] = *(const short8*)&Ws[(wn + j * 16 + frow) * 40 + fk];
#pragma unroll
            for (int i = 0; i < 4; ++i)
#pragma unroll
                for (int j = 0; j < 4; ++j)
                    acc[i][j] = __builtin_amdgcn_mfma_f32_16x16x32_bf16(
                        af[i], bfr[j], acc[i][j], 0, 0, 0);
        }
    } else {
        const int isbf = *flag;
        for (int kt = k0; kt < kend; kt += 32) {
            ushort8v a0 = *(const ushort8v*)(Ald + kt);
            ushort8v a1 = *(const ushort8v*)(Ald + kt + 8);
            ushort8v w0, w1;
            if (isbf) {
                const unsigned short* Wp = (const unsigned short*)Wv + wldbase + kt;
                w0 = *(const ushort8v*)(Wp);
                w1 = *(const ushort8v*)(Wp + 8);
            } else {
                const float* Wp = (const float*)Wv + wldbase + kt;
                float4 f0 = *(const float4*)(Wp);
                float4 f1 = *(const float4*)(Wp + 4);
                float4 f2 = *(const float4*)(Wp + 8);
                float4 f3 = *(const float4*)(Wp + 12);
                unsigned short wt[16];
                wt[0] = f2bf(f0.x); wt[1] = f2bf(f0.y); wt[2]  = f2bf(f0.z); wt[3]  = f2bf(f0.w);
                wt[4] = f2bf(f1.x); wt[5] = f2bf(f1.y); wt[6]  = f2bf(f1.z); wt[7]  = f2bf(f1.w);
                wt[8] = f2bf(f2.x); wt[9] = f2bf(f2.y); wt[10] = f2bf(f2.z); wt[11] = f2bf(f2.w);
                wt[12] = f2bf(f3.x); wt[13] = f2bf(f3.y); wt[14] = f2bf(f3.z); wt[15] = f2bf(f3.w);
                w0 = *(const ushort8v*)&wt[0];
                w1 = *(const ushort8v*)&wt[8];
            }
            __syncthreads();
            *(ushort8v*)Adst = a0; *(ushort8v*)(Adst + 8) = a1;
            *(ushort8v*)Wdst = w0; *(ushort8v*)(Wdst + 8) = w1;
            __syncthreads();

            short8 af[4], bfr[4];
#pragma unroll
            for (int i = 0; i < 4; ++i)
                af[i] = *(const short8*)&As[(wm + i * 16 + frow) * 40 + fk];
#pragma unroll
            for (int j = 0; j < 4; ++j)
                bfr[j] = *(const short8*)&Ws[(wn + j * 16 + frow) * 40 + fk];
#pragma unroll
            for (int i = 0; i < 4; ++i)
#pragma unroll
                for (int j = 0; j < 4; ++j)
                    acc[i][j] = __builtin_amdgcn_mfma_f32_16x16x32_bf16(
                        af[i], bfr[j], acc[i][j], 0, 0, 0);
        }
    }

#pragma unroll
    for (int i = 0; i < 4; ++i) {
        const int r0 = bm + wm + i * 16 + ((lane >> 4) << 2);
#pragma unroll
        for (int j = 0; j < 4; ++j) {
            const int c = bn + wn + j * 16 + (lane & 15);
#pragma unroll
            for (int g = 0; g < 4; ++g) {
                const size_t idx = (size_t)(r0 + g) * N + c;
                const float v = acc[i][j][g];
                if (EPI == 0) {
                    ((float*)outp)[idx] = v;
                } else if (EPI == 1) {
                    ((float*)outp)[idx] = v + R[idx];
                } else {
                    const float gv = R[idx];
                    const float sg = 1.0f / (1.0f + __expf(-gv));
                    ((unsigned short*)outp)[idx] = f2bf(gv * sg * v);
                }
            }
        }
    }
}

// ---------------- RoPE (interleaved pairs), in-place on q and k_pe ----------------
__global__ __launch_bounds__(256) void rope_k(
    float* __restrict__ qb, float* __restrict__ kva,
    const void* __restrict__ fc, const void* __restrict__ fs,
    const int* __restrict__ flag)
{
    const int isbf = *flag;
    const int t = blockIdx.x;
    const int tid = threadIdx.x;
    __shared__ float c[32], s[32];
    if (tid < 32) {
        c[tid] = ldf(fc, t * 32 + tid, isbf);
        s[tid] = ldf(fs, t * 32 + tid, isbf);
    }
    __syncthreads();
    for (int p = tid; p < 512; p += 256) {
        const int h = p >> 5, i = p & 31;
        float* base = qb + (size_t)t * 3072 + h * 192 + 128 + 2 * i;
        const float x0 = base[0], x1 = base[1];
        base[0] = x0 * c[i] - x1 * s[i];
        base[1] = x0 * s[i] + x1 * c[i];
    }
    if (tid < 32) {
        float* base = kva + (size_t)t * 576 + 512 + 2 * tid;
        const float x0 = base[0], x1 = base[1];
        base[0] = x0 * c[tid] - x1 * s[tid];
        base[1] = x0 * s[tid] + x1 * c[tid];
    }
}

// ---------------- KV prep: split K to hi/lo bf16 [h][t][192], transpose V ----------------
__global__ __launch_bounds__(256) void kvprep_k(
    const float* __restrict__ kvb,   // [1024][4096]
    const float* __restrict__ kva,   // [1024][576]
    unsigned short* __restrict__ kh, unsigned short* __restrict__ kl,
    unsigned short* __restrict__ vt)
{
    const int tt = blockIdx.x, h = blockIdx.y;
    const int tid = threadIdx.x;
    const int tbase = tt * 64;
    for (int i = tid; i < 64 * 192; i += 256) {
        const int t = i / 192, k = i % 192;
        const float v = (k < 128)
            ? kvb[(size_t)(tbase + t) * 4096 + h * 256 + k]
            : kva[(size_t)(tbase + t) * 576 + 512 + (k - 128)];
        const unsigned short hi = f2bf(v);
        const size_t o = ((size_t)h * 1024 + tbase + t) * 192 + k;
        kh[o] = hi;
        kl[o] = f2bf(v - us2f(hi));
    }
    __shared__ unsigned short Vl[128][72];
    for (int i = tid; i < 64 * 128; i += 256) {
        const int t = i >> 7, d = i & 127;
        Vl[d][t] = f2bf(kvb[(size_t)(tbase + t) * 4096 + h * 256 + 128 + d]);
    }
    __syncthreads();
    for (int i = tid; i < 128 * 64; i += 256) {
        const int d = i >> 6, t = i & 63;
        vt[((size_t)h * 128 + d) * 1024 + tbase + t] = Vl[d][t];
    }
}

// ---------------- MFMA flash attention (round 7) ----------------
__global__ __launch_bounds__(256) void attn_mfma_k(
    const float* __restrict__ qb,
    const unsigned short* __restrict__ kh,
    const unsigned short* __restrict__ kl,
    const unsigned short* __restrict__ vt,
    unsigned short* __restrict__ y)
{
    const int qt = blockIdx.x, h = blockIdx.y;
    const int s0 = qt * QBLK;
    const int tid = threadIdx.x;
    const int lane = tid & 63, wave = tid >> 6;
    const int frow = lane & 15;
    const int fk8 = (lane >> 4) << 3;
    const int g4 = (lane >> 4) << 2;

    __shared__ __align__(16) unsigned short Ksh[KVB][200];
    __shared__ __align__(16) unsigned short Ksl[KVB][200];
    __shared__ __align__(16) unsigned short Vs[128][40];
    __shared__ __align__(16) unsigned short Ps[4][16][40];

    const int wrow0 = s0 + wave * 16;
    short8 qhf[6], qlf[6];
    {
        const float* qrow = qb + (size_t)(wrow0 + frow) * 3072 + h * 192 + fk8;
#pragma unroll
        for (int ks = 0; ks < 6; ++ks) {
            float4 f0 = *(const float4*)(qrow + ks * 32);
            float4 f1 = *(const float4*)(qrow + ks * 32 + 4);
            float fv[8] = {f0.x, f0.y, f0.z, f0.w, f1.x, f1.y, f1.z, f1.w};
            unsigned short th[8], tl[8];
#pragma unroll
            for (int u = 0; u < 8; ++u) {
                th[u] = f2bf(fv[u]);
                tl[u] = f2bf(fv[u] - us2f(th[u]));
            }
            qhf[ks] = *(short8*)th;
            qlf[ks] = *(short8*)tl;
        }
    }

    f32x4 O[8] = {};
    float m_run[4] = {-1e30f, -1e30f, -1e30f, -1e30f};
    float l_run[4] = {};

    const int ntiles = (s0 + QBLK) / KVB;
    for (int tt = 0; tt < ntiles; ++tt) {
        const int t0 = tt * KVB;
        __syncthreads();
        for (int i = tid; i < KVB * 24; i += 256) {
            const int r = i / 24, c = (i % 24) * 8;
            const size_t gof = ((size_t)h * 1024 + t0 + r) * 192 + c;
            *(ushort8v*)&Ksh[r][c] = *(const ushort8v*)(kh + gof);
            *(ushort8v*)&Ksl[r][c] = *(const ushort8v*)(kl + gof);
        }
        for (int i = tid; i < 128 * 4; i += 256) {
            const int d = i >> 2, c = (i & 3) * 8;
            *(ushort8v*)&Vs[d][c] =
                *(const ushort8v*)(vt + ((size_t)h * 128 + d) * 1024 + t0 + c);
        }
        __syncthreads();

        const bool active = (t0 <= wrow0 + 15);
        if (active) {
            f32x4 s[2] = {};
#pragma unroll
            for (int j = 0; j < 2; ++j) {
                const unsigned short* kb = &Ksh[j * 16 + frow][fk8];
                const unsigned short* lb = &Ksl[j * 16 + frow][fk8];
#pragma unroll
                for (int ks = 0; ks < 6; ++ks) {
                    short8 bh = *(const short8*)(kb + ks * 32);
                    short8 bl = *(const short8*)(lb + ks * 32);
                    s[j] = __builtin_amdgcn_mfma_f32_16x16x32_bf16(qhf[ks], bh, s[j], 0, 0, 0);
                    s[j] = __builtin_amdgcn_mfma_f32_16x16x32_bf16(qhf[ks], bl, s[j], 0, 0, 0);
                    s[j] = __builtin_amdgcn_mfma_f32_16x16x32_bf16(qlf[ks], bh, s[j], 0, 0, 0);
                }
            }
            const bool edge = (t0 + KVB - 1 > wrow0);
            float sv[2][4];
#pragma unroll
            for (int j = 0; j < 2; ++j)
#pragma unroll
                for (int g = 0; g < 4; ++g) {
                    float v = s[j][g] * -96.0f;
                    if (edge) {
                        const int col = t0 + j * 16 + frow;
                        const int row = wrow0 + g4 + g;
                        if (col > row) v = -1e30f;
                    }
                    sv[j][g] = v;
                }
            float alpha[4];
#pragma unroll
            for (int g = 0; g < 4; ++g) {
                float mt = fmaxf(sv[0][g], sv[1][g]);
                mt = fmaxf(mt, __shfl_xor(mt, 1));
                mt = fmaxf(mt, __shfl_xor(mt, 2));
                mt = fmaxf(mt, __shfl_xor(mt, 4));
                mt = fmaxf(mt, __shfl_xor(mt, 8));
                const float mn = fmaxf(m_run[g], mt);
                alpha[g] = __expf(m_run[g] - mn);
                m_run[g] = mn;
                const float p0 = __expf(sv[0][g] - mn);
                const float p1 = __expf(sv[1][g] - mn);
                sv[0][g] = p0; sv[1][g] = p1;
                float ps = p0 + p1;
                ps += __shfl_xor(ps, 1);
                ps += __shfl_xor(ps, 2);
                ps += __shfl_xor(ps, 4);
                ps += __shfl_xor(ps, 8);
                l_run[g] = l_run[g] * alpha[g] + ps;
            }
#pragma unroll
            for (int jt = 0; jt < 8; ++jt)
#pragma unroll
                for (int g = 0; g < 4; ++g)
                    O[jt][g] *= alpha[g];
#pragma unroll
            for (int j = 0; j < 2; ++j)
#pragma unroll
                for (int g = 0; g < 4; ++g)
                    Ps[wave][g4 + g][j * 16 + frow] = f2bf(sv[j][g]);
        }
        __syncthreads();
        if (active) {
            short8 pa = *(const short8*)&Ps[wave][frow][fk8];
#pragma unroll
            for (int jt = 0; jt < 8; ++jt) {
                short8 vb = *(const short8*)&Vs[jt * 16 + frow][fk8];
                O[jt] = __builtin_amdgcn_mfma_f32_16x16x32_bf16(pa, vb, O[jt], 0, 0, 0);
            }
        }
    }

#pragma unroll
    for (int g = 0; g < 4; ++g) {
        const float invl = 1.0f / l_run[g];
        const int row = wrow0 + g4 + g;
        unsigned short* yo = y + (size_t)row * 2048 + h * 128;
#pragma unroll
        for (int jt = 0; jt < 8; ++jt)
            yo[jt * 16 + frow] = f2bf(O[jt][g] * invl);
    }
}

extern "C" void kernel_launch(void* const* d_in, const int* in_sizes, int n_in,
                              void* d_out, int out_size, void* d_ws, size_t ws_size,
                              hipStream_t stream) {
    (void)in_sizes; (void)n_in; (void)out_size;
    const void* x       = d_in[0];
    const void* fcos    = d_in[2];
    const void* fsin    = d_in[3];
    const void* attn_nw = d_in[4];
    const void* wq_a    = d_in[5];
    const void* q_nw    = d_in[6];
    const void* wq_b    = d_in[7];
    const void* wkv_a   = d_in[8];
    const void* kv_nw   = d_in[9];
    const void* wkv_b   = d_in[10];
    const void* wo      = d_in[11];
    const void* ffn_nw  = d_in[12];
    const void* w1      = d_in[13];
    const void* w2      = d_in[14];
    const void* w3      = d_in[15];

    int* flag = (int*)d_ws;
    float* a  = (float*)d_ws + 64;
    const size_t M1 = 1048576;
    // Arena (float units), peak 16M floats = 64 MiB:
    float* xf  = a;                                               // [0,2M) f32 residual
    unsigned short* hh = (unsigned short*)(a + 2 * M1);           // [2M,3M)
    unsigned short* hl = (unsigned short*)(a + 3 * M1);           // [3M,4M)
    float* qa  = a + 4 * M1;                                      // [4M,5.5M)
    float* kva = a + 4 * M1;                                      // [4M,4.5625M) (qa dead)
    unsigned short* kvnh = (unsigned short*)(a + 4 * M1 + 655360);
    unsigned short* kvnl = (unsigned short*)(a + 4 * M1 + 655360 + 262144);
    unsigned short* qah = (unsigned short*)(a + 5 * M1 + 524288); // [5.5M,6.25M)
    unsigned short* qal = (unsigned short*)(a + 6 * M1 + 262144); // [6.25M,7M)
    float* qb  = a + 7 * M1;                                      // [7M,10M)
    float* kvb = a + 10 * M1;                                     // [10M,14M)
    unsigned short* kh = (unsigned short*)(a + 2 * M1);           // [2M,3.5M)
    unsigned short* kl = (unsigned short*)(a + 5 * M1 + 524288);  // [5.5M,7M)
    unsigned short* vt = (unsigned short*)(a + 14 * M1);          // [14M,15M)
    unsigned short* yb = (unsigned short*)(a + 3 * M1 + 524288);  // [3.5M,4.5M) !
    unsigned short* hb  = (unsigned short*)(a + 2 * M1);          // [2M,3M)
    float* gb  = a + 4 * M1;                                      // [4M,12M)
    unsigned short* gb2 = (unsigned short*)(a + 12 * M1);         // [12M,16M)
    float* x2  = xf;
    // Split-K partials:
    float* sp0 = a + 10 * M1;            // score-path scratch (pre-kvb phase)
    // FFN partials: [5M,9M) — dead during wo GEMM (qb/kl consumed by attn) and
    // during w2 GEMM (inside dead gb). MUST NOT overlap yb [3.5M,4.5M).
    float* fp0 = a + 5 * M1;
    float* fp1 = a + 7 * M1;
    // Prepared weights (beyond 16M; only if ws_size allows):
    unsigned short* wo_b  = (unsigned short*)(a + 16 * M1);       // 4M us
    unsigned short* w1_b  = (unsigned short*)(a + 18 * M1);       // 16M us
    unsigned short* w3_b  = (unsigned short*)(a + 26 * M1);       // 16M us
    unsigned short* w2_b  = (unsigned short*)(a + 34 * M1);       // 16M us
    unsigned short* wqa_h = (unsigned short*)(a + 42 * M1);
    unsigned short* wqa_l = wqa_h + 3145728u;
    unsigned short* wqb_h = (unsigned short*)(a + 45 * M1);
    unsigned short* wqb_l = wqb_h + 4718592u;
    unsigned short* wkva_h = (unsigned short*)(a + 49 * M1 + 524288);
    unsigned short* wkva_l = wkva_h + 1179648u;
    unsigned short* wkvb_h = (unsigned short*)(a + 50 * M1 + 655360);
    unsigned short* wkvb_l = wkvb_h + 2097152u;
    const size_t NEED = 256 + (size_t)(52 * M1 + 655360) * 4;     // ~220.7 MB
    const int prep = (ws_size >= NEED) ? 1 : 0;

    detect_k<<<1, 64, 0, stream>>>(x, flag);

    if (prep) {
        cvt_bf_k<<<1024, 256, 0, stream>>>(wo, wo_b, (size_t)2048 * 2048, flag);
        cvt_bf_k<<<2048, 256, 0, stream>>>(w1, w1_b, (size_t)8192 * 2048, flag);
        cvt_bf_k<<<2048, 256, 0, stream>>>(w3, w3_b, (size_t)8192 * 2048, flag);
        cvt_bf_k<<<2048, 256, 0, stream>>>(w2, w2_b, (size_t)2048 * 8192, flag);
        cvt_hl_k<<<1024, 256, 0, stream>>>(wq_a, wqa_h, wqa_l, (size_t)1536 * 2048, flag);
        cvt_hl_k<<<1024, 256, 0, stream>>>(wq_b, wqb_h, wqb_l, (size_t)3072 * 1536, flag);
        cvt_hl_k<<<512, 256, 0, stream>>>(wkv_a, wkva_h, wkva_l, (size_t)576 * 2048, flag);
        cvt_hl_k<<<1024, 256, 0, stream>>>(wkv_b, wkvb_h, wkvb_l, (size_t)4096 * 512, flag);
    }
    const void* Wqa = prep ? (const void*)wqa_h : wq_a;
    const void* Wqb = prep ? (const void*)wqb_h : wq_b;
    const void* Wkva = prep ? (const void*)wkva_h : wkv_a;
    const void* Wkvb = prep ? (const void*)wkvb_h : wkv_b;
    const unsigned short* WqaL = prep ? wqa_l : nullptr;
    const unsigned short* WqbL = prep ? wqb_l : nullptr;
    const unsigned short* WkvaL = prep ? wkva_l : nullptr;
    const unsigned short* WkvbL = prep ? wkvb_l : nullptr;
    const void* WoP = prep ? (const void*)wo_b : wo;
    const void* W1P = prep ? (const void*)w1_b : w1;
    const void* W3P = prep ? (const void*)w3_b : w3;
    const void* W2P = prep ? (const void*)w2_b : w2;

    for (int b = 0; b < 2; ++b) {
        const size_t eoff = (size_t)b * TT * DD;
        float* outb = (float*)d_out + eoff;

        // --- attention path (split-bf16 MFMA score chain, split-K=2) ---
        rmsnorm_x_hl_k<<<TT, 256, 0, stream>>>(x, eoff, attn_nw, hh, hl, xf, flag);
        // qa = rms(h) @ wq_a^T   (N=1536, K=2048)
        gemm_mfma3_k<<<dim3(12, 8), 256, 0, stream>>>(hh, hl, Wqa, WqaL, sp0, 1536, 2048, 0, 1024, prep, flag);
        gemm_mfma3_k<<<dim3(12, 8), 256, 0, stream>>>(hh, hl, Wqa, WqaL, sp0 + 1572864, 1536, 2048, 1024, 1024, prep, flag);
        combine_k<0><<<1024, 256, 0, stream>>>(sp0, sp0 + 1572864, nullptr, qa, 393216);
        rmsnorm_hl_k<<<TT, 256, 0, stream>>>(qa, q_nw, qah, qal, 1536, 1536, flag);
        // qb = q @ wq_b^T   (N=3072, K=1536)
        gemm_mfma3_k<<<dim3(24, 8), 256, 0, stream>>>(qah, qal, Wqb, WqbL, sp0, 3072, 1536, 0, 768, prep, flag);
        gemm_mfma3_k<<<dim3(24, 8), 256, 0, stream>>>(qah, qal, Wqb, WqbL, sp0 + 3145728, 3072, 1536, 768, 768, prep, flag);
        combine_k<0><<<1024, 256, 0, stream>>>(sp0, sp0 + 3145728, nullptr, qb, 786432);
        // kva = h @ wkv_a^T   (N=576, K=2048)
        gemm_mfma3_k<<<dim3(5, 8), 256, 0, stream>>>(hh, hl, Wkva, WkvaL, sp0, 576, 2048, 0, 1024, prep, flag);
        gemm_mfma3_k<<<dim3(5, 8), 256, 0, stream>>>(hh, hl, Wkva, WkvaL, sp0 + 589824, 576, 2048, 1024, 1024, prep, flag);
        combine_k<0><<<1024, 256, 0, stream>>>(sp0, sp0 + 589824, nullptr, kva, 147456);
        rmsnorm_hl_k<<<TT, 256, 0, stream>>>(kva, kv_nw, kvnh, kvnl, 512, 576, flag);
        rope_k<<<TT, 256, 0, stream>>>(qb, kva, fcos, fsin, flag);
        // kvb = kvnorm @ wkv_b^T   (N=4096, K=512)
        gemm_mfma3_k<<<dim3(32, 8), 256, 0, stream>>>(kvnh, kvnl, Wkvb, WkvbL, kvb, 4096, 512, 0, 512, prep, flag);
        kvprep_k<<<dim3(16, 16), 256, 0, stream>>>(kvb, kva, kh, kl, vt);
        attn_mfma_k<<<dim3(TT / QBLK, 16), 256, 0, stream>>>(qb, kh, kl, vt, yb);

        // --- FFN MFMA bf16 GEMMs ---
        // x2 = xf + yb @ wo^T   (N=2048, K=2048, split-K=2)
        gemm_mfma_k<0><<<dim3(16, 8), 256, 0, stream>>>(yb, WoP, nullptr, fp0, 2048, 2048, 0, 1024, prep, flag);
        gemm_mfma_k<0><<<dim3(16, 8), 256, 0, stream>>>(yb, WoP, nullptr, fp1, 2048, 2048, 1024, 1024, prep, flag);
        combine_k<1><<<1024, 256, 0, stream>>>(fp0, fp1, xf, x2, 524288);
        rmsnorm_bf_k<<<TT, 256, 0, stream>>>(x2, ffn_nw, hb, 2048, flag);
        // gb = hb @ w1^T   (N=8192, K=2048)
        gemm_mfma_k<0><<<dim3(64, 8), 256, 0, stream>>>(hb, W1P, nullptr, gb, 8192, 2048, 0, 2048, prep, flag);
        // gb2 = bf16(silu(gb) * (hb @ w3^T))
        gemm_mfma_k<3><<<dim3(64, 8), 256, 0, stream>>>(hb, W3P, gb, gb2, 8192, 2048, 0, 2048, prep, flag);
        // outb = x2 + gb2 @ w2^T   (N=2048, K=8192, split-K=2)
        gemm_mfma_k<0><<<dim3(16, 8), 256, 0, stream>>>(gb2, W2P, nullptr, fp0, 2048, 8192, 0, 4096, prep, flag);
        gemm_mfma_k<0><<<dim3(16, 8), 256, 0, stream>>>(gb2, W2P, nullptr, fp1, 2048, 8192, 4096, 4096, prep, flag);
        combine_k<1><<<1024, 256, 0, stream>>>(fp0, fp1, x2, outb, 524288);
    }
}

// Round 6
// 1351.142 us; speedup vs baseline: 2.4961x; 1.4718x over previous
//
#include <hip/hip_runtime.h>
#include <hip/hip_bf16.h>
#include <cstddef>

// DeepSeekBlock: B=2 T=1024 D=2048 H=16 NOPE=128 ROPE=64 QKD=192
// QLORA=1536 KVLORA=512 VHD=128 INTER=8192
// Round 11 = round 10 resubmitted verbatim (round-10 bench died to an infra
// failure: "MI355X container failed twice"; no counters. Arena re-audited: all
// split-K partial windows are inside the 16M arena and race-free).
// Round 10: split-K as ONE launch via gridDim.z (round 9's two half-dispatches
// serialized on the stream -> each ran at 128 blocks / 5% occupancy). z-slice
// computes k in [z*klen,(z+1)*klen), writes partial at C + z*M*N; combine_k<S>
// sums S partials (+residual). Grids now 320-512 blocks (1.25-2 blocks/CU).
// Partial arenas: score [10M,16M); wo [5M,13M) (yb=[3.5M,4.5M) untouched); w2 [2M,10M).
// Weight prep + pipelined staging + MFMA flash attention unchanged from round 9.

#define TT 1024
#define DD 2048
#define QBLK 64
#define KVB 32

using bf16 = __hip_bfloat16;
typedef __attribute__((ext_vector_type(8))) short short8;
typedef __attribute__((ext_vector_type(8))) unsigned short ushort8v;
typedef __attribute__((ext_vector_type(4))) float f32x4;

__device__ __forceinline__ float us2f(unsigned short u) {
    return __uint_as_float(((unsigned int)u) << 16);
}
__device__ __forceinline__ float ldf(const void* p, size_t i, int isbf) {
    return isbf ? us2f(((const unsigned short*)p)[i]) : ((const float*)p)[i];
}
__device__ __forceinline__ unsigned short f2bf(float f) {
    __hip_bfloat16 b = __float2bfloat16(f);
    return *reinterpret_cast<unsigned short*>(&b);
}

// ---------------- input dtype detection ----------------
__global__ __launch_bounds__(64) void detect_k(const void* __restrict__ x,
                                               int* __restrict__ flag)
{
    __shared__ int cnt;
    if (threadIdx.x == 0) cnt = 0;
    __syncthreads();
    const unsigned short* u = (const unsigned short*)x;
    int bad = 0;
    for (int i = threadIdx.x; i < 512; i += 64) {
        const float v = us2f(u[i]);
        const float a = fabsf(v);
        if (!(a < 1e6f) || (v != 0.0f && a < 1e-30f)) bad++;
    }
    atomicAdd(&cnt, bad);
    __syncthreads();
    if (threadIdx.x == 0) *flag = (cnt > 32) ? 0 : 1;   // 0 = f32, 1 = bf16
}

// ---------------- weight prep: any -> bf16 ----------------
__global__ __launch_bounds__(256) void cvt_bf_k(
    const void* __restrict__ src, unsigned short* __restrict__ dst,
    size_t n, const int* __restrict__ flag)
{
    const int isbf = *flag;
    const size_t stride = (size_t)gridDim.x * 2048;
    for (size_t i = ((size_t)blockIdx.x * 256 + threadIdx.x) * 8; i < n; i += stride) {
        if (isbf) {
            *(ushort8v*)(dst + i) = *(const ushort8v*)((const unsigned short*)src + i);
        } else {
            const float* s = (const float*)src + i;
            float4 f0 = *(const float4*)s, f1 = *(const float4*)(s + 4);
            unsigned short t[8] = {f2bf(f0.x), f2bf(f0.y), f2bf(f0.z), f2bf(f0.w),
                                   f2bf(f1.x), f2bf(f1.y), f2bf(f1.z), f2bf(f1.w)};
            *(ushort8v*)(dst + i) = *(const ushort8v*)t;
        }
    }
}

// ---------------- weight prep: any -> hi/lo bf16 pair ----------------
__global__ __launch_bounds__(256) void cvt_hl_k(
    const void* __restrict__ src, unsigned short* __restrict__ dh,
    unsigned short* __restrict__ dl, size_t n, const int* __restrict__ flag)
{
    const int isbf = *flag;
    const size_t stride = (size_t)gridDim.x * 2048;
    for (size_t i = ((size_t)blockIdx.x * 256 + threadIdx.x) * 8; i < n; i += stride) {
        unsigned short th[8], tl[8];
        if (isbf) {
            const unsigned short* s = (const unsigned short*)src + i;
#pragma unroll
            for (int u = 0; u < 8; ++u) { th[u] = s[u]; tl[u] = 0; }
        } else {
            const float* s = (const float*)src + i;
#pragma unroll
            for (int u = 0; u < 8; ++u) {
                const float v = s[u];
                th[u] = f2bf(v);
                tl[u] = f2bf(v - us2f(th[u]));
            }
        }
        *(ushort8v*)(dh + i) = *(const ushort8v*)th;
        *(ushort8v*)(dl + i) = *(const ushort8v*)tl;
    }
}

// ---------------- split-K combine: out = sum_{s<S} p[s] (+ R) ----------------
// Partial s lives at p + s*n4 (float4 units).
template <int S, int HASR>
__global__ __launch_bounds__(256) void combine_k(
    const float* __restrict__ p, const float* __restrict__ R,
    float* __restrict__ out, int n4)
{
    const int stride = gridDim.x * 256;
    const float4* pp = (const float4*)p;
    for (int i = blockIdx.x * 256 + threadIdx.x; i < n4; i += stride) {
        float4 o = pp[i];
#pragma unroll
        for (int s = 1; s < S; ++s) {
            const float4 b4 = pp[(size_t)s * n4 + i];
            o.x += b4.x; o.y += b4.y; o.z += b4.z; o.w += b4.w;
        }
        if (HASR) {
            const float4 r4 = ((const float4*)R)[i];
            o.x += r4.x; o.y += r4.y; o.z += r4.z; o.w += r4.w;
        }
        ((float4*)out)[i] = o;
    }
}

// ---------------- rmsnorm f32 -> hi/lo bf16 pair ----------------
__global__ __launch_bounds__(256) void rmsnorm_hl_k(
    const float* __restrict__ in, const void* __restrict__ w,
    unsigned short* __restrict__ oh, unsigned short* __restrict__ ol,
    int L, int istride, const int* __restrict__ flag)
{
    const int isbf = *flag;
    const int m = blockIdx.x, tid = threadIdx.x;
    const float* row = in + (size_t)m * istride;
    float ss = 0.f;
    for (int i = tid; i < L; i += 256) { float v = row[i]; ss += v * v; }
    __shared__ float red[256];
    red[tid] = ss; __syncthreads();
    for (int s = 128; s > 0; s >>= 1) {
        if (tid < s) red[tid] += red[tid + s];
        __syncthreads();
    }
    const float scale = 1.0f / sqrtf(red[0] / (float)L + 1e-6f);
    unsigned short* hrow = oh + (size_t)m * L;
    unsigned short* lrow = ol + (size_t)m * L;
    for (int i = tid; i < L; i += 256) {
        const float v = row[i] * scale * ldf(w, i, isbf);
        const unsigned short hi = f2bf(v);
        hrow[i] = hi;
        lrow[i] = f2bf(v - us2f(hi));
    }
}

// ---------------- rmsnorm f32->bf16 (FFN input) ----------------
__global__ __launch_bounds__(256) void rmsnorm_bf_k(
    const float* __restrict__ in, const void* __restrict__ w,
    unsigned short* __restrict__ out, int L,
    const int* __restrict__ flag)
{
    const int isbf = *flag;
    const int m = blockIdx.x, tid = threadIdx.x;
    const float* row = in + (size_t)m * L;
    float ss = 0.f;
    for (int i = tid; i < L; i += 256) { float v = row[i]; ss += v * v; }
    __shared__ float red[256];
    red[tid] = ss; __syncthreads();
    for (int s = 128; s > 0; s >>= 1) {
        if (tid < s) red[tid] += red[tid + s];
        __syncthreads();
    }
    const float scale = 1.0f / sqrtf(red[0] / (float)L + 1e-6f);
    unsigned short* orow = out + (size_t)m * L;
    for (int i = tid; i < L; i += 256)
        orow[i] = f2bf(row[i] * scale * ldf(w, i, isbf));
}

// rmsnorm on input x: writes hi/lo bf16 h and f32 residual copy
__global__ __launch_bounds__(256) void rmsnorm_x_hl_k(
    const void* __restrict__ x, size_t eoff, const void* __restrict__ w,
    unsigned short* __restrict__ hh, unsigned short* __restrict__ hl,
    float* __restrict__ xf, const int* __restrict__ flag)
{
    const int isbf = *flag;
    const int m = blockIdx.x, tid = threadIdx.x;
    const size_t base = eoff + (size_t)m * DD;
    float* xrow = xf + (size_t)m * DD;
    float ss = 0.f;
    float vals[8];
    for (int i = 0; i < 8; ++i) {
        float v = ldf(x, base + tid + 256 * i, isbf);
        vals[i] = v; ss += v * v;
        xrow[tid + 256 * i] = v;
    }
    __shared__ float red[256];
    red[tid] = ss; __syncthreads();
    for (int s = 128; s > 0; s >>= 1) {
        if (tid < s) red[tid] += red[tid + s];
        __syncthreads();
    }
    const float scale = 1.0f / sqrtf(red[0] / (float)DD + 1e-6f);
    unsigned short* hrow = hh + (size_t)m * DD;
    unsigned short* lrow = hl + (size_t)m * DD;
    for (int i = 0; i < 8; ++i) {
        const float v = vals[i] * scale * ldf(w, tid + 256 * i, isbf);
        const unsigned short hi = f2bf(v);
        hrow[tid + 256 * i] = hi;
        lrow[tid + 256 * i] = f2bf(v - us2f(hi));
    }
}

// ---------------- split-bf16 MFMA GEMM: C(M,N) f32 = (Ah+Al)(Wh+Wl)^T ----------------
// presplit=1: Wv/Wlo are pre-split bf16 hi/lo; pipelined staging. presplit=0:
// W f32/bf16 per flag. Split-K via gridDim.z: slice z does k in [z*klen,(z+1)*klen)
// and writes partial at C + z*1024*N.
__global__ __launch_bounds__(256) void gemm_mfma3_k(
    const unsigned short* __restrict__ Ah, const unsigned short* __restrict__ Al,
    const void* __restrict__ Wv, const unsigned short* __restrict__ Wlo,
    float* __restrict__ C, int N, int K, int klen,
    int presplit, const int* __restrict__ flag)
{
    __shared__ unsigned short Ash[128 * 40];
    __shared__ unsigned short Asl[128 * 40];
    __shared__ unsigned short Wsh[128 * 40];
    __shared__ unsigned short Wsl[128 * 40];
    const int tid = threadIdx.x;
    const int lane = tid & 63;
    const int wave = tid >> 6;
    const int wm = (wave >> 1) << 6, wn = (wave & 1) << 6;
    const int bm = blockIdx.y << 7, bn = blockIdx.x << 7;
    const int k0 = blockIdx.z * klen;
    const size_t zoff = (size_t)blockIdx.z * 1024 * N;
    const int srow = tid >> 1, scol = (tid & 1) << 4;
    const unsigned short* Ahld = Ah + (size_t)(bm + srow) * K + scol;
    const unsigned short* Alld = Al + (size_t)(bm + srow) * K + scol;
    const int wrow = bn + srow;
    const size_t wldbase = (size_t)((wrow < N) ? wrow : (N - 1)) * K + scol;
    unsigned short* Ahdst = &Ash[srow * 40 + scol];
    unsigned short* Aldst = &Asl[srow * 40 + scol];
    unsigned short* Whdst = &Wsh[srow * 40 + scol];
    unsigned short* Wldst = &Wsl[srow * 40 + scol];
    const int frow = lane & 15;
    const int fk = (lane >> 4) << 3;
    const int kend = k0 + klen;

    f32x4 acc[4][4] = {};

    if (presplit) {
        const unsigned short* Whp = (const unsigned short*)Wv + wldbase;
        const unsigned short* Wlp = Wlo + wldbase;
        ushort8v ca0h = *(const ushort8v*)(Ahld + k0);
        ushort8v ca1h = *(const ushort8v*)(Ahld + k0 + 8);
        ushort8v ca0l = *(const ushort8v*)(Alld + k0);
        ushort8v ca1l = *(const ushort8v*)(Alld + k0 + 8);
        ushort8v cw0h = *(const ushort8v*)(Whp + k0);
        ushort8v cw1h = *(const ushort8v*)(Whp + k0 + 8);
        ushort8v cw0l = *(const ushort8v*)(Wlp + k0);
        ushort8v cw1l = *(const ushort8v*)(Wlp + k0 + 8);
        for (int kt = k0; kt < kend; kt += 32) {
            __syncthreads();
            *(ushort8v*)Ahdst = ca0h; *(ushort8v*)(Ahdst + 8) = ca1h;
            *(ushort8v*)Aldst = ca0l; *(ushort8v*)(Aldst + 8) = ca1l;
            *(ushort8v*)Whdst = cw0h; *(ushort8v*)(Whdst + 8) = cw1h;
            *(ushort8v*)Wldst = cw0l; *(ushort8v*)(Wldst + 8) = cw1l;
            __syncthreads();
            // issue next tile's loads AFTER the barrier: they fly during MFMA
            const int nk = (kt + 32 < kend) ? kt + 32 : kt;
            ca0h = *(const ushort8v*)(Ahld + nk);
            ca1h = *(const ushort8v*)(Ahld + nk + 8);
            ca0l = *(const ushort8v*)(Alld + nk);
            ca1l = *(const ushort8v*)(Alld + nk + 8);
            cw0h = *(const ushort8v*)(Whp + nk);
            cw1h = *(const ushort8v*)(Whp + nk + 8);
            cw0l = *(const ushort8v*)(Wlp + nk);
            cw1l = *(const ushort8v*)(Wlp + nk + 8);

            short8 afh[4], afl[4], bfh[4], bfl[4];
#pragma unroll
            for (int i = 0; i < 4; ++i) {
                afh[i] = *(const short8*)&Ash[(wm + i * 16 + frow) * 40 + fk];
                afl[i] = *(const short8*)&Asl[(wm + i * 16 + frow) * 40 + fk];
            }
#pragma unroll
            for (int j = 0; j < 4; ++j) {
                bfh[j] = *(const short8*)&Wsh[(wn + j * 16 + frow) * 40 + fk];
                bfl[j] = *(const short8*)&Wsl[(wn + j * 16 + frow) * 40 + fk];
            }
#pragma unroll
            for (int i = 0; i < 4; ++i)
#pragma unroll
                for (int j = 0; j < 4; ++j) {
                    acc[i][j] = __builtin_amdgcn_mfma_f32_16x16x32_bf16(
                        afh[i], bfh[j], acc[i][j], 0, 0, 0);
                    acc[i][j] = __builtin_amdgcn_mfma_f32_16x16x32_bf16(
                        afh[i], bfl[j], acc[i][j], 0, 0, 0);
                    acc[i][j] = __builtin_amdgcn_mfma_f32_16x16x32_bf16(
                        afl[i], bfh[j], acc[i][j], 0, 0, 0);
                }
        }
    } else {
        const int isbf = *flag;
        for (int kt = k0; kt < kend; kt += 32) {
            ushort8v a0h = *(const ushort8v*)(Ahld + kt);
            ushort8v a1h = *(const ushort8v*)(Ahld + kt + 8);
            ushort8v a0l = *(const ushort8v*)(Alld + kt);
            ushort8v a1l = *(const ushort8v*)(Alld + kt + 8);
            ushort8v w0h, w1h, w0l, w1l;
            if (isbf) {
                const unsigned short* Wp = (const unsigned short*)Wv + wldbase + kt;
                w0h = *(const ushort8v*)(Wp);
                w1h = *(const ushort8v*)(Wp + 8);
                w0l = w0h ^ w0h;
                w1l = w0l;
            } else {
                const float* Wp = (const float*)Wv + wldbase + kt;
                unsigned short th[16], tl[16];
#pragma unroll
                for (int t4 = 0; t4 < 4; ++t4) {
                    float4 f = *(const float4*)(Wp + 4 * t4);
                    float fv[4] = {f.x, f.y, f.z, f.w};
#pragma unroll
                    for (int u = 0; u < 4; ++u) {
                        const unsigned short hi = f2bf(fv[u]);
                        th[4 * t4 + u] = hi;
                        tl[4 * t4 + u] = f2bf(fv[u] - us2f(hi));
                    }
                }
                w0h = *(ushort8v*)&th[0]; w1h = *(ushort8v*)&th[8];
                w0l = *(ushort8v*)&tl[0]; w1l = *(ushort8v*)&tl[8];
            }
            __syncthreads();
            *(ushort8v*)Ahdst = a0h; *(ushort8v*)(Ahdst + 8) = a1h;
            *(ushort8v*)Aldst = a0l; *(ushort8v*)(Aldst + 8) = a1l;
            *(ushort8v*)Whdst = w0h; *(ushort8v*)(Whdst + 8) = w1h;
            *(ushort8v*)Wldst = w0l; *(ushort8v*)(Wldst + 8) = w1l;
            __syncthreads();

            short8 afh[4], afl[4], bfh[4], bfl[4];
#pragma unroll
            for (int i = 0; i < 4; ++i) {
                afh[i] = *(const short8*)&Ash[(wm + i * 16 + frow) * 40 + fk];
                afl[i] = *(const short8*)&Asl[(wm + i * 16 + frow) * 40 + fk];
            }
#pragma unroll
            for (int j = 0; j < 4; ++j) {
                bfh[j] = *(const short8*)&Wsh[(wn + j * 16 + frow) * 40 + fk];
                bfl[j] = *(const short8*)&Wsl[(wn + j * 16 + frow) * 40 + fk];
            }
#pragma unroll
            for (int i = 0; i < 4; ++i)
#pragma unroll
                for (int j = 0; j < 4; ++j) {
                    acc[i][j] = __builtin_amdgcn_mfma_f32_16x16x32_bf16(
                        afh[i], bfh[j], acc[i][j], 0, 0, 0);
                    acc[i][j] = __builtin_amdgcn_mfma_f32_16x16x32_bf16(
                        afh[i], bfl[j], acc[i][j], 0, 0, 0);
                    acc[i][j] = __builtin_amdgcn_mfma_f32_16x16x32_bf16(
                        afl[i], bfh[j], acc[i][j], 0, 0, 0);
                }
        }
    }

#pragma unroll
    for (int i = 0; i < 4; ++i) {
        const int r0 = bm + wm + i * 16 + ((lane >> 4) << 2);
#pragma unroll
        for (int j = 0; j < 4; ++j) {
            const int c = bn + wn + j * 16 + (lane & 15);
            if (c < N) {
#pragma unroll
                for (int g = 0; g < 4; ++g)
                    C[zoff + (size_t)(r0 + g) * N + c] = acc[i][j][g];
            }
        }
    }
}

// ---------------- bf16 MFMA GEMM (FFN path) ----------------
// wready=1: W is bf16; pipelined staging. Split-K via gridDim.z (partial at
// outp + z*1024*N; use EPI=0 for split launches). EPI 0: f32 C = acc;
// EPI 1: f32 C = R + acc; EPI 3: bf16 C = bf16(silu(R) * acc).
template <int EPI>
__global__ __launch_bounds__(256) void gemm_mfma_k(
    const unsigned short* __restrict__ A, const void* __restrict__ Wv,
    const float* __restrict__ R, void* __restrict__ outp,
    int N, int K, int klen, int wready, const int* __restrict__ flag)
{
    __shared__ unsigned short As[128 * 40];
    __shared__ unsigned short Ws[128 * 40];
    const int tid = threadIdx.x;
    const int lane = tid & 63;
    const int wave = tid >> 6;
    const int wm = (wave >> 1) << 6, wn = (wave & 1) << 6;
    const int bm = blockIdx.y << 7, bn = blockIdx.x << 7;
    const int k0 = blockIdx.z * klen;
    const size_t zoff = (size_t)blockIdx.z * 1024 * N;
    const int srow = tid >> 1, scol = (tid & 1) << 4;
    const unsigned short* Ald = A + (size_t)(bm + srow) * K + scol;
    const size_t wldbase = (size_t)(bn + srow) * K + scol;
    unsigned short* Adst = &As[srow * 40 + scol];
    unsigned short* Wdst = &Ws[srow * 40 + scol];
    const int frow = lane & 15;
    const int fk = (lane >> 4) << 3;
    const int kend = k0 + klen;

    f32x4 acc[4][4] = {};

    if (wready) {
        const unsigned short* Wp = (const unsigned short*)Wv + wldbase;
        ushort8v ca0 = *(const ushort8v*)(Ald + k0);
        ushort8v ca1 = *(const ushort8v*)(Ald + k0 + 8);
        ushort8v cw0 = *(const ushort8v*)(Wp + k0);
        ushort8v cw1 = *(const ushort8v*)(Wp + k0 + 8);
        for (int kt = k0; kt < kend; kt += 32) {
            __syncthreads();
            *(ushort8v*)Adst = ca0; *(ushort8v*)(Adst + 8) = ca1;
            *(ushort8v*)Wdst = cw0; *(ushort8v*)(Wdst + 8) = cw1;
            __syncthreads();
            const int nk = (kt + 32 < kend) ? kt + 32 : kt;
            ca0 = *(const ushort8v*)(Ald + nk);
            ca1 = *(const ushort8v*)(Ald + nk + 8);
            cw0 = *(const ushort8v*)(Wp + nk);
            cw1 = *(const ushort8v*)(Wp + nk + 8);

            short8 af[4], bfr[4];
#pragma unroll
            for (int i = 0; i < 4; ++i)
                af[i] = *(const short8*)&As[(wm + i * 16 + frow) * 40 + fk];
#pragma unroll
            for (int j = 0; j < 4; ++j)
                bfr[j] = *(const short8*)&Ws[(wn + j * 16 + frow) * 40 + fk];
#pragma unroll
            for (int i = 0; i < 4; ++i)
#pragma unroll
                for (int j = 0; j < 4; ++j)
                    acc[i][j] = __builtin_amdgcn_mfma_f32_16x16x32_bf16(
                        af[i], bfr[j], acc[i][j], 0, 0, 0);
        }
    } else {
        const int isbf = *flag;
        for (int kt = k0; kt < kend; kt += 32) {
            ushort8v a0 = *(const ushort8v*)(Ald + kt);
            ushort8v a1 = *(const ushort8v*)(Ald + kt + 8);
            ushort8v w0, w1;
            if (isbf) {
                const unsigned short* Wp = (const unsigned short*)Wv + wldbase + kt;
                w0 = *(const ushort8v*)(Wp);
                w1 = *(const ushort8v*)(Wp + 8);
            } else {
                const float* Wp = (const float*)Wv + wldbase + kt;
                float4 f0 = *(const float4*)(Wp);
                float4 f1 = *(const float4*)(Wp + 4);
                float4 f2 = *(const float4*)(Wp + 8);
                float4 f3 = *(const float4*)(Wp + 12);
                unsigned short wt[16];
                wt[0] = f2bf(f0.x); wt[1] = f2bf(f0.y); wt[2]  = f2bf(f0.z); wt[3]  = f2bf(f0.w);
                wt[4] = f2bf(f1.x); wt[5] = f2bf(f1.y); wt[6]  = f2bf(f1.z); wt[7]  = f2bf(f1.w);
                wt[8] = f2bf(f2.x); wt[9] = f2bf(f2.y); wt[10] = f2bf(f2.z); wt[11] = f2bf(f2.w);
                wt[12] = f2bf(f3.x); wt[13] = f2bf(f3.y); wt[14] = f2bf(f3.z); wt[15] = f2bf(f3.w);
                w0 = *(const ushort8v*)&wt[0];
                w1 = *(const ushort8v*)&wt[8];
            }
            __syncthreads();
            *(ushort8v*)Adst = a0; *(ushort8v*)(Adst + 8) = a1;
            *(ushort8v*)Wdst = w0; *(ushort8v*)(Wdst + 8) = w1;
            __syncthreads();

            short8 af[4], bfr[4];
#pragma unroll
            for (int i = 0; i < 4; ++i)
                af[i] = *(const short8*)&As[(wm + i * 16 + frow) * 40 + fk];
#pragma unroll
            for (int j = 0; j < 4; ++j)
                bfr[j] = *(const short8*)&Ws[(wn + j * 16 + frow) * 40 + fk];
#pragma unroll
            for (int i = 0; i < 4; ++i)
#pragma unroll
                for (int j = 0; j < 4; ++j)
                    acc[i][j] = __builtin_amdgcn_mfma_f32_16x16x32_bf16(
                        af[i], bfr[j], acc[i][j], 0, 0, 0);
        }
    }

#pragma unroll
    for (int i = 0; i < 4; ++i) {
        const int r0 = bm + wm + i * 16 + ((lane >> 4) << 2);
#pragma unroll
        for (int j = 0; j < 4; ++j) {
            const int c = bn + wn + j * 16 + (lane & 15);
#pragma unroll
            for (int g = 0; g < 4; ++g) {
                const size_t idx = zoff + (size_t)(r0 + g) * N + c;
                const float v = acc[i][j][g];
                if (EPI == 0) {
                    ((float*)outp)[idx] = v;
                } else if (EPI == 1) {
                    ((float*)outp)[idx] = v + R[idx];
                } else {
                    const float gv = R[idx];
                    const float sg = 1.0f / (1.0f + __expf(-gv));
                    ((unsigned short*)outp)[idx] = f2bf(gv * sg * v);
                }
            }
        }
    }
}

// ---------------- RoPE (interleaved pairs), in-place on q and k_pe ----------------
__global__ __launch_bounds__(256) void rope_k(
    float* __restrict__ qb, float* __restrict__ kva,
    const void* __restrict__ fc, const void* __restrict__ fs,
    const int* __restrict__ flag)
{
    const int isbf = *flag;
    const int t = blockIdx.x;
    const int tid = threadIdx.x;
    __shared__ float c[32], s[32];
    if (tid < 32) {
        c[tid] = ldf(fc, t * 32 + tid, isbf);
        s[tid] = ldf(fs, t * 32 + tid, isbf);
    }
    __syncthreads();
    for (int p = tid; p < 512; p += 256) {
        const int h = p >> 5, i = p & 31;
        float* base = qb + (size_t)t * 3072 + h * 192 + 128 + 2 * i;
        const float x0 = base[0], x1 = base[1];
        base[0] = x0 * c[i] - x1 * s[i];
        base[1] = x0 * s[i] + x1 * c[i];
    }
    if (tid < 32) {
        float* base = kva + (size_t)t * 576 + 512 + 2 * tid;
        const float x0 = base[0], x1 = base[1];
        base[0] = x0 * c[tid] - x1 * s[tid];
        base[1] = x0 * s[tid] + x1 * c[tid];
    }
}

// ---------------- KV prep: split K to hi/lo bf16 [h][t][192], transpose V ----------------
__global__ __launch_bounds__(256) void kvprep_k(
    const float* __restrict__ kvb,   // [1024][4096]
    const float* __restrict__ kva,   // [1024][576]
    unsigned short* __restrict__ kh, unsigned short* __restrict__ kl,
    unsigned short* __restrict__ vt)
{
    const int tt = blockIdx.x, h = blockIdx.y;
    const int tid = threadIdx.x;
    const int tbase = tt * 64;
    for (int i = tid; i < 64 * 192; i += 256) {
        const int t = i / 192, k = i % 192;
        const float v = (k < 128)
            ? kvb[(size_t)(tbase + t) * 4096 + h * 256 + k]
            : kva[(size_t)(tbase + t) * 576 + 512 + (k - 128)];
        const unsigned short hi = f2bf(v);
        const size_t o = ((size_t)h * 1024 + tbase + t) * 192 + k;
        kh[o] = hi;
        kl[o] = f2bf(v - us2f(hi));
    }
    __shared__ unsigned short Vl[128][72];
    for (int i = tid; i < 64 * 128; i += 256) {
        const int t = i >> 7, d = i & 127;
        Vl[d][t] = f2bf(kvb[(size_t)(tbase + t) * 4096 + h * 256 + 128 + d]);
    }
    __syncthreads();
    for (int i = tid; i < 128 * 64; i += 256) {
        const int d = i >> 6, t = i & 63;
        vt[((size_t)h * 128 + d) * 1024 + tbase + t] = Vl[d][t];
    }
}

// ---------------- MFMA flash attention ----------------
__global__ __launch_bounds__(256) void attn_mfma_k(
    const float* __restrict__ qb,
    const unsigned short* __restrict__ kh,
    const unsigned short* __restrict__ kl,
    const unsigned short* __restrict__ vt,
    unsigned short* __restrict__ y)
{
    const int qt = blockIdx.x, h = blockIdx.y;
    const int s0 = qt * QBLK;
    const int tid = threadIdx.x;
    const int lane = tid & 63, wave = tid >> 6;
    const int frow = lane & 15;
    const int fk8 = (lane >> 4) << 3;
    const int g4 = (lane >> 4) << 2;

    __shared__ __align__(16) unsigned short Ksh[KVB][200];
    __shared__ __align__(16) unsigned short Ksl[KVB][200];
    __shared__ __align__(16) unsigned short Vs[128][40];
    __shared__ __align__(16) unsigned short Ps[4][16][40];

    const int wrow0 = s0 + wave * 16;
    short8 qhf[6], qlf[6];
    {
        const float* qrow = qb + (size_t)(wrow0 + frow) * 3072 + h * 192 + fk8;
#pragma unroll
        for (int ks = 0; ks < 6; ++ks) {
            float4 f0 = *(const float4*)(qrow + ks * 32);
            float4 f1 = *(const float4*)(qrow + ks * 32 + 4);
            float fv[8] = {f0.x, f0.y, f0.z, f0.w, f1.x, f1.y, f1.z, f1.w};
            unsigned short th[8], tl[8];
#pragma unroll
            for (int u = 0; u < 8; ++u) {
                th[u] = f2bf(fv[u]);
                tl[u] = f2bf(fv[u] - us2f(th[u]));
            }
            qhf[ks] = *(short8*)th;
            qlf[ks] = *(short8*)tl;
        }
    }

    f32x4 O[8] = {};
    float m_run[4] = {-1e30f, -1e30f, -1e30f, -1e30f};
    float l_run[4] = {};

    const int ntiles = (s0 + QBLK) / KVB;
    for (int tt = 0; tt < ntiles; ++tt) {
        const int t0 = tt * KVB;
        __syncthreads();
        for (int i = tid; i < KVB * 24; i += 256) {
            const int r = i / 24, c = (i % 24) * 8;
            const size_t gof = ((size_t)h * 1024 + t0 + r) * 192 + c;
            *(ushort8v*)&Ksh[r][c] = *(const ushort8v*)(kh + gof);
            *(ushort8v*)&Ksl[r][c] = *(const ushort8v*)(kl + gof);
        }
        for (int i = tid; i < 128 * 4; i += 256) {
            const int d = i >> 2, c = (i & 3) * 8;
            *(ushort8v*)&Vs[d][c] =
                *(const ushort8v*)(vt + ((size_t)h * 128 + d) * 1024 + t0 + c);
        }
        __syncthreads();

        const bool active = (t0 <= wrow0 + 15);
        if (active) {
            f32x4 s[2] = {};
#pragma unroll
            for (int j = 0; j < 2; ++j) {
                const unsigned short* kb = &Ksh[j * 16 + frow][fk8];
                const unsigned short* lb = &Ksl[j * 16 + frow][fk8];
#pragma unroll
                for (int ks = 0; ks < 6; ++ks) {
                    short8 bh = *(const short8*)(kb + ks * 32);
                    short8 bl = *(const short8*)(lb + ks * 32);
                    s[j] = __builtin_amdgcn_mfma_f32_16x16x32_bf16(qhf[ks], bh, s[j], 0, 0, 0);
                    s[j] = __builtin_amdgcn_mfma_f32_16x16x32_bf16(qhf[ks], bl, s[j], 0, 0, 0);
                    s[j] = __builtin_amdgcn_mfma_f32_16x16x32_bf16(qlf[ks], bh, s[j], 0, 0, 0);
                }
            }
            const bool edge = (t0 + KVB - 1 > wrow0);
            float sv[2][4];
#pragma unroll
            for (int j = 0; j < 2; ++j)
#pragma unroll
                for (int g = 0; g < 4; ++g) {
                    float v = s[j][g] * -96.0f;
                    if (edge) {
                        const int col = t0 + j * 16 + frow;
                        const int row = wrow0 + g4 + g;
                        if (col > row) v = -1e30f;
                    }
                    sv[j][g] = v;
                }
            float alpha[4];
#pragma unroll
            for (int g = 0; g < 4; ++g) {
                float mt = fmaxf(sv[0][g], sv[1][g]);
                mt = fmaxf(mt, __shfl_xor(mt, 1));
                mt = fmaxf(mt, __shfl_xor(mt, 2));
                mt = fmaxf(mt, __shfl_xor(mt, 4));
                mt = fmaxf(mt, __shfl_xor(mt, 8));
                const float mn = fmaxf(m_run[g], mt);
                alpha[g] = __expf(m_run[g] - mn);
                m_run[g] = mn;
                const float p0 = __expf(sv[0][g] - mn);
                const float p1 = __expf(sv[1][g] - mn);
                sv[0][g] = p0; sv[1][g] = p1;
                float ps = p0 + p1;
                ps += __shfl_xor(ps, 1);
                ps += __shfl_xor(ps, 2);
                ps += __shfl_xor(ps, 4);
                ps += __shfl_xor(ps, 8);
                l_run[g] = l_run[g] * alpha[g] + ps;
            }
#pragma unroll
            for (int jt = 0; jt < 8; ++jt)
#pragma unroll
                for (int g = 0; g < 4; ++g)
                    O[jt][g] *= alpha[g];
#pragma unroll
            for (int j = 0; j < 2; ++j)
#pragma unroll
                for (int g = 0; g < 4; ++g)
                    Ps[wave][g4 + g][j * 16 + frow] = f2bf(sv[j][g]);
        }
        __syncthreads();
        if (active) {
            short8 pa = *(const short8*)&Ps[wave][frow][fk8];
#pragma unroll
            for (int jt = 0; jt < 8; ++jt) {
                short8 vb = *(const short8*)&Vs[jt * 16 + frow][fk8];
                O[jt] = __builtin_amdgcn_mfma_f32_16x16x32_bf16(pa, vb, O[jt], 0, 0, 0);
            }
        }
    }

#pragma unroll
    for (int g = 0; g < 4; ++g) {
        const float invl = 1.0f / l_run[g];
        const int row = wrow0 + g4 + g;
        unsigned short* yo = y + (size_t)row * 2048 + h * 128;
#pragma unroll
        for (int jt = 0; jt < 8; ++jt)
            yo[jt * 16 + frow] = f2bf(O[jt][g] * invl);
    }
}

extern "C" void kernel_launch(void* const* d_in, const int* in_sizes, int n_in,
                              void* d_out, int out_size, void* d_ws, size_t ws_size,
                              hipStream_t stream) {
    (void)in_sizes; (void)n_in; (void)out_size;
    const void* x       = d_in[0];
    const void* fcos    = d_in[2];
    const void* fsin    = d_in[3];
    const void* attn_nw = d_in[4];
    const void* wq_a    = d_in[5];
    const void* q_nw    = d_in[6];
    const void* wq_b    = d_in[7];
    const void* wkv_a   = d_in[8];
    const void* kv_nw   = d_in[9];
    const void* wkv_b   = d_in[10];
    const void* wo      = d_in[11];
    const void* ffn_nw  = d_in[12];
    const void* w1      = d_in[13];
    const void* w2      = d_in[14];
    const void* w3      = d_in[15];

    int* flag = (int*)d_ws;
    float* a  = (float*)d_ws + 64;
    const size_t M1 = 1048576;
    // Arena (float units), peak 16M floats = 64 MiB:
    float* xf  = a;                                               // [0,2M) f32 residual
    unsigned short* hh = (unsigned short*)(a + 2 * M1);           // [2M,3M)
    unsigned short* hl = (unsigned short*)(a + 3 * M1);           // [3M,4M)
    float* qa  = a + 4 * M1;                                      // [4M,5.5M)
    float* kva = a + 4 * M1;                                      // [4M,4.5625M) (qa dead)
    unsigned short* kvnh = (unsigned short*)(a + 4 * M1 + 655360);
    unsigned short* kvnl = (unsigned short*)(a + 4 * M1 + 655360 + 262144);
    unsigned short* qah = (unsigned short*)(a + 5 * M1 + 524288); // [5.5M,6.25M)
    unsigned short* qal = (unsigned short*)(a + 6 * M1 + 262144); // [6.25M,7M)
    float* qb  = a + 7 * M1;                                      // [7M,10M)
    float* kvb = a + 10 * M1;                                     // [10M,14M)
    unsigned short* kh = (unsigned short*)(a + 2 * M1);           // [2M,3.5M)
    unsigned short* kl = (unsigned short*)(a + 5 * M1 + 524288);  // [5.5M,7M)
    unsigned short* vt = (unsigned short*)(a + 14 * M1);          // [14M,15M)
    unsigned short* yb = (unsigned short*)(a + 3 * M1 + 524288);  // [3.5M,4.5M) !
    unsigned short* hb  = (unsigned short*)(a + 2 * M1);          // [2M,3M)
    float* gb  = a + 4 * M1;                                      // [4M,12M)
    unsigned short* gb2 = (unsigned short*)(a + 12 * M1);         // [12M,16M)
    float* x2  = xf;
    // Split-K partial arenas (stride = M*N floats per slice):
    float* sp  = a + 10 * M1;   // score path: wq_a 4x1.5M=[10M,16M); wq_b 2x3M; wkv_a 8x0.5625M
    float* fpo = a + 5 * M1;    // wo: 4x2M = [5M,13M)  (yb [3.5M,4.5M) untouched)
    float* fp2 = a + 2 * M1;    // w2: 4x2M = [2M,10M)  (hb/gb dead by then)
    // Prepared weights (beyond 16M; only if ws_size allows):
    unsigned short* wo_b  = (unsigned short*)(a + 16 * M1);       // 4M us
    unsigned short* w1_b  = (unsigned short*)(a + 18 * M1);       // 16M us
    unsigned short* w3_b  = (unsigned short*)(a + 26 * M1);       // 16M us
    unsigned short* w2_b  = (unsigned short*)(a + 34 * M1);       // 16M us
    unsigned short* wqa_h = (unsigned short*)(a + 42 * M1);
    unsigned short* wqa_l = wqa_h + 3145728u;
    unsigned short* wqb_h = (unsigned short*)(a + 45 * M1);
    unsigned short* wqb_l = wqb_h + 4718592u;
    unsigned short* wkva_h = (unsigned short*)(a + 49 * M1 + 524288);
    unsigned short* wkva_l = wkva_h + 1179648u;
    unsigned short* wkvb_h = (unsigned short*)(a + 50 * M1 + 655360);
    unsigned short* wkvb_l = wkvb_h + 2097152u;
    const size_t NEED = 256 + (size_t)(52 * M1 + 655360) * 4;     // ~220.7 MB
    const int prep = (ws_size >= NEED) ? 1 : 0;

    detect_k<<<1, 64, 0, stream>>>(x, flag);

    if (prep) {
        cvt_bf_k<<<1024, 256, 0, stream>>>(wo, wo_b, (size_t)2048 * 2048, flag);
        cvt_bf_k<<<2048, 256, 0, stream>>>(w1, w1_b, (size_t)8192 * 2048, flag);
        cvt_bf_k<<<2048, 256, 0, stream>>>(w3, w3_b, (size_t)8192 * 2048, flag);
        cvt_bf_k<<<2048, 256, 0, stream>>>(w2, w2_b, (size_t)2048 * 8192, flag);
        cvt_hl_k<<<1024, 256, 0, stream>>>(wq_a, wqa_h, wqa_l, (size_t)1536 * 2048, flag);
        cvt_hl_k<<<1024, 256, 0, stream>>>(wq_b, wqb_h, wqb_l, (size_t)3072 * 1536, flag);
        cvt_hl_k<<<512, 256, 0, stream>>>(wkv_a, wkva_h, wkva_l, (size_t)576 * 2048, flag);
        cvt_hl_k<<<1024, 256, 0, stream>>>(wkv_b, wkvb_h, wkvb_l, (size_t)4096 * 512, flag);
    }
    const void* Wqa = prep ? (const void*)wqa_h : wq_a;
    const void* Wqb = prep ? (const void*)wqb_h : wq_b;
    const void* Wkva = prep ? (const void*)wkva_h : wkv_a;
    const void* Wkvb = prep ? (const void*)wkvb_h : wkv_b;
    const unsigned short* WqaL = prep ? wqa_l : nullptr;
    const unsigned short* WqbL = prep ? wqb_l : nullptr;
    const unsigned short* WkvaL = prep ? wkva_l : nullptr;
    const unsigned short* WkvbL = prep ? wkvb_l : nullptr;
    const void* WoP = prep ? (const void*)wo_b : wo;
    const void* W1P = prep ? (const void*)w1_b : w1;
    const void* W3P = prep ? (const void*)w3_b : w3;
    const void* W2P = prep ? (const void*)w2_b : w2;

    for (int b = 0; b < 2; ++b) {
        const size_t eoff = (size_t)b * TT * DD;
        float* outb = (float*)d_out + eoff;

        // --- attention path (split-bf16 MFMA score chain, single-launch split-K) ---
        rmsnorm_x_hl_k<<<TT, 256, 0, stream>>>(x, eoff, attn_nw, hh, hl, xf, flag);
        // qa = rms(h) @ wq_a^T   (N=1536, K=2048, S=4 -> 384 blocks)
        gemm_mfma3_k<<<dim3(12, 8, 4), 256, 0, stream>>>(hh, hl, Wqa, WqaL, sp, 1536, 2048, 512, prep, flag);
        combine_k<4, 0><<<1024, 256, 0, stream>>>(sp, nullptr, qa, 393216);
        rmsnorm_hl_k<<<TT, 256, 0, stream>>>(qa, q_nw, qah, qal, 1536, 1536, flag);
        // qb = q @ wq_b^T   (N=3072, K=1536, S=2 -> 384 blocks)
        gemm_mfma3_k<<<dim3(24, 8, 2), 256, 0, stream>>>(qah, qal, Wqb, WqbL, sp, 3072, 1536, 768, prep, flag);
        combine_k<2, 0><<<1024, 256, 0, stream>>>(sp, nullptr, qb, 786432);
        // kva = h @ wkv_a^T   (N=576, K=2048, S=8 -> 320 blocks)
        gemm_mfma3_k<<<dim3(5, 8, 8), 256, 0, stream>>>(hh, hl, Wkva, WkvaL, sp, 576, 2048, 256, prep, flag);
        combine_k<8, 0><<<1024, 256, 0, stream>>>(sp, nullptr, kva, 147456);
        rmsnorm_hl_k<<<TT, 256, 0, stream>>>(kva, kv_nw, kvnh, kvnl, 512, 576, flag);
        rope_k<<<TT, 256, 0, stream>>>(qb, kva, fcos, fsin, flag);
        // kvb = kvnorm @ wkv_b^T   (N=4096, K=512, 256 blocks)
        gemm_mfma3_k<<<dim3(32, 8, 1), 256, 0, stream>>>(kvnh, kvnl, Wkvb, WkvbL, kvb, 4096, 512, 512, prep, flag);
        kvprep_k<<<dim3(16, 16), 256, 0, stream>>>(kvb, kva, kh, kl, vt);
        attn_mfma_k<<<dim3(TT / QBLK, 16), 256, 0, stream>>>(qb, kh, kl, vt, yb);

        // --- FFN MFMA bf16 GEMMs ---
        // x2 = xf + yb @ wo^T   (N=2048, K=2048, S=4 -> 512 blocks)
        gemm_mfma_k<0><<<dim3(16, 8, 4), 256, 0, stream>>>(yb, WoP, nullptr, fpo, 2048, 2048, 512, prep, flag);
        combine_k<4, 1><<<1024, 256, 0, stream>>>(fpo, xf, x2, 524288);
        rmsnorm_bf_k<<<TT, 256, 0, stream>>>(x2, ffn_nw, hb, 2048, flag);
        // gb = hb @ w1^T   (N=8192, K=2048, 512 blocks)
        gemm_mfma_k<0><<<dim3(64, 8, 1), 256, 0, stream>>>(hb, W1P, nullptr, gb, 8192, 2048, 2048, prep, flag);
        // gb2 = bf16(silu(gb) * (hb @ w3^T))
        gemm_mfma_k<3><<<dim3(64, 8, 1), 256, 0, stream>>>(hb, W3P, gb, gb2, 8192, 2048, 2048, prep, flag);
        // outb = x2 + gb2 @ w2^T   (N=2048, K=8192, S=4 -> 512 blocks)
        gemm_mfma_k<0><<<dim3(16, 8, 4), 256, 0, stream>>>(gb2, W2P, nullptr, fp2, 2048, 8192, 2048, prep, flag);
        combine_k<4, 1><<<1024, 256, 0, stream>>>(fp2, x2, outb, 524288);
    }
}

// Round 7
// 1344.512 us; speedup vs baseline: 2.5084x; 1.0049x over previous
//
#include <hip/hip_runtime.h>
#include <hip/hip_bf16.h>
#include <cstddef>

// DeepSeekBlock: B=2 T=1024 D=2048 H=16 NOPE=128 ROPE=64 QKD=192
// QLORA=1536 KVLORA=512 VHD=128 INTER=8192
// Round 12 (on passing round-11 @1351us):
//  - Attention: flash split-KV via blockIdx.z (2 slices of (qt+1) KV tiles each).
//    Each slice writes unnormalized partial (O bf16, m, l) to opart [10M,14M);
//    attn_merge_k combines (online-softmax merge) -> yb. Grid 256->512 blocks,
//    critical path halves (qt=15: 32->16 tiles).
//  - w1+w3 fused into gemm_swiglu_k: stage A once + both W tiles (61KB LDS,
//    2 blocks/CU), 32 MFMA/k-step/wave, epilogue bf16(silu(acc1)*acc3) -> gb2.
//    Deletes the 64MB gb f32 round-trip.
// Everything else = round 11 (single-launch split-K, weight prep, MFMA flash).

#define TT 1024
#define DD 2048
#define QBLK 64
#define KVB 32

using bf16 = __hip_bfloat16;
typedef __attribute__((ext_vector_type(8))) short short8;
typedef __attribute__((ext_vector_type(8))) unsigned short ushort8v;
typedef __attribute__((ext_vector_type(4))) float f32x4;

__device__ __forceinline__ float us2f(unsigned short u) {
    return __uint_as_float(((unsigned int)u) << 16);
}
__device__ __forceinline__ float ldf(const void* p, size_t i, int isbf) {
    return isbf ? us2f(((const unsigned short*)p)[i]) : ((const float*)p)[i];
}
__device__ __forceinline__ unsigned short f2bf(float f) {
    __hip_bfloat16 b = __float2bfloat16(f);
    return *reinterpret_cast<unsigned short*>(&b);
}

// ---------------- input dtype detection ----------------
__global__ __launch_bounds__(64) void detect_k(const void* __restrict__ x,
                                               int* __restrict__ flag)
{
    __shared__ int cnt;
    if (threadIdx.x == 0) cnt = 0;
    __syncthreads();
    const unsigned short* u = (const unsigned short*)x;
    int bad = 0;
    for (int i = threadIdx.x; i < 512; i += 64) {
        const float v = us2f(u[i]);
        const float a = fabsf(v);
        if (!(a < 1e6f) || (v != 0.0f && a < 1e-30f)) bad++;
    }
    atomicAdd(&cnt, bad);
    __syncthreads();
    if (threadIdx.x == 0) *flag = (cnt > 32) ? 0 : 1;   // 0 = f32, 1 = bf16
}

// ---------------- weight prep: any -> bf16 ----------------
__global__ __launch_bounds__(256) void cvt_bf_k(
    const void* __restrict__ src, unsigned short* __restrict__ dst,
    size_t n, const int* __restrict__ flag)
{
    const int isbf = *flag;
    const size_t stride = (size_t)gridDim.x * 2048;
    for (size_t i = ((size_t)blockIdx.x * 256 + threadIdx.x) * 8; i < n; i += stride) {
        if (isbf) {
            *(ushort8v*)(dst + i) = *(const ushort8v*)((const unsigned short*)src + i);
        } else {
            const float* s = (const float*)src + i;
            float4 f0 = *(const float4*)s, f1 = *(const float4*)(s + 4);
            unsigned short t[8] = {f2bf(f0.x), f2bf(f0.y), f2bf(f0.z), f2bf(f0.w),
                                   f2bf(f1.x), f2bf(f1.y), f2bf(f1.z), f2bf(f1.w)};
            *(ushort8v*)(dst + i) = *(const ushort8v*)t;
        }
    }
}

// ---------------- weight prep: any -> hi/lo bf16 pair ----------------
__global__ __launch_bounds__(256) void cvt_hl_k(
    const void* __restrict__ src, unsigned short* __restrict__ dh,
    unsigned short* __restrict__ dl, size_t n, const int* __restrict__ flag)
{
    const int isbf = *flag;
    const size_t stride = (size_t)gridDim.x * 2048;
    for (size_t i = ((size_t)blockIdx.x * 256 + threadIdx.x) * 8; i < n; i += stride) {
        unsigned short th[8], tl[8];
        if (isbf) {
            const unsigned short* s = (const unsigned short*)src + i;
#pragma unroll
            for (int u = 0; u < 8; ++u) { th[u] = s[u]; tl[u] = 0; }
        } else {
            const float* s = (const float*)src + i;
#pragma unroll
            for (int u = 0; u < 8; ++u) {
                const float v = s[u];
                th[u] = f2bf(v);
                tl[u] = f2bf(v - us2f(th[u]));
            }
        }
        *(ushort8v*)(dh + i) = *(const ushort8v*)th;
        *(ushort8v*)(dl + i) = *(const ushort8v*)tl;
    }
}

// ---------------- split-K combine: out = sum_{s<S} p[s] (+ R) ----------------
template <int S, int HASR>
__global__ __launch_bounds__(256) void combine_k(
    const float* __restrict__ p, const float* __restrict__ R,
    float* __restrict__ out, int n4)
{
    const int stride = gridDim.x * 256;
    const float4* pp = (const float4*)p;
    for (int i = blockIdx.x * 256 + threadIdx.x; i < n4; i += stride) {
        float4 o = pp[i];
#pragma unroll
        for (int s = 1; s < S; ++s) {
            const float4 b4 = pp[(size_t)s * n4 + i];
            o.x += b4.x; o.y += b4.y; o.z += b4.z; o.w += b4.w;
        }
        if (HASR) {
            const float4 r4 = ((const float4*)R)[i];
            o.x += r4.x; o.y += r4.y; o.z += r4.z; o.w += r4.w;
        }
        ((float4*)out)[i] = o;
    }
}

// ---------------- rmsnorm f32 -> hi/lo bf16 pair ----------------
__global__ __launch_bounds__(256) void rmsnorm_hl_k(
    const float* __restrict__ in, const void* __restrict__ w,
    unsigned short* __restrict__ oh, unsigned short* __restrict__ ol,
    int L, int istride, const int* __restrict__ flag)
{
    const int isbf = *flag;
    const int m = blockIdx.x, tid = threadIdx.x;
    const float* row = in + (size_t)m * istride;
    float ss = 0.f;
    for (int i = tid; i < L; i += 256) { float v = row[i]; ss += v * v; }
    __shared__ float red[256];
    red[tid] = ss; __syncthreads();
    for (int s = 128; s > 0; s >>= 1) {
        if (tid < s) red[tid] += red[tid + s];
        __syncthreads();
    }
    const float scale = 1.0f / sqrtf(red[0] / (float)L + 1e-6f);
    unsigned short* hrow = oh + (size_t)m * L;
    unsigned short* lrow = ol + (size_t)m * L;
    for (int i = tid; i < L; i += 256) {
        const float v = row[i] * scale * ldf(w, i, isbf);
        const unsigned short hi = f2bf(v);
        hrow[i] = hi;
        lrow[i] = f2bf(v - us2f(hi));
    }
}

// ---------------- rmsnorm f32->bf16 (FFN input) ----------------
__global__ __launch_bounds__(256) void rmsnorm_bf_k(
    const float* __restrict__ in, const void* __restrict__ w,
    unsigned short* __restrict__ out, int L,
    const int* __restrict__ flag)
{
    const int isbf = *flag;
    const int m = blockIdx.x, tid = threadIdx.x;
    const float* row = in + (size_t)m * L;
    float ss = 0.f;
    for (int i = tid; i < L; i += 256) { float v = row[i]; ss += v * v; }
    __shared__ float red[256];
    red[tid] = ss; __syncthreads();
    for (int s = 128; s > 0; s >>= 1) {
        if (tid < s) red[tid] += red[tid + s];
        __syncthreads();
    }
    const float scale = 1.0f / sqrtf(red[0] / (float)L + 1e-6f);
    unsigned short* orow = out + (size_t)m * L;
    for (int i = tid; i < L; i += 256)
        orow[i] = f2bf(row[i] * scale * ldf(w, i, isbf));
}

// rmsnorm on input x: writes hi/lo bf16 h and f32 residual copy
__global__ __launch_bounds__(256) void rmsnorm_x_hl_k(
    const void* __restrict__ x, size_t eoff, const void* __restrict__ w,
    unsigned short* __restrict__ hh, unsigned short* __restrict__ hl,
    float* __restrict__ xf, const int* __restrict__ flag)
{
    const int isbf = *flag;
    const int m = blockIdx.x, tid = threadIdx.x;
    const size_t base = eoff + (size_t)m * DD;
    float* xrow = xf + (size_t)m * DD;
    float ss = 0.f;
    float vals[8];
    for (int i = 0; i < 8; ++i) {
        float v = ldf(x, base + tid + 256 * i, isbf);
        vals[i] = v; ss += v * v;
        xrow[tid + 256 * i] = v;
    }
    __shared__ float red[256];
    red[tid] = ss; __syncthreads();
    for (int s = 128; s > 0; s >>= 1) {
        if (tid < s) red[tid] += red[tid + s];
        __syncthreads();
    }
    const float scale = 1.0f / sqrtf(red[0] / (float)DD + 1e-6f);
    unsigned short* hrow = hh + (size_t)m * DD;
    unsigned short* lrow = hl + (size_t)m * DD;
    for (int i = 0; i < 8; ++i) {
        const float v = vals[i] * scale * ldf(w, tid + 256 * i, isbf);
        const unsigned short hi = f2bf(v);
        hrow[tid + 256 * i] = hi;
        lrow[tid + 256 * i] = f2bf(v - us2f(hi));
    }
}

// ---------------- split-bf16 MFMA GEMM: C(M,N) f32 = (Ah+Al)(Wh+Wl)^T ----------------
__global__ __launch_bounds__(256) void gemm_mfma3_k(
    const unsigned short* __restrict__ Ah, const unsigned short* __restrict__ Al,
    const void* __restrict__ Wv, const unsigned short* __restrict__ Wlo,
    float* __restrict__ C, int N, int K, int klen,
    int presplit, const int* __restrict__ flag)
{
    __shared__ unsigned short Ash[128 * 40];
    __shared__ unsigned short Asl[128 * 40];
    __shared__ unsigned short Wsh[128 * 40];
    __shared__ unsigned short Wsl[128 * 40];
    const int tid = threadIdx.x;
    const int lane = tid & 63;
    const int wave = tid >> 6;
    const int wm = (wave >> 1) << 6, wn = (wave & 1) << 6;
    const int bm = blockIdx.y << 7, bn = blockIdx.x << 7;
    const int k0 = blockIdx.z * klen;
    const size_t zoff = (size_t)blockIdx.z * 1024 * N;
    const int srow = tid >> 1, scol = (tid & 1) << 4;
    const unsigned short* Ahld = Ah + (size_t)(bm + srow) * K + scol;
    const unsigned short* Alld = Al + (size_t)(bm + srow) * K + scol;
    const int wrow = bn + srow;
    const size_t wldbase = (size_t)((wrow < N) ? wrow : (N - 1)) * K + scol;
    unsigned short* Ahdst = &Ash[srow * 40 + scol];
    unsigned short* Aldst = &Asl[srow * 40 + scol];
    unsigned short* Whdst = &Wsh[srow * 40 + scol];
    unsigned short* Wldst = &Wsl[srow * 40 + scol];
    const int frow = lane & 15;
    const int fk = (lane >> 4) << 3;
    const int kend = k0 + klen;

    f32x4 acc[4][4] = {};

    if (presplit) {
        const unsigned short* Whp = (const unsigned short*)Wv + wldbase;
        const unsigned short* Wlp = Wlo + wldbase;
        ushort8v ca0h = *(const ushort8v*)(Ahld + k0);
        ushort8v ca1h = *(const ushort8v*)(Ahld + k0 + 8);
        ushort8v ca0l = *(const ushort8v*)(Alld + k0);
        ushort8v ca1l = *(const ushort8v*)(Alld + k0 + 8);
        ushort8v cw0h = *(const ushort8v*)(Whp + k0);
        ushort8v cw1h = *(const ushort8v*)(Whp + k0 + 8);
        ushort8v cw0l = *(const ushort8v*)(Wlp + k0);
        ushort8v cw1l = *(const ushort8v*)(Wlp + k0 + 8);
        for (int kt = k0; kt < kend; kt += 32) {
            __syncthreads();
            *(ushort8v*)Ahdst = ca0h; *(ushort8v*)(Ahdst + 8) = ca1h;
            *(ushort8v*)Aldst = ca0l; *(ushort8v*)(Aldst + 8) = ca1l;
            *(ushort8v*)Whdst = cw0h; *(ushort8v*)(Whdst + 8) = cw1h;
            *(ushort8v*)Wldst = cw0l; *(ushort8v*)(Wldst + 8) = cw1l;
            __syncthreads();
            const int nk = (kt + 32 < kend) ? kt + 32 : kt;
            ca0h = *(const ushort8v*)(Ahld + nk);
            ca1h = *(const ushort8v*)(Ahld + nk + 8);
            ca0l = *(const ushort8v*)(Alld + nk);
            ca1l = *(const ushort8v*)(Alld + nk + 8);
            cw0h = *(const ushort8v*)(Whp + nk);
            cw1h = *(const ushort8v*)(Whp + nk + 8);
            cw0l = *(const ushort8v*)(Wlp + nk);
            cw1l = *(const ushort8v*)(Wlp + nk + 8);

            short8 afh[4], afl[4], bfh[4], bfl[4];
#pragma unroll
            for (int i = 0; i < 4; ++i) {
                afh[i] = *(const short8*)&Ash[(wm + i * 16 + frow) * 40 + fk];
                afl[i] = *(const short8*)&Asl[(wm + i * 16 + frow) * 40 + fk];
            }
#pragma unroll
            for (int j = 0; j < 4; ++j) {
                bfh[j] = *(const short8*)&Wsh[(wn + j * 16 + frow) * 40 + fk];
                bfl[j] = *(const short8*)&Wsl[(wn + j * 16 + frow) * 40 + fk];
            }
#pragma unroll
            for (int i = 0; i < 4; ++i)
#pragma unroll
                for (int j = 0; j < 4; ++j) {
                    acc[i][j] = __builtin_amdgcn_mfma_f32_16x16x32_bf16(
                        afh[i], bfh[j], acc[i][j], 0, 0, 0);
                    acc[i][j] = __builtin_amdgcn_mfma_f32_16x16x32_bf16(
                        afh[i], bfl[j], acc[i][j], 0, 0, 0);
                    acc[i][j] = __builtin_amdgcn_mfma_f32_16x16x32_bf16(
                        afl[i], bfh[j], acc[i][j], 0, 0, 0);
                }
        }
    } else {
        const int isbf = *flag;
        for (int kt = k0; kt < kend; kt += 32) {
            ushort8v a0h = *(const ushort8v*)(Ahld + kt);
            ushort8v a1h = *(const ushort8v*)(Ahld + kt + 8);
            ushort8v a0l = *(const ushort8v*)(Alld + kt);
            ushort8v a1l = *(const ushort8v*)(Alld + kt + 8);
            ushort8v w0h, w1h, w0l, w1l;
            if (isbf) {
                const unsigned short* Wp = (const unsigned short*)Wv + wldbase + kt;
                w0h = *(const ushort8v*)(Wp);
                w1h = *(const ushort8v*)(Wp + 8);
                w0l = w0h ^ w0h;
                w1l = w0l;
            } else {
                const float* Wp = (const float*)Wv + wldbase + kt;
                unsigned short th[16], tl[16];
#pragma unroll
                for (int t4 = 0; t4 < 4; ++t4) {
                    float4 f = *(const float4*)(Wp + 4 * t4);
                    float fv[4] = {f.x, f.y, f.z, f.w};
#pragma unroll
                    for (int u = 0; u < 4; ++u) {
                        const unsigned short hi = f2bf(fv[u]);
                        th[4 * t4 + u] = hi;
                        tl[4 * t4 + u] = f2bf(fv[u] - us2f(hi));
                    }
                }
                w0h = *(ushort8v*)&th[0]; w1h = *(ushort8v*)&th[8];
                w0l = *(ushort8v*)&tl[0]; w1l = *(ushort8v*)&tl[8];
            }
            __syncthreads();
            *(ushort8v*)Ahdst = a0h; *(ushort8v*)(Ahdst + 8) = a1h;
            *(ushort8v*)Aldst = a0l; *(ushort8v*)(Aldst + 8) = a1l;
            *(ushort8v*)Whdst = w0h; *(ushort8v*)(Whdst + 8) = w1h;
            *(ushort8v*)Wldst = w0l; *(ushort8v*)(Wldst + 8) = w1l;
            __syncthreads();

            short8 afh[4], afl[4], bfh[4], bfl[4];
#pragma unroll
            for (int i = 0; i < 4; ++i) {
                afh[i] = *(const short8*)&Ash[(wm + i * 16 + frow) * 40 + fk];
                afl[i] = *(const short8*)&Asl[(wm + i * 16 + frow) * 40 + fk];
            }
#pragma unroll
            for (int j = 0; j < 4; ++j) {
                bfh[j] = *(const short8*)&Wsh[(wn + j * 16 + frow) * 40 + fk];
                bfl[j] = *(const short8*)&Wsl[(wn + j * 16 + frow) * 40 + fk];
            }
#pragma unroll
            for (int i = 0; i < 4; ++i)
#pragma unroll
                for (int j = 0; j < 4; ++j) {
                    acc[i][j] = __builtin_amdgcn_mfma_f32_16x16x32_bf16(
                        afh[i], bfh[j], acc[i][j], 0, 0, 0);
                    acc[i][j] = __builtin_amdgcn_mfma_f32_16x16x32_bf16(
                        afh[i], bfl[j], acc[i][j], 0, 0, 0);
                    acc[i][j] = __builtin_amdgcn_mfma_f32_16x16x32_bf16(
                        afl[i], bfh[j], acc[i][j], 0, 0, 0);
                }
        }
    }

#pragma unroll
    for (int i = 0; i < 4; ++i) {
        const int r0 = bm + wm + i * 16 + ((lane >> 4) << 2);
#pragma unroll
        for (int j = 0; j < 4; ++j) {
            const int c = bn + wn + j * 16 + (lane & 15);
            if (c < N) {
#pragma unroll
                for (int g = 0; g < 4; ++g)
                    C[zoff + (size_t)(r0 + g) * N + c] = acc[i][j][g];
            }
        }
    }
}

// ---------------- bf16 MFMA GEMM (FFN path) ----------------
template <int EPI>
__global__ __launch_bounds__(256) void gemm_mfma_k(
    const unsigned short* __restrict__ A, const void* __restrict__ Wv,
    const float* __restrict__ R, void* __restrict__ outp,
    int N, int K, int klen, int wready, const int* __restrict__ flag)
{
    __shared__ unsigned short As[128 * 40];
    __shared__ unsigned short Ws[128 * 40];
    const int tid = threadIdx.x;
    const int lane = tid & 63;
    const int wave = tid >> 6;
    const int wm = (wave >> 1) << 6, wn = (wave & 1) << 6;
    const int bm = blockIdx.y << 7, bn = blockIdx.x << 7;
    const int k0 = blockIdx.z * klen;
    const size_t zoff = (size_t)blockIdx.z * 1024 * N;
    const int srow = tid >> 1, scol = (tid & 1) << 4;
    const unsigned short* Ald = A + (size_t)(bm + srow) * K + scol;
    const size_t wldbase = (size_t)(bn + srow) * K + scol;
    unsigned short* Adst = &As[srow * 40 + scol];
    unsigned short* Wdst = &Ws[srow * 40 + scol];
    const int frow = lane & 15;
    const int fk = (lane >> 4) << 3;
    const int kend = k0 + klen;

    f32x4 acc[4][4] = {};

    if (wready) {
        const unsigned short* Wp = (const unsigned short*)Wv + wldbase;
        ushort8v ca0 = *(const ushort8v*)(Ald + k0);
        ushort8v ca1 = *(const ushort8v*)(Ald + k0 + 8);
        ushort8v cw0 = *(const ushort8v*)(Wp + k0);
        ushort8v cw1 = *(const ushort8v*)(Wp + k0 + 8);
        for (int kt = k0; kt < kend; kt += 32) {
            __syncthreads();
            *(ushort8v*)Adst = ca0; *(ushort8v*)(Adst + 8) = ca1;
            *(ushort8v*)Wdst = cw0; *(ushort8v*)(Wdst + 8) = cw1;
            __syncthreads();
            const int nk = (kt + 32 < kend) ? kt + 32 : kt;
            ca0 = *(const ushort8v*)(Ald + nk);
            ca1 = *(const ushort8v*)(Ald + nk + 8);
            cw0 = *(const ushort8v*)(Wp + nk);
            cw1 = *(const ushort8v*)(Wp + nk + 8);

            short8 af[4], bfr[4];
#pragma unroll
            for (int i = 0; i < 4; ++i)
                af[i] = *(const short8*)&As[(wm + i * 16 + frow) * 40 + fk];
#pragma unroll
            for (int j = 0; j < 4; ++j)
                bfr[j] = *(const short8*)&Ws[(wn + j * 16 + frow) * 40 + fk];
#pragma unroll
            for (int i = 0; i < 4; ++i)
#pragma unroll
                for (int j = 0; j < 4; ++j)
                    acc[i][j] = __builtin_amdgcn_mfma_f32_16x16x32_bf16(
                        af[i], bfr[j], acc[i][j], 0, 0, 0);
        }
    } else {
        const int isbf = *flag;
        for (int kt = k0; kt < kend; kt += 32) {
            ushort8v a0 = *(const ushort8v*)(Ald + kt);
            ushort8v a1 = *(const ushort8v*)(Ald + kt + 8);
            ushort8v w0, w1;
            if (isbf) {
                const unsigned short* Wp = (const unsigned short*)Wv + wldbase + kt;
                w0 = *(const ushort8v*)(Wp);
                w1 = *(const ushort8v*)(Wp + 8);
            } else {
                const float* Wp = (const float*)Wv + wldbase + kt;
                float4 f0 = *(const float4*)(Wp);
                float4 f1 = *(const float4*)(Wp + 4);
                float4 f2 = *(const float4*)(Wp + 8);
                float4 f3 = *(const float4*)(Wp + 12);
                unsigned short wt[16];
                wt[0] = f2bf(f0.x); wt[1] = f2bf(f0.y); wt[2]  = f2bf(f0.z); wt[3]  = f2bf(f0.w);
                wt[4] = f2bf(f1.x); wt[5] = f2bf(f1.y); wt[6]  = f2bf(f1.z); wt[7]  = f2bf(f1.w);
                wt[8] = f2bf(f2.x); wt[9] = f2bf(f2.y); wt[10] = f2bf(f2.z); wt[11] = f2bf(f2.w);
                wt[12] = f2bf(f3.x); wt[13] = f2bf(f3.y); wt[14] = f2bf(f3.z); wt[15] = f2bf(f3.w);
                w0 = *(const ushort8v*)&wt[0];
                w1 = *(const ushort8v*)&wt[8];
            }
            __syncthreads();
            *(ushort8v*)Adst = a0; *(ushort8v*)(Adst + 8) = a1;
            *(ushort8v*)Wdst = w0; *(ushort8v*)(Wdst + 8) = w1;
            __syncthreads();

            short8 af[4], bfr[4];
#pragma unroll
            for (int i = 0; i < 4; ++i)
                af[i] = *(const short8*)&As[(wm + i * 16 + frow) * 40 + fk];
#pragma unroll
            for (int j = 0; j < 4; ++j)
                bfr[j] = *(const short8*)&Ws[(wn + j * 16 + frow) * 40 + fk];
#pragma unroll
            for (int i = 0; i < 4; ++i)
#pragma unroll
                for (int j = 0; j < 4; ++j)
                    acc[i][j] = __builtin_amdgcn_mfma_f32_16x16x32_bf16(
                        af[i], bfr[j], acc[i][j], 0, 0, 0);
        }
    }

#pragma unroll
    for (int i = 0; i < 4; ++i) {
        const int r0 = bm + wm + i * 16 + ((lane >> 4) << 2);
#pragma unroll
        for (int j = 0; j < 4; ++j) {
            const int c = bn + wn + j * 16 + (lane & 15);
#pragma unroll
            for (int g = 0; g < 4; ++g) {
                const size_t idx = zoff + (size_t)(r0 + g) * N + c;
                const float v = acc[i][j][g];
                if (EPI == 0) {
                    ((float*)outp)[idx] = v;
                } else if (EPI == 1) {
                    ((float*)outp)[idx] = v + R[idx];
                } else {
                    const float gv = R[idx];
                    const float sg = 1.0f / (1.0f + __expf(-gv));
                    ((unsigned short*)outp)[idx] = f2bf(gv * sg * v);
                }
            }
        }
    }
}

// ---------------- fused swiglu GEMM: out = bf16(silu(A@W1^T) * (A@W3^T)) ----------------
// A bf16 [1024][K]; W1/W3 per wready (bf16 prepped or f32/bf16 raw).
// 128x128 tile, stages A once + both W tiles. N=8192-like grids.
__global__ __launch_bounds__(256) void gemm_swiglu_k(
    const unsigned short* __restrict__ A, const void* __restrict__ W1v,
    const void* __restrict__ W3v, unsigned short* __restrict__ outp,
    int N, int K, int wready, const int* __restrict__ flag)
{
    __shared__ unsigned short As[128 * 40];
    __shared__ unsigned short Ws1[128 * 40];
    __shared__ unsigned short Ws3[128 * 40];
    const int tid = threadIdx.x;
    const int lane = tid & 63;
    const int wave = tid >> 6;
    const int wm = (wave >> 1) << 6, wn = (wave & 1) << 6;
    const int bm = blockIdx.y << 7, bn = blockIdx.x << 7;
    const int srow = tid >> 1, scol = (tid & 1) << 4;
    const unsigned short* Ald = A + (size_t)(bm + srow) * K + scol;
    const size_t wldbase = (size_t)(bn + srow) * K + scol;
    unsigned short* Adst = &As[srow * 40 + scol];
    unsigned short* W1dst = &Ws1[srow * 40 + scol];
    unsigned short* W3dst = &Ws3[srow * 40 + scol];
    const int frow = lane & 15;
    const int fk = (lane >> 4) << 3;

    f32x4 acc1[4][4] = {};
    f32x4 acc3[4][4] = {};

    if (wready) {
        const unsigned short* W1p = (const unsigned short*)W1v + wldbase;
        const unsigned short* W3p = (const unsigned short*)W3v + wldbase;
        ushort8v ca0 = *(const ushort8v*)(Ald);
        ushort8v ca1 = *(const ushort8v*)(Ald + 8);
        ushort8v c10 = *(const ushort8v*)(W1p);
        ushort8v c11 = *(const ushort8v*)(W1p + 8);
        ushort8v c30 = *(const ushort8v*)(W3p);
        ushort8v c31 = *(const ushort8v*)(W3p + 8);
        for (int kt = 0; kt < K; kt += 32) {
            __syncthreads();
            *(ushort8v*)Adst = ca0; *(ushort8v*)(Adst + 8) = ca1;
            *(ushort8v*)W1dst = c10; *(ushort8v*)(W1dst + 8) = c11;
            *(ushort8v*)W3dst = c30; *(ushort8v*)(W3dst + 8) = c31;
            __syncthreads();
            const int nk = (kt + 32 < K) ? kt + 32 : kt;
            ca0 = *(const ushort8v*)(Ald + nk);
            ca1 = *(const ushort8v*)(Ald + nk + 8);
            c10 = *(const ushort8v*)(W1p + nk);
            c11 = *(const ushort8v*)(W1p + nk + 8);
            c30 = *(const ushort8v*)(W3p + nk);
            c31 = *(const ushort8v*)(W3p + nk + 8);

            short8 af[4], b1[4], b3[4];
#pragma unroll
            for (int i = 0; i < 4; ++i)
                af[i] = *(const short8*)&As[(wm + i * 16 + frow) * 40 + fk];
#pragma unroll
            for (int j = 0; j < 4; ++j) {
                b1[j] = *(const short8*)&Ws1[(wn + j * 16 + frow) * 40 + fk];
                b3[j] = *(const short8*)&Ws3[(wn + j * 16 + frow) * 40 + fk];
            }
#pragma unroll
            for (int i = 0; i < 4; ++i)
#pragma unroll
                for (int j = 0; j < 4; ++j) {
                    acc1[i][j] = __builtin_amdgcn_mfma_f32_16x16x32_bf16(
                        af[i], b1[j], acc1[i][j], 0, 0, 0);
                    acc3[i][j] = __builtin_amdgcn_mfma_f32_16x16x32_bf16(
                        af[i], b3[j], acc3[i][j], 0, 0, 0);
                }
        }
    } else {
        const int isbf = *flag;
        for (int kt = 0; kt < K; kt += 32) {
            ushort8v a0 = *(const ushort8v*)(Ald + kt);
            ushort8v a1 = *(const ushort8v*)(Ald + kt + 8);
            ushort8v w10, w11, w30, w31;
            if (isbf) {
                const unsigned short* W1p = (const unsigned short*)W1v + wldbase + kt;
                const unsigned short* W3p = (const unsigned short*)W3v + wldbase + kt;
                w10 = *(const ushort8v*)(W1p); w11 = *(const ushort8v*)(W1p + 8);
                w30 = *(const ushort8v*)(W3p); w31 = *(const ushort8v*)(W3p + 8);
            } else {
                const float* W1p = (const float*)W1v + wldbase + kt;
                const float* W3p = (const float*)W3v + wldbase + kt;
                unsigned short t1[16], t3[16];
#pragma unroll
                for (int t4 = 0; t4 < 4; ++t4) {
                    float4 f1 = *(const float4*)(W1p + 4 * t4);
                    float4 f3 = *(const float4*)(W3p + 4 * t4);
                    float v1[4] = {f1.x, f1.y, f1.z, f1.w};
                    float v3[4] = {f3.x, f3.y, f3.z, f3.w};
#pragma unroll
                    for (int u = 0; u < 4; ++u) {
                        t1[4 * t4 + u] = f2bf(v1[u]);
                        t3[4 * t4 + u] = f2bf(v3[u]);
                    }
                }
                w10 = *(ushort8v*)&t1[0]; w11 = *(ushort8v*)&t1[8];
                w30 = *(ushort8v*)&t3[0]; w31 = *(ushort8v*)&t3[8];
            }
            __syncthreads();
            *(ushort8v*)Adst = a0; *(ushort8v*)(Adst + 8) = a1;
            *(ushort8v*)W1dst = w10; *(ushort8v*)(W1dst + 8) = w11;
            *(ushort8v*)W3dst = w30; *(ushort8v*)(W3dst + 8) = w31;
            __syncthreads();

            short8 af[4], b1[4], b3[4];
#pragma unroll
            for (int i = 0; i < 4; ++i)
                af[i] = *(const short8*)&As[(wm + i * 16 + frow) * 40 + fk];
#pragma unroll
            for (int j = 0; j < 4; ++j) {
                b1[j] = *(const short8*)&Ws1[(wn + j * 16 + frow) * 40 + fk];
                b3[j] = *(const short8*)&Ws3[(wn + j * 16 + frow) * 40 + fk];
            }
#pragma unroll
            for (int i = 0; i < 4; ++i)
#pragma unroll
                for (int j = 0; j < 4; ++j) {
                    acc1[i][j] = __builtin_amdgcn_mfma_f32_16x16x32_bf16(
                        af[i], b1[j], acc1[i][j], 0, 0, 0);
                    acc3[i][j] = __builtin_amdgcn_mfma_f32_16x16x32_bf16(
                        af[i], b3[j], acc3[i][j], 0, 0, 0);
                }
        }
    }

#pragma unroll
    for (int i = 0; i < 4; ++i) {
        const int r0 = bm + wm + i * 16 + ((lane >> 4) << 2);
#pragma unroll
        for (int j = 0; j < 4; ++j) {
            const int c = bn + wn + j * 16 + (lane & 15);
#pragma unroll
            for (int g = 0; g < 4; ++g) {
                const float gv = acc1[i][j][g];
                const float sg = 1.0f / (1.0f + __expf(-gv));
                outp[(size_t)(r0 + g) * N + c] = f2bf(gv * sg * acc3[i][j][g]);
            }
        }
    }
}

// ---------------- RoPE (interleaved pairs), in-place on q and k_pe ----------------
__global__ __launch_bounds__(256) void rope_k(
    float* __restrict__ qb, float* __restrict__ kva,
    const void* __restrict__ fc, const void* __restrict__ fs,
    const int* __restrict__ flag)
{
    const int isbf = *flag;
    const int t = blockIdx.x;
    const int tid = threadIdx.x;
    __shared__ float c[32], s[32];
    if (tid < 32) {
        c[tid] = ldf(fc, t * 32 + tid, isbf);
        s[tid] = ldf(fs, t * 32 + tid, isbf);
    }
    __syncthreads();
    for (int p = tid; p < 512; p += 256) {
        const int h = p >> 5, i = p & 31;
        float* base = qb + (size_t)t * 3072 + h * 192 + 128 + 2 * i;
        const float x0 = base[0], x1 = base[1];
        base[0] = x0 * c[i] - x1 * s[i];
        base[1] = x0 * s[i] + x1 * c[i];
    }
    if (tid < 32) {
        float* base = kva + (size_t)t * 576 + 512 + 2 * tid;
        const float x0 = base[0], x1 = base[1];
        base[0] = x0 * c[tid] - x1 * s[tid];
        base[1] = x0 * s[tid] + x1 * c[tid];
    }
}

// ---------------- KV prep: split K to hi/lo bf16 [h][t][192], transpose V ----------------
__global__ __launch_bounds__(256) void kvprep_k(
    const float* __restrict__ kvb,   // [1024][4096]
    const float* __restrict__ kva,   // [1024][576]
    unsigned short* __restrict__ kh, unsigned short* __restrict__ kl,
    unsigned short* __restrict__ vt)
{
    const int tt = blockIdx.x, h = blockIdx.y;
    const int tid = threadIdx.x;
    const int tbase = tt * 64;
    for (int i = tid; i < 64 * 192; i += 256) {
        const int t = i / 192, k = i % 192;
        const float v = (k < 128)
            ? kvb[(size_t)(tbase + t) * 4096 + h * 256 + k]
            : kva[(size_t)(tbase + t) * 576 + 512 + (k - 128)];
        const unsigned short hi = f2bf(v);
        const size_t o = ((size_t)h * 1024 + tbase + t) * 192 + k;
        kh[o] = hi;
        kl[o] = f2bf(v - us2f(hi));
    }
    __shared__ unsigned short Vl[128][72];
    for (int i = tid; i < 64 * 128; i += 256) {
        const int t = i >> 7, d = i & 127;
        Vl[d][t] = f2bf(kvb[(size_t)(tbase + t) * 4096 + h * 256 + 128 + d]);
    }
    __syncthreads();
    for (int i = tid; i < 128 * 64; i += 256) {
        const int d = i >> 6, t = i & 63;
        vt[((size_t)h * 128 + d) * 1024 + tbase + t] = Vl[d][t];
    }
}

// ---------------- MFMA flash attention, split-KV via blockIdx.z ----------------
// z slice handles (qt+1) KV tiles: z=0 -> [0, qt+1), z=1 -> [qt+1, 2(qt+1)).
// Writes unnormalized partial per (z,row,h): O[128] bf16 + m,l f32 (66-float rec).
__global__ __launch_bounds__(256) void attn_mfma_k(
    const float* __restrict__ qb,
    const unsigned short* __restrict__ kh,
    const unsigned short* __restrict__ kl,
    const unsigned short* __restrict__ vt,
    float* __restrict__ opart)
{
    const int qt = blockIdx.x, h = blockIdx.y, z = blockIdx.z;
    const int s0 = qt * QBLK;
    const int tid = threadIdx.x;
    const int lane = tid & 63, wave = tid >> 6;
    const int frow = lane & 15;
    const int fk8 = (lane >> 4) << 3;
    const int g4 = (lane >> 4) << 2;

    __shared__ __align__(16) unsigned short Ksh[KVB][200];
    __shared__ __align__(16) unsigned short Ksl[KVB][200];
    __shared__ __align__(16) unsigned short Vs[128][40];
    __shared__ __align__(16) unsigned short Ps[4][16][40];

    const int wrow0 = s0 + wave * 16;
    short8 qhf[6], qlf[6];
    {
        const float* qrow = qb + (size_t)(wrow0 + frow) * 3072 + h * 192 + fk8;
#pragma unroll
        for (int ks = 0; ks < 6; ++ks) {
            float4 f0 = *(const float4*)(qrow + ks * 32);
            float4 f1 = *(const float4*)(qrow + ks * 32 + 4);
            float fv[8] = {f0.x, f0.y, f0.z, f0.w, f1.x, f1.y, f1.z, f1.w};
            unsigned short th[8], tl[8];
#pragma unroll
            for (int u = 0; u < 8; ++u) {
                th[u] = f2bf(fv[u]);
                tl[u] = f2bf(fv[u] - us2f(th[u]));
            }
            qhf[ks] = *(short8*)th;
            qlf[ks] = *(short8*)tl;
        }
    }

    f32x4 O[8] = {};
    float m_run[4] = {-1e30f, -1e30f, -1e30f, -1e30f};
    float l_run[4] = {};

    const int t_beg = z * (qt + 1);
    const int t_end = t_beg + (qt + 1);
    for (int tt = t_beg; tt < t_end; ++tt) {
        const int t0 = tt * KVB;
        __syncthreads();
        for (int i = tid; i < KVB * 24; i += 256) {
            const int r = i / 24, c = (i % 24) * 8;
            const size_t gof = ((size_t)h * 1024 + t0 + r) * 192 + c;
            *(ushort8v*)&Ksh[r][c] = *(const ushort8v*)(kh + gof);
            *(ushort8v*)&Ksl[r][c] = *(const ushort8v*)(kl + gof);
        }
        for (int i = tid; i < 128 * 4; i += 256) {
            const int d = i >> 2, c = (i & 3) * 8;
            *(ushort8v*)&Vs[d][c] =
                *(const ushort8v*)(vt + ((size_t)h * 128 + d) * 1024 + t0 + c);
        }
        __syncthreads();

        const bool active = (t0 <= wrow0 + 15);
        if (active) {
            f32x4 s[2] = {};
#pragma unroll
            for (int j = 0; j < 2; ++j) {
                const unsigned short* kb = &Ksh[j * 16 + frow][fk8];
                const unsigned short* lb = &Ksl[j * 16 + frow][fk8];
#pragma unroll
                for (int ks = 0; ks < 6; ++ks) {
                    short8 bh = *(const short8*)(kb + ks * 32);
                    short8 bl = *(const short8*)(lb + ks * 32);
                    s[j] = __builtin_amdgcn_mfma_f32_16x16x32_bf16(qhf[ks], bh, s[j], 0, 0, 0);
                    s[j] = __builtin_amdgcn_mfma_f32_16x16x32_bf16(qhf[ks], bl, s[j], 0, 0, 0);
                    s[j] = __builtin_amdgcn_mfma_f32_16x16x32_bf16(qlf[ks], bh, s[j], 0, 0, 0);
                }
            }
            const bool edge = (t0 + KVB - 1 > wrow0);
            float sv[2][4];
#pragma unroll
            for (int j = 0; j < 2; ++j)
#pragma unroll
                for (int g = 0; g < 4; ++g) {
                    float v = s[j][g] * -96.0f;
                    if (edge) {
                        const int col = t0 + j * 16 + frow;
                        const int row = wrow0 + g4 + g;
                        if (col > row) v = -1e30f;
                    }
                    sv[j][g] = v;
                }
            float alpha[4];
#pragma unroll
            for (int g = 0; g < 4; ++g) {
                float mt = fmaxf(sv[0][g], sv[1][g]);
                mt = fmaxf(mt, __shfl_xor(mt, 1));
                mt = fmaxf(mt, __shfl_xor(mt, 2));
                mt = fmaxf(mt, __shfl_xor(mt, 4));
                mt = fmaxf(mt, __shfl_xor(mt, 8));
                const float mn = fmaxf(m_run[g], mt);
                alpha[g] = __expf(m_run[g] - mn);
                m_run[g] = mn;
                const float p0 = __expf(sv[0][g] - mn);
                const float p1 = __expf(sv[1][g] - mn);
                sv[0][g] = p0; sv[1][g] = p1;
                float ps = p0 + p1;
                ps += __shfl_xor(ps, 1);
                ps += __shfl_xor(ps, 2);
                ps += __shfl_xor(ps, 4);
                ps += __shfl_xor(ps, 8);
                l_run[g] = l_run[g] * alpha[g] + ps;
            }
#pragma unroll
            for (int jt = 0; jt < 8; ++jt)
#pragma unroll
                for (int g = 0; g < 4; ++g)
                    O[jt][g] *= alpha[g];
#pragma unroll
            for (int j = 0; j < 2; ++j)
#pragma unroll
                for (int g = 0; g < 4; ++g)
                    Ps[wave][g4 + g][j * 16 + frow] = f2bf(sv[j][g]);
        }
        __syncthreads();
        if (active) {
            short8 pa = *(const short8*)&Ps[wave][frow][fk8];
#pragma unroll
            for (int jt = 0; jt < 8; ++jt) {
                short8 vb = *(const short8*)&Vs[jt * 16 + frow][fk8];
                O[jt] = __builtin_amdgcn_mfma_f32_16x16x32_bf16(pa, vb, O[jt], 0, 0, 0);
            }
        }
    }

    // epilogue: unnormalized partial (O bf16, m, l)
#pragma unroll
    for (int g = 0; g < 4; ++g) {
        const int row = wrow0 + g4 + g;
        float* rec = opart + (((size_t)z * 1024 + row) * 16 + h) * 66;
        unsigned short* ob = (unsigned short*)rec;
#pragma unroll
        for (int jt = 0; jt < 8; ++jt)
            ob[jt * 16 + frow] = f2bf(O[jt][g]);
        if ((lane & 15) == 0) { rec[64] = m_run[g]; rec[65] = l_run[g]; }
    }
}

// ---------------- attention split-KV merge -> yb ----------------
__global__ __launch_bounds__(256) void attn_merge_k(
    const float* __restrict__ opart, unsigned short* __restrict__ y)
{
    const int r = blockIdx.x;
    for (int i = threadIdx.x; i < 2048; i += 256) {
        const int h = i >> 7, d = i & 127;
        const float* r0 = opart + (((size_t)r) * 16 + h) * 66;
        const float* r1 = opart + (((size_t)1024 + r) * 16 + h) * 66;
        const float m0 = r0[64], l0 = r0[65];
        const float m1 = r1[64], l1 = r1[65];
        const float mm = fmaxf(m0, m1);
        const float a0 = __expf(m0 - mm), a1 = __expf(m1 - mm);
        const float denom = l0 * a0 + l1 * a1;
        const float o0 = us2f(((const unsigned short*)r0)[d]);
        const float o1 = us2f(((const unsigned short*)r1)[d]);
        y[(size_t)r * 2048 + h * 128 + d] = f2bf((o0 * a0 + o1 * a1) / denom);
    }
}

extern "C" void kernel_launch(void* const* d_in, const int* in_sizes, int n_in,
                              void* d_out, int out_size, void* d_ws, size_t ws_size,
                              hipStream_t stream) {
    (void)in_sizes; (void)n_in; (void)out_size;
    const void* x       = d_in[0];
    const void* fcos    = d_in[2];
    const void* fsin    = d_in[3];
    const void* attn_nw = d_in[4];
    const void* wq_a    = d_in[5];
    const void* q_nw    = d_in[6];
    const void* wq_b    = d_in[7];
    const void* wkv_a   = d_in[8];
    const void* kv_nw   = d_in[9];
    const void* wkv_b   = d_in[10];
    const void* wo      = d_in[11];
    const void* ffn_nw  = d_in[12];
    const void* w1      = d_in[13];
    const void* w2      = d_in[14];
    const void* w3      = d_in[15];

    int* flag = (int*)d_ws;
    float* a  = (float*)d_ws + 64;
    const size_t M1 = 1048576;
    // Arena (float units), peak 16M floats = 64 MiB:
    float* xf  = a;                                               // [0,2M) f32 residual
    unsigned short* hh = (unsigned short*)(a + 2 * M1);           // [2M,3M)
    unsigned short* hl = (unsigned short*)(a + 3 * M1);           // [3M,4M)
    float* qa  = a + 4 * M1;                                      // [4M,5.5M)
    float* kva = a + 4 * M1;                                      // [4M,4.5625M) (qa dead)
    unsigned short* kvnh = (unsigned short*)(a + 4 * M1 + 655360);
    unsigned short* kvnl = (unsigned short*)(a + 4 * M1 + 655360 + 262144);
    unsigned short* qah = (unsigned short*)(a + 5 * M1 + 524288); // [5.5M,6.25M)
    unsigned short* qal = (unsigned short*)(a + 6 * M1 + 262144); // [6.25M,7M)
    float* qb  = a + 7 * M1;                                      // [7M,10M)
    float* kvb = a + 10 * M1;                                     // [10M,14M); dead after kvprep
    unsigned short* kh = (unsigned short*)(a + 2 * M1);           // [2M,3.5M)
    unsigned short* kl = (unsigned short*)(a + 5 * M1 + 524288);  // [5.5M,7M)
    unsigned short* vt = (unsigned short*)(a + 14 * M1);          // [14M,15M)
    unsigned short* yb = (unsigned short*)(a + 3 * M1 + 524288);  // [3.5M,4.5M)
    unsigned short* hb  = (unsigned short*)(a + 2 * M1);          // [2M,3M)
    unsigned short* gb2 = (unsigned short*)(a + 12 * M1);         // [12M,16M)
    float* x2  = xf;
    // Split-K partial arenas (stride = M*N floats per slice):
    float* sp  = a + 10 * M1;   // score path: [10M,16M)
    float* fpo = a + 5 * M1;    // wo: 4x2M = [5M,13M)  (yb [3.5M,4.5M) untouched; opart dead)
    float* fp2 = a + 2 * M1;    // w2: 4x2M = [2M,10M)  (hb dead by then)
    // Attention split-KV partials: 2 x 1024 x 16 x 66 floats = 2.16M @ [10M,~12.2M)
    float* opart = a + 10 * M1;
    // Prepared weights (beyond 16M; only if ws_size allows):
    unsigned short* wo_b  = (unsigned short*)(a + 16 * M1);       // 4M us
    unsigned short* w1_b  = (unsigned short*)(a + 18 * M1);       // 16M us
    unsigned short* w3_b  = (unsigned short*)(a + 26 * M1);       // 16M us
    unsigned short* w2_b  = (unsigned short*)(a + 34 * M1);       // 16M us
    unsigned short* wqa_h = (unsigned short*)(a + 42 * M1);
    unsigned short* wqa_l = wqa_h + 3145728u;
    unsigned short* wqb_h = (unsigned short*)(a + 45 * M1);
    unsigned short* wqb_l = wqb_h + 4718592u;
    unsigned short* wkva_h = (unsigned short*)(a + 49 * M1 + 524288);
    unsigned short* wkva_l = wkva_h + 1179648u;
    unsigned short* wkvb_h = (unsigned short*)(a + 50 * M1 + 655360);
    unsigned short* wkvb_l = wkvb_h + 2097152u;
    const size_t NEED = 256 + (size_t)(52 * M1 + 655360) * 4;     // ~220.7 MB
    const int prep = (ws_size >= NEED) ? 1 : 0;

    detect_k<<<1, 64, 0, stream>>>(x, flag);

    if (prep) {
        cvt_bf_k<<<1024, 256, 0, stream>>>(wo, wo_b, (size_t)2048 * 2048, flag);
        cvt_bf_k<<<2048, 256, 0, stream>>>(w1, w1_b, (size_t)8192 * 2048, flag);
        cvt_bf_k<<<2048, 256, 0, stream>>>(w3, w3_b, (size_t)8192 * 2048, flag);
        cvt_bf_k<<<2048, 256, 0, stream>>>(w2, w2_b, (size_t)2048 * 8192, flag);
        cvt_hl_k<<<1024, 256, 0, stream>>>(wq_a, wqa_h, wqa_l, (size_t)1536 * 2048, flag);
        cvt_hl_k<<<1024, 256, 0, stream>>>(wq_b, wqb_h, wqb_l, (size_t)3072 * 1536, flag);
        cvt_hl_k<<<512, 256, 0, stream>>>(wkv_a, wkva_h, wkva_l, (size_t)576 * 2048, flag);
        cvt_hl_k<<<1024, 256, 0, stream>>>(wkv_b, wkvb_h, wkvb_l, (size_t)4096 * 512, flag);
    }
    const void* Wqa = prep ? (const void*)wqa_h : wq_a;
    const void* Wqb = prep ? (const void*)wqb_h : wq_b;
    const void* Wkva = prep ? (const void*)wkva_h : wkv_a;
    const void* Wkvb = prep ? (const void*)wkvb_h : wkv_b;
    const unsigned short* WqaL = prep ? wqa_l : nullptr;
    const unsigned short* WqbL = prep ? wqb_l : nullptr;
    const unsigned short* WkvaL = prep ? wkva_l : nullptr;
    const unsigned short* WkvbL = prep ? wkvb_l : nullptr;
    const void* WoP = prep ? (const void*)wo_b : wo;
    const void* W1P = prep ? (const void*)w1_b : w1;
    const void* W3P = prep ? (const void*)w3_b : w3;
    const void* W2P = prep ? (const void*)w2_b : w2;

    for (int b = 0; b < 2; ++b) {
        const size_t eoff = (size_t)b * TT * DD;
        float* outb = (float*)d_out + eoff;

        // --- attention path (split-bf16 MFMA score chain, single-launch split-K) ---
        rmsnorm_x_hl_k<<<TT, 256, 0, stream>>>(x, eoff, attn_nw, hh, hl, xf, flag);
        gemm_mfma3_k<<<dim3(12, 8, 4), 256, 0, stream>>>(hh, hl, Wqa, WqaL, sp, 1536, 2048, 512, prep, flag);
        combine_k<4, 0><<<1024, 256, 0, stream>>>(sp, nullptr, qa, 393216);
        rmsnorm_hl_k<<<TT, 256, 0, stream>>>(qa, q_nw, qah, qal, 1536, 1536, flag);
        gemm_mfma3_k<<<dim3(24, 8, 2), 256, 0, stream>>>(qah, qal, Wqb, WqbL, sp, 3072, 1536, 768, prep, flag);
        combine_k<2, 0><<<1024, 256, 0, stream>>>(sp, nullptr, qb, 786432);
        gemm_mfma3_k<<<dim3(5, 8, 8), 256, 0, stream>>>(hh, hl, Wkva, WkvaL, sp, 576, 2048, 256, prep, flag);
        combine_k<8, 0><<<1024, 256, 0, stream>>>(sp, nullptr, kva, 147456);
        rmsnorm_hl_k<<<TT, 256, 0, stream>>>(kva, kv_nw, kvnh, kvnl, 512, 576, flag);
        rope_k<<<TT, 256, 0, stream>>>(qb, kva, fcos, fsin, flag);
        gemm_mfma3_k<<<dim3(32, 8, 1), 256, 0, stream>>>(kvnh, kvnl, Wkvb, WkvbL, kvb, 4096, 512, 512, prep, flag);
        kvprep_k<<<dim3(16, 16), 256, 0, stream>>>(kvb, kva, kh, kl, vt);
        // flash attention, split-KV z=2 (kvb dead -> opart at [10M,~12.2M))
        attn_mfma_k<<<dim3(TT / QBLK, 16, 2), 256, 0, stream>>>(qb, kh, kl, vt, opart);
        attn_merge_k<<<TT, 256, 0, stream>>>(opart, yb);

        // --- FFN MFMA bf16 GEMMs ---
        // x2 = xf + yb @ wo^T   (N=2048, K=2048, S=4 -> 512 blocks)
        gemm_mfma_k<0><<<dim3(16, 8, 4), 256, 0, stream>>>(yb, WoP, nullptr, fpo, 2048, 2048, 512, prep, flag);
        combine_k<4, 1><<<1024, 256, 0, stream>>>(fpo, xf, x2, 524288);
        rmsnorm_bf_k<<<TT, 256, 0, stream>>>(x2, ffn_nw, hb, 2048, flag);
        // gb2 = bf16(silu(hb@w1^T) * (hb@w3^T))   (N=8192, K=2048, 512 blocks)
        gemm_swiglu_k<<<dim3(64, 8), 256, 0, stream>>>(hb, W1P, W3P, gb2, 8192, 2048, prep, flag);
        // outb = x2 + gb2 @ w2^T   (N=2048, K=8192, S=4 -> 512 blocks)
        gemm_mfma_k<0><<<dim3(16, 8, 4), 256, 0, stream>>>(gb2, W2P, nullptr, fp2, 2048, 8192, 2048, prep, flag);
        combine_k<4, 1><<<1024, 256, 0, stream>>>(fp2, x2, outb, 524288);
    }
}

// Round 8
// 1324.521 us; speedup vs baseline: 2.5463x; 1.0151x over previous
//
#include <hip/hip_runtime.h>
#include <hip/hip_bf16.h>
#include <cstddef>

// DeepSeekBlock: B=2 T=1024 D=2048 H=16 NOPE=128 ROPE=64 QKD=192
// QLORA=1536 KVLORA=512 VHD=128 INTER=8192
// Round 13 (on passing round-12 @1344us):
//  - GEMM staging (wready/presplit paths) ported to __builtin_amdgcn_global_load_lds
//    width=16 (m97 pattern): per k-step {issue DMA -> barrier -> ds_read+MFMA ->
//    barrier}. No VGPR round-trip, no ds_write phase, less addr VALU.
//  - DMA needs linear LDS (wave-uniform base + lane*16B): tile [128][32] ushort.
//    Bank conflicts fixed BOTH-sides (rule #21): global source pre-swizzled
//    slot^=(row&3), read addr XORed identically -> 4-way (1.58x) instead of 8-way.
//  - Fallback (prep=0) keeps old reg-staged stride-40 layout in oversized raw LDS.
// Attention split-KV + swiglu fusion + single-launch split-K from round 12 kept.

#define TT 1024
#define DD 2048
#define QBLK 64
#define KVB 32

using bf16 = __hip_bfloat16;
typedef __attribute__((ext_vector_type(8))) short short8;
typedef __attribute__((ext_vector_type(8))) unsigned short ushort8v;
typedef __attribute__((ext_vector_type(4))) float f32x4;

__device__ __forceinline__ float us2f(unsigned short u) {
    return __uint_as_float(((unsigned int)u) << 16);
}
__device__ __forceinline__ float ldf(const void* p, size_t i, int isbf) {
    return isbf ? us2f(((const unsigned short*)p)[i]) : ((const float*)p)[i];
}
__device__ __forceinline__ unsigned short f2bf(float f) {
    __hip_bfloat16 b = __float2bfloat16(f);
    return *reinterpret_cast<unsigned short*>(&b);
}
// async global->LDS, 16B per lane; lds dest = wave-uniform base + lane*16B
__device__ __forceinline__ void gld16(const unsigned short* g, unsigned short* l) {
    __builtin_amdgcn_global_load_lds(
        (const __attribute__((address_space(1))) void*)g,
        (__attribute__((address_space(3))) void*)l, 16, 0, 0);
}

// ---------------- input dtype detection ----------------
__global__ __launch_bounds__(64) void detect_k(const void* __restrict__ x,
                                               int* __restrict__ flag)
{
    __shared__ int cnt;
    if (threadIdx.x == 0) cnt = 0;
    __syncthreads();
    const unsigned short* u = (const unsigned short*)x;
    int bad = 0;
    for (int i = threadIdx.x; i < 512; i += 64) {
        const float v = us2f(u[i]);
        const float a = fabsf(v);
        if (!(a < 1e6f) || (v != 0.0f && a < 1e-30f)) bad++;
    }
    atomicAdd(&cnt, bad);
    __syncthreads();
    if (threadIdx.x == 0) *flag = (cnt > 32) ? 0 : 1;   // 0 = f32, 1 = bf16
}

// ---------------- weight prep: any -> bf16 ----------------
__global__ __launch_bounds__(256) void cvt_bf_k(
    const void* __restrict__ src, unsigned short* __restrict__ dst,
    size_t n, const int* __restrict__ flag)
{
    const int isbf = *flag;
    const size_t stride = (size_t)gridDim.x * 2048;
    for (size_t i = ((size_t)blockIdx.x * 256 + threadIdx.x) * 8; i < n; i += stride) {
        if (isbf) {
            *(ushort8v*)(dst + i) = *(const ushort8v*)((const unsigned short*)src + i);
        } else {
            const float* s = (const float*)src + i;
            float4 f0 = *(const float4*)s, f1 = *(const float4*)(s + 4);
            unsigned short t[8] = {f2bf(f0.x), f2bf(f0.y), f2bf(f0.z), f2bf(f0.w),
                                   f2bf(f1.x), f2bf(f1.y), f2bf(f1.z), f2bf(f1.w)};
            *(ushort8v*)(dst + i) = *(const ushort8v*)t;
        }
    }
}

// ---------------- weight prep: any -> hi/lo bf16 pair ----------------
__global__ __launch_bounds__(256) void cvt_hl_k(
    const void* __restrict__ src, unsigned short* __restrict__ dh,
    unsigned short* __restrict__ dl, size_t n, const int* __restrict__ flag)
{
    const int isbf = *flag;
    const size_t stride = (size_t)gridDim.x * 2048;
    for (size_t i = ((size_t)blockIdx.x * 256 + threadIdx.x) * 8; i < n; i += stride) {
        unsigned short th[8], tl[8];
        if (isbf) {
            const unsigned short* s = (const unsigned short*)src + i;
#pragma unroll
            for (int u = 0; u < 8; ++u) { th[u] = s[u]; tl[u] = 0; }
        } else {
            const float* s = (const float*)src + i;
#pragma unroll
            for (int u = 0; u < 8; ++u) {
                const float v = s[u];
                th[u] = f2bf(v);
                tl[u] = f2bf(v - us2f(th[u]));
            }
        }
        *(ushort8v*)(dh + i) = *(const ushort8v*)th;
        *(ushort8v*)(dl + i) = *(const ushort8v*)tl;
    }
}

// ---------------- split-K combine: out = sum_{s<S} p[s] (+ R) ----------------
template <int S, int HASR>
__global__ __launch_bounds__(256) void combine_k(
    const float* __restrict__ p, const float* __restrict__ R,
    float* __restrict__ out, int n4)
{
    const int stride = gridDim.x * 256;
    const float4* pp = (const float4*)p;
    for (int i = blockIdx.x * 256 + threadIdx.x; i < n4; i += stride) {
        float4 o = pp[i];
#pragma unroll
        for (int s = 1; s < S; ++s) {
            const float4 b4 = pp[(size_t)s * n4 + i];
            o.x += b4.x; o.y += b4.y; o.z += b4.z; o.w += b4.w;
        }
        if (HASR) {
            const float4 r4 = ((const float4*)R)[i];
            o.x += r4.x; o.y += r4.y; o.z += r4.z; o.w += r4.w;
        }
        ((float4*)out)[i] = o;
    }
}

// ---------------- rmsnorm f32 -> hi/lo bf16 pair ----------------
__global__ __launch_bounds__(256) void rmsnorm_hl_k(
    const float* __restrict__ in, const void* __restrict__ w,
    unsigned short* __restrict__ oh, unsigned short* __restrict__ ol,
    int L, int istride, const int* __restrict__ flag)
{
    const int isbf = *flag;
    const int m = blockIdx.x, tid = threadIdx.x;
    const float* row = in + (size_t)m * istride;
    float ss = 0.f;
    for (int i = tid; i < L; i += 256) { float v = row[i]; ss += v * v; }
    __shared__ float red[256];
    red[tid] = ss; __syncthreads();
    for (int s = 128; s > 0; s >>= 1) {
        if (tid < s) red[tid] += red[tid + s];
        __syncthreads();
    }
    const float scale = 1.0f / sqrtf(red[0] / (float)L + 1e-6f);
    unsigned short* hrow = oh + (size_t)m * L;
    unsigned short* lrow = ol + (size_t)m * L;
    for (int i = tid; i < L; i += 256) {
        const float v = row[i] * scale * ldf(w, i, isbf);
        const unsigned short hi = f2bf(v);
        hrow[i] = hi;
        lrow[i] = f2bf(v - us2f(hi));
    }
}

// ---------------- rmsnorm f32->bf16 (FFN input) ----------------
__global__ __launch_bounds__(256) void rmsnorm_bf_k(
    const float* __restrict__ in, const void* __restrict__ w,
    unsigned short* __restrict__ out, int L,
    const int* __restrict__ flag)
{
    const int isbf = *flag;
    const int m = blockIdx.x, tid = threadIdx.x;
    const float* row = in + (size_t)m * L;
    float ss = 0.f;
    for (int i = tid; i < L; i += 256) { float v = row[i]; ss += v * v; }
    __shared__ float red[256];
    red[tid] = ss; __syncthreads();
    for (int s = 128; s > 0; s >>= 1) {
        if (tid < s) red[tid] += red[tid + s];
        __syncthreads();
    }
    const float scale = 1.0f / sqrtf(red[0] / (float)L + 1e-6f);
    unsigned short* orow = out + (size_t)m * L;
    for (int i = tid; i < L; i += 256)
        orow[i] = f2bf(row[i] * scale * ldf(w, i, isbf));
}

// rmsnorm on input x: writes hi/lo bf16 h and f32 residual copy
__global__ __launch_bounds__(256) void rmsnorm_x_hl_k(
    const void* __restrict__ x, size_t eoff, const void* __restrict__ w,
    unsigned short* __restrict__ hh, unsigned short* __restrict__ hl,
    float* __restrict__ xf, const int* __restrict__ flag)
{
    const int isbf = *flag;
    const int m = blockIdx.x, tid = threadIdx.x;
    const size_t base = eoff + (size_t)m * DD;
    float* xrow = xf + (size_t)m * DD;
    float ss = 0.f;
    float vals[8];
    for (int i = 0; i < 8; ++i) {
        float v = ldf(x, base + tid + 256 * i, isbf);
        vals[i] = v; ss += v * v;
        xrow[tid + 256 * i] = v;
    }
    __shared__ float red[256];
    red[tid] = ss; __syncthreads();
    for (int s = 128; s > 0; s >>= 1) {
        if (tid < s) red[tid] += red[tid + s];
        __syncthreads();
    }
    const float scale = 1.0f / sqrtf(red[0] / (float)DD + 1e-6f);
    unsigned short* hrow = hh + (size_t)m * DD;
    unsigned short* lrow = hl + (size_t)m * DD;
    for (int i = 0; i < 8; ++i) {
        const float v = vals[i] * scale * ldf(w, tid + 256 * i, isbf);
        const unsigned short hi = f2bf(v);
        hrow[tid + 256 * i] = hi;
        lrow[tid + 256 * i] = f2bf(v - us2f(hi));
    }
}

// ---------------- split-bf16 MFMA GEMM: C(M,N) f32 = (Ah+Al)(Wh+Wl)^T ----------------
// presplit=1: global_load_lds staging, linear [128][32] LDS, slot^(row&3) swizzle.
// presplit=0: old reg-staged stride-40 path. Split-K via gridDim.z.
__global__ __launch_bounds__(256) void gemm_mfma3_k(
    const unsigned short* __restrict__ Ah, const unsigned short* __restrict__ Al,
    const void* __restrict__ Wv, const unsigned short* __restrict__ Wlo,
    float* __restrict__ C, int N, int K, int klen,
    int presplit, const int* __restrict__ flag)
{
    __shared__ __align__(16) unsigned short lds[20480];
    const int tid = threadIdx.x;
    const int lane = tid & 63;
    const int wave = tid >> 6;
    const int wm = (wave >> 1) << 6, wn = (wave & 1) << 6;
    const int bm = blockIdx.y << 7, bn = blockIdx.x << 7;
    const int k0 = blockIdx.z * klen;
    const size_t zoff = (size_t)blockIdx.z * 1024 * N;
    const int frow = lane & 15;
    const int fk = (lane >> 4) << 3;
    const int kend = k0 + klen;

    f32x4 acc[4][4] = {};

    if (presplit) {
        unsigned short* Lah = lds;
        unsigned short* Lal = lds + 4096;
        unsigned short* Lwh = lds + 8192;
        unsigned short* Lwl = lds + 12288;
        const unsigned short* Whp = (const unsigned short*)Wv;
        const int lrow = lane >> 2;
        const int sp8 = ((lane & 3) ^ (lrow & 3)) << 3;
        const int rA0 = wave * 32 + lrow;
        const int rA1 = wave * 32 + 16 + lrow;
        const int wr0 = (bn + rA0 < N) ? bn + rA0 : N - 1;
        const int wr1 = (bn + rA1 < N) ? bn + rA1 : N - 1;
        const size_t gA0 = (size_t)(bm + rA0) * K + sp8;
        const size_t gA1 = (size_t)(bm + rA1) * K + sp8;
        const size_t gW0 = (size_t)wr0 * K + sp8;
        const size_t gW1 = (size_t)wr1 * K + sp8;
        unsigned short* d0 = lds + wave * 1024;          // per-wave region, +512 for j=1
        const int xa = ((fk >> 3) ^ (frow & 3)) << 3;

        for (int kt = k0; kt < kend; kt += 32) {
            gld16(Ah + gA0 + kt, Lah + wave * 1024);
            gld16(Ah + gA1 + kt, Lah + wave * 1024 + 512);
            gld16(Al + gA0 + kt, Lal + wave * 1024);
            gld16(Al + gA1 + kt, Lal + wave * 1024 + 512);
            gld16(Whp + gW0 + kt, Lwh + wave * 1024);
            gld16(Whp + gW1 + kt, Lwh + wave * 1024 + 512);
            gld16(Wlo + gW0 + kt, Lwl + wave * 1024);
            gld16(Wlo + gW1 + kt, Lwl + wave * 1024 + 512);
            __syncthreads();

            short8 afh[4], afl[4], bfh[4], bfl[4];
#pragma unroll
            for (int i = 0; i < 4; ++i) {
                afh[i] = *(const short8*)&Lah[(wm + i * 16 + frow) * 32 + xa];
                afl[i] = *(const short8*)&Lal[(wm + i * 16 + frow) * 32 + xa];
            }
#pragma unroll
            for (int j = 0; j < 4; ++j) {
                bfh[j] = *(const short8*)&Lwh[(wn + j * 16 + frow) * 32 + xa];
                bfl[j] = *(const short8*)&Lwl[(wn + j * 16 + frow) * 32 + xa];
            }
#pragma unroll
            for (int i = 0; i < 4; ++i)
#pragma unroll
                for (int j = 0; j < 4; ++j) {
                    acc[i][j] = __builtin_amdgcn_mfma_f32_16x16x32_bf16(
                        afh[i], bfh[j], acc[i][j], 0, 0, 0);
                    acc[i][j] = __builtin_amdgcn_mfma_f32_16x16x32_bf16(
                        afh[i], bfl[j], acc[i][j], 0, 0, 0);
                    acc[i][j] = __builtin_amdgcn_mfma_f32_16x16x32_bf16(
                        afl[i], bfh[j], acc[i][j], 0, 0, 0);
                }
            __syncthreads();
        }
        (void)d0;
    } else {
        unsigned short* Ash = lds;
        unsigned short* Asl = lds + 5120;
        unsigned short* Wsh = lds + 10240;
        unsigned short* Wsl = lds + 15360;
        const int isbf = *flag;
        const int srow = tid >> 1, scol = (tid & 1) << 4;
        const unsigned short* Ahld = Ah + (size_t)(bm + srow) * K + scol;
        const unsigned short* Alld = Al + (size_t)(bm + srow) * K + scol;
        const int wrow = bn + srow;
        const size_t wldbase = (size_t)((wrow < N) ? wrow : (N - 1)) * K + scol;
        unsigned short* Ahdst = &Ash[srow * 40 + scol];
        unsigned short* Aldst = &Asl[srow * 40 + scol];
        unsigned short* Whdst = &Wsh[srow * 40 + scol];
        unsigned short* Wldst = &Wsl[srow * 40 + scol];
        for (int kt = k0; kt < kend; kt += 32) {
            ushort8v a0h = *(const ushort8v*)(Ahld + kt);
            ushort8v a1h = *(const ushort8v*)(Ahld + kt + 8);
            ushort8v a0l = *(const ushort8v*)(Alld + kt);
            ushort8v a1l = *(const ushort8v*)(Alld + kt + 8);
            ushort8v w0h, w1h, w0l, w1l;
            if (isbf) {
                const unsigned short* Wp = (const unsigned short*)Wv + wldbase + kt;
                w0h = *(const ushort8v*)(Wp);
                w1h = *(const ushort8v*)(Wp + 8);
                w0l = w0h ^ w0h;
                w1l = w0l;
            } else {
                const float* Wp = (const float*)Wv + wldbase + kt;
                unsigned short th[16], tl[16];
#pragma unroll
                for (int t4 = 0; t4 < 4; ++t4) {
                    float4 f = *(const float4*)(Wp + 4 * t4);
                    float fv[4] = {f.x, f.y, f.z, f.w};
#pragma unroll
                    for (int u = 0; u < 4; ++u) {
                        const unsigned short hi = f2bf(fv[u]);
                        th[4 * t4 + u] = hi;
                        tl[4 * t4 + u] = f2bf(fv[u] - us2f(hi));
                    }
                }
                w0h = *(ushort8v*)&th[0]; w1h = *(ushort8v*)&th[8];
                w0l = *(ushort8v*)&tl[0]; w1l = *(ushort8v*)&tl[8];
            }
            __syncthreads();
            *(ushort8v*)Ahdst = a0h; *(ushort8v*)(Ahdst + 8) = a1h;
            *(ushort8v*)Aldst = a0l; *(ushort8v*)(Aldst + 8) = a1l;
            *(ushort8v*)Whdst = w0h; *(ushort8v*)(Whdst + 8) = w1h;
            *(ushort8v*)Wldst = w0l; *(ushort8v*)(Wldst + 8) = w1l;
            __syncthreads();

            short8 afh[4], afl[4], bfh[4], bfl[4];
#pragma unroll
            for (int i = 0; i < 4; ++i) {
                afh[i] = *(const short8*)&Ash[(wm + i * 16 + frow) * 40 + fk];
                afl[i] = *(const short8*)&Asl[(wm + i * 16 + frow) * 40 + fk];
            }
#pragma unroll
            for (int j = 0; j < 4; ++j) {
                bfh[j] = *(const short8*)&Wsh[(wn + j * 16 + frow) * 40 + fk];
                bfl[j] = *(const short8*)&Wsl[(wn + j * 16 + frow) * 40 + fk];
            }
#pragma unroll
            for (int i = 0; i < 4; ++i)
#pragma unroll
                for (int j = 0; j < 4; ++j) {
                    acc[i][j] = __builtin_amdgcn_mfma_f32_16x16x32_bf16(
                        afh[i], bfh[j], acc[i][j], 0, 0, 0);
                    acc[i][j] = __builtin_amdgcn_mfma_f32_16x16x32_bf16(
                        afh[i], bfl[j], acc[i][j], 0, 0, 0);
                    acc[i][j] = __builtin_amdgcn_mfma_f32_16x16x32_bf16(
                        afl[i], bfh[j], acc[i][j], 0, 0, 0);
                }
        }
    }

#pragma unroll
    for (int i = 0; i < 4; ++i) {
        const int r0 = bm + wm + i * 16 + ((lane >> 4) << 2);
#pragma unroll
        for (int j = 0; j < 4; ++j) {
            const int c = bn + wn + j * 16 + (lane & 15);
            if (c < N) {
#pragma unroll
                for (int g = 0; g < 4; ++g)
                    C[zoff + (size_t)(r0 + g) * N + c] = acc[i][j][g];
            }
        }
    }
}

// ---------------- bf16 MFMA GEMM (FFN path) ----------------
// wready=1: global_load_lds staging, linear [128][32] LDS, slot^(row&3) swizzle.
// EPI 0: f32 C = acc; EPI 1: f32 C = R + acc; EPI 3: bf16 C = bf16(silu(R)*acc).
template <int EPI>
__global__ __launch_bounds__(256) void gemm_mfma_k(
    const unsigned short* __restrict__ A, const void* __restrict__ Wv,
    const float* __restrict__ R, void* __restrict__ outp,
    int N, int K, int klen, int wready, const int* __restrict__ flag)
{
    __shared__ __align__(16) unsigned short lds[10240];
    const int tid = threadIdx.x;
    const int lane = tid & 63;
    const int wave = tid >> 6;
    const int wm = (wave >> 1) << 6, wn = (wave & 1) << 6;
    const int bm = blockIdx.y << 7, bn = blockIdx.x << 7;
    const int k0 = blockIdx.z * klen;
    const size_t zoff = (size_t)blockIdx.z * 1024 * N;
    const int frow = lane & 15;
    const int fk = (lane >> 4) << 3;
    const int kend = k0 + klen;

    f32x4 acc[4][4] = {};

    if (wready) {
        unsigned short* As = lds;
        unsigned short* Ws = lds + 4096;
        const unsigned short* Wp = (const unsigned short*)Wv;
        const int lrow = lane >> 2;
        const int sp8 = ((lane & 3) ^ (lrow & 3)) << 3;
        const int rA0 = wave * 32 + lrow;
        const int rA1 = wave * 32 + 16 + lrow;
        const size_t gA0 = (size_t)(bm + rA0) * K + sp8;
        const size_t gA1 = (size_t)(bm + rA1) * K + sp8;
        const size_t gW0 = (size_t)(bn + rA0) * K + sp8;
        const size_t gW1 = (size_t)(bn + rA1) * K + sp8;
        const int xa = ((fk >> 3) ^ (frow & 3)) << 3;

        for (int kt = k0; kt < kend; kt += 32) {
            gld16(A + gA0 + kt, As + wave * 1024);
            gld16(A + gA1 + kt, As + wave * 1024 + 512);
            gld16(Wp + gW0 + kt, Ws + wave * 1024);
            gld16(Wp + gW1 + kt, Ws + wave * 1024 + 512);
            __syncthreads();

            short8 af[4], bfr[4];
#pragma unroll
            for (int i = 0; i < 4; ++i)
                af[i] = *(const short8*)&As[(wm + i * 16 + frow) * 32 + xa];
#pragma unroll
            for (int j = 0; j < 4; ++j)
                bfr[j] = *(const short8*)&Ws[(wn + j * 16 + frow) * 32 + xa];
#pragma unroll
            for (int i = 0; i < 4; ++i)
#pragma unroll
                for (int j = 0; j < 4; ++j)
                    acc[i][j] = __builtin_amdgcn_mfma_f32_16x16x32_bf16(
                        af[i], bfr[j], acc[i][j], 0, 0, 0);
            __syncthreads();
        }
    } else {
        unsigned short* As = lds;
        unsigned short* Ws = lds + 5120;
        const int isbf = *flag;
        const int srow = tid >> 1, scol = (tid & 1) << 4;
        const unsigned short* Ald = A + (size_t)(bm + srow) * K + scol;
        const size_t wldbase = (size_t)(bn + srow) * K + scol;
        unsigned short* Adst = &As[srow * 40 + scol];
        unsigned short* Wdst = &Ws[srow * 40 + scol];
        for (int kt = k0; kt < kend; kt += 32) {
            ushort8v a0 = *(const ushort8v*)(Ald + kt);
            ushort8v a1 = *(const ushort8v*)(Ald + kt + 8);
            ushort8v w0, w1;
            if (isbf) {
                const unsigned short* Wpp = (const unsigned short*)Wv + wldbase + kt;
                w0 = *(const ushort8v*)(Wpp);
                w1 = *(const ushort8v*)(Wpp + 8);
            } else {
                const float* Wpp = (const float*)Wv + wldbase + kt;
                float4 f0 = *(const float4*)(Wpp);
                float4 f1 = *(const float4*)(Wpp + 4);
                float4 f2 = *(const float4*)(Wpp + 8);
                float4 f3 = *(const float4*)(Wpp + 12);
                unsigned short wt[16];
                wt[0] = f2bf(f0.x); wt[1] = f2bf(f0.y); wt[2]  = f2bf(f0.z); wt[3]  = f2bf(f0.w);
                wt[4] = f2bf(f1.x); wt[5] = f2bf(f1.y); wt[6]  = f2bf(f1.z); wt[7]  = f2bf(f1.w);
                wt[8] = f2bf(f2.x); wt[9] = f2bf(f2.y); wt[10] = f2bf(f2.z); wt[11] = f2bf(f2.w);
                wt[12] = f2bf(f3.x); wt[13] = f2bf(f3.y); wt[14] = f2bf(f3.z); wt[15] = f2bf(f3.w);
                w0 = *(const ushort8v*)&wt[0];
                w1 = *(const ushort8v*)&wt[8];
            }
            __syncthreads();
            *(ushort8v*)Adst = a0; *(ushort8v*)(Adst + 8) = a1;
            *(ushort8v*)Wdst = w0; *(ushort8v*)(Wdst + 8) = w1;
            __syncthreads();

            short8 af[4], bfr[4];
#pragma unroll
            for (int i = 0; i < 4; ++i)
                af[i] = *(const short8*)&As[(wm + i * 16 + frow) * 40 + fk];
#pragma unroll
            for (int j = 0; j < 4; ++j)
                bfr[j] = *(const short8*)&Ws[(wn + j * 16 + frow) * 40 + fk];
#pragma unroll
            for (int i = 0; i < 4; ++i)
#pragma unroll
                for (int j = 0; j < 4; ++j)
                    acc[i][j] = __builtin_amdgcn_mfma_f32_16x16x32_bf16(
                        af[i], bfr[j], acc[i][j], 0, 0, 0);
        }
    }

#pragma unroll
    for (int i = 0; i < 4; ++i) {
        const int r0 = bm + wm + i * 16 + ((lane >> 4) << 2);
#pragma unroll
        for (int j = 0; j < 4; ++j) {
            const int c = bn + wn + j * 16 + (lane & 15);
#pragma unroll
            for (int g = 0; g < 4; ++g) {
                const size_t idx = zoff + (size_t)(r0 + g) * N + c;
                const float v = acc[i][j][g];
                if (EPI == 0) {
                    ((float*)outp)[idx] = v;
                } else if (EPI == 1) {
                    ((float*)outp)[idx] = v + R[idx];
                } else {
                    const float gv = R[idx];
                    const float sg = 1.0f / (1.0f + __expf(-gv));
                    ((unsigned short*)outp)[idx] = f2bf(gv * sg * v);
                }
            }
        }
    }
}

// ---------------- fused swiglu GEMM: out = bf16(silu(A@W1^T) * (A@W3^T)) ----------------
__global__ __launch_bounds__(256) void gemm_swiglu_k(
    const unsigned short* __restrict__ A, const void* __restrict__ W1v,
    const void* __restrict__ W3v, unsigned short* __restrict__ outp,
    int N, int K, int wready, const int* __restrict__ flag)
{
    __shared__ __align__(16) unsigned short lds[15360];
    const int tid = threadIdx.x;
    const int lane = tid & 63;
    const int wave = tid >> 6;
    const int wm = (wave >> 1) << 6, wn = (wave & 1) << 6;
    const int bm = blockIdx.y << 7, bn = blockIdx.x << 7;
    const int frow = lane & 15;
    const int fk = (lane >> 4) << 3;

    f32x4 acc1[4][4] = {};
    f32x4 acc3[4][4] = {};

    if (wready) {
        unsigned short* As = lds;
        unsigned short* L1 = lds + 4096;
        unsigned short* L3 = lds + 8192;
        const unsigned short* W1p = (const unsigned short*)W1v;
        const unsigned short* W3p = (const unsigned short*)W3v;
        const int lrow = lane >> 2;
        const int sp8 = ((lane & 3) ^ (lrow & 3)) << 3;
        const int rA0 = wave * 32 + lrow;
        const int rA1 = wave * 32 + 16 + lrow;
        const size_t gA0 = (size_t)(bm + rA0) * K + sp8;
        const size_t gA1 = (size_t)(bm + rA1) * K + sp8;
        const size_t gW0 = (size_t)(bn + rA0) * K + sp8;
        const size_t gW1 = (size_t)(bn + rA1) * K + sp8;
        const int xa = ((fk >> 3) ^ (frow & 3)) << 3;

        for (int kt = 0; kt < K; kt += 32) {
            gld16(A + gA0 + kt, As + wave * 1024);
            gld16(A + gA1 + kt, As + wave * 1024 + 512);
            gld16(W1p + gW0 + kt, L1 + wave * 1024);
            gld16(W1p + gW1 + kt, L1 + wave * 1024 + 512);
            gld16(W3p + gW0 + kt, L3 + wave * 1024);
            gld16(W3p + gW1 + kt, L3 + wave * 1024 + 512);
            __syncthreads();

            short8 af[4], b1[4], b3[4];
#pragma unroll
            for (int i = 0; i < 4; ++i)
                af[i] = *(const short8*)&As[(wm + i * 16 + frow) * 32 + xa];
#pragma unroll
            for (int j = 0; j < 4; ++j) {
                b1[j] = *(const short8*)&L1[(wn + j * 16 + frow) * 32 + xa];
                b3[j] = *(const short8*)&L3[(wn + j * 16 + frow) * 32 + xa];
            }
#pragma unroll
            for (int i = 0; i < 4; ++i)
#pragma unroll
                for (int j = 0; j < 4; ++j) {
                    acc1[i][j] = __builtin_amdgcn_mfma_f32_16x16x32_bf16(
                        af[i], b1[j], acc1[i][j], 0, 0, 0);
                    acc3[i][j] = __builtin_amdgcn_mfma_f32_16x16x32_bf16(
                        af[i], b3[j], acc3[i][j], 0, 0, 0);
                }
            __syncthreads();
        }
    } else {
        unsigned short* As = lds;
        unsigned short* Ws1 = lds + 5120;
        unsigned short* Ws3 = lds + 10240;
        const int isbf = *flag;
        const int srow = tid >> 1, scol = (tid & 1) << 4;
        const unsigned short* Ald = A + (size_t)(bm + srow) * K + scol;
        const size_t wldbase = (size_t)(bn + srow) * K + scol;
        unsigned short* Adst = &As[srow * 40 + scol];
        unsigned short* W1dst = &Ws1[srow * 40 + scol];
        unsigned short* W3dst = &Ws3[srow * 40 + scol];
        for (int kt = 0; kt < K; kt += 32) {
            ushort8v a0 = *(const ushort8v*)(Ald + kt);
            ushort8v a1 = *(const ushort8v*)(Ald + kt + 8);
            ushort8v w10, w11, w30, w31;
            if (isbf) {
                const unsigned short* W1p = (const unsigned short*)W1v + wldbase + kt;
                const unsigned short* W3p = (const unsigned short*)W3v + wldbase + kt;
                w10 = *(const ushort8v*)(W1p); w11 = *(const ushort8v*)(W1p + 8);
                w30 = *(const ushort8v*)(W3p); w31 = *(const ushort8v*)(W3p + 8);
            } else {
                const float* W1p = (const float*)W1v + wldbase + kt;
                const float* W3p = (const float*)W3v + wldbase + kt;
                unsigned short t1[16], t3[16];
#pragma unroll
                for (int t4 = 0; t4 < 4; ++t4) {
                    float4 f1 = *(const float4*)(W1p + 4 * t4);
                    float4 f3 = *(const float4*)(W3p + 4 * t4);
                    float v1[4] = {f1.x, f1.y, f1.z, f1.w};
                    float v3[4] = {f3.x, f3.y, f3.z, f3.w};
#pragma unroll
                    for (int u = 0; u < 4; ++u) {
                        t1[4 * t4 + u] = f2bf(v1[u]);
                        t3[4 * t4 + u] = f2bf(v3[u]);
                    }
                }
                w10 = *(ushort8v*)&t1[0]; w11 = *(ushort8v*)&t1[8];
                w30 = *(ushort8v*)&t3[0]; w31 = *(ushort8v*)&t3[8];
            }
            __syncthreads();
            *(ushort8v*)Adst = a0; *(ushort8v*)(Adst + 8) = a1;
            *(ushort8v*)W1dst = w10; *(ushort8v*)(W1dst + 8) = w11;
            *(ushort8v*)W3dst = w30; *(ushort8v*)(W3dst + 8) = w31;
            __syncthreads();

            short8 af[4], b1[4], b3[4];
#pragma unroll
            for (int i = 0; i < 4; ++i)
                af[i] = *(const short8*)&As[(wm + i * 16 + frow) * 40 + fk];
#pragma unroll
            for (int j = 0; j < 4; ++j) {
                b1[j] = *(const short8*)&Ws1[(wn + j * 16 + frow) * 40 + fk];
                b3[j] = *(const short8*)&Ws3[(wn + j * 16 + frow) * 40 + fk];
            }
#pragma unroll
            for (int i = 0; i < 4; ++i)
#pragma unroll
                for (int j = 0; j < 4; ++j) {
                    acc1[i][j] = __builtin_amdgcn_mfma_f32_16x16x32_bf16(
                        af[i], b1[j], acc1[i][j], 0, 0, 0);
                    acc3[i][j] = __builtin_amdgcn_mfma_f32_16x16x32_bf16(
                        af[i], b3[j], acc3[i][j], 0, 0, 0);
                }
        }
    }

#pragma unroll
    for (int i = 0; i < 4; ++i) {
        const int r0 = bm + wm + i * 16 + ((lane >> 4) << 2);
#pragma unroll
        for (int j = 0; j < 4; ++j) {
            const int c = bn + wn + j * 16 + (lane & 15);
#pragma unroll
            for (int g = 0; g < 4; ++g) {
                const float gv = acc1[i][j][g];
                const float sg = 1.0f / (1.0f + __expf(-gv));
                outp[(size_t)(r0 + g) * N + c] = f2bf(gv * sg * acc3[i][j][g]);
            }
        }
    }
}

// ---------------- RoPE (interleaved pairs), in-place on q and k_pe ----------------
__global__ __launch_bounds__(256) void rope_k(
    float* __restrict__ qb, float* __restrict__ kva,
    const void* __restrict__ fc, const void* __restrict__ fs,
    const int* __restrict__ flag)
{
    const int isbf = *flag;
    const int t = blockIdx.x;
    const int tid = threadIdx.x;
    __shared__ float c[32], s[32];
    if (tid < 32) {
        c[tid] = ldf(fc, t * 32 + tid, isbf);
        s[tid] = ldf(fs, t * 32 + tid, isbf);
    }
    __syncthreads();
    for (int p = tid; p < 512; p += 256) {
        const int h = p >> 5, i = p & 31;
        float* base = qb + (size_t)t * 3072 + h * 192 + 128 + 2 * i;
        const float x0 = base[0], x1 = base[1];
        base[0] = x0 * c[i] - x1 * s[i];
        base[1] = x0 * s[i] + x1 * c[i];
    }
    if (tid < 32) {
        float* base = kva + (size_t)t * 576 + 512 + 2 * tid;
        const float x0 = base[0], x1 = base[1];
        base[0] = x0 * c[tid] - x1 * s[tid];
        base[1] = x0 * s[tid] + x1 * c[tid];
    }
}

// ---------------- KV prep: split K to hi/lo bf16 [h][t][192], transpose V ----------------
__global__ __launch_bounds__(256) void kvprep_k(
    const float* __restrict__ kvb,   // [1024][4096]
    const float* __restrict__ kva,   // [1024][576]
    unsigned short* __restrict__ kh, unsigned short* __restrict__ kl,
    unsigned short* __restrict__ vt)
{
    const int tt = blockIdx.x, h = blockIdx.y;
    const int tid = threadIdx.x;
    const int tbase = tt * 64;
    for (int i = tid; i < 64 * 192; i += 256) {
        const int t = i / 192, k = i % 192;
        const float v = (k < 128)
            ? kvb[(size_t)(tbase + t) * 4096 + h * 256 + k]
            : kva[(size_t)(tbase + t) * 576 + 512 + (k - 128)];
        const unsigned short hi = f2bf(v);
        const size_t o = ((size_t)h * 1024 + tbase + t) * 192 + k;
        kh[o] = hi;
        kl[o] = f2bf(v - us2f(hi));
    }
    __shared__ unsigned short Vl[128][72];
    for (int i = tid; i < 64 * 128; i += 256) {
        const int t = i >> 7, d = i & 127;
        Vl[d][t] = f2bf(kvb[(size_t)(tbase + t) * 4096 + h * 256 + 128 + d]);
    }
    __syncthreads();
    for (int i = tid; i < 128 * 64; i += 256) {
        const int d = i >> 6, t = i & 63;
        vt[((size_t)h * 128 + d) * 1024 + tbase + t] = Vl[d][t];
    }
}

// ---------------- MFMA flash attention, split-KV via blockIdx.z ----------------
__global__ __launch_bounds__(256) void attn_mfma_k(
    const float* __restrict__ qb,
    const unsigned short* __restrict__ kh,
    const unsigned short* __restrict__ kl,
    const unsigned short* __restrict__ vt,
    float* __restrict__ opart)
{
    const int qt = blockIdx.x, h = blockIdx.y, z = blockIdx.z;
    const int s0 = qt * QBLK;
    const int tid = threadIdx.x;
    const int lane = tid & 63, wave = tid >> 6;
    const int frow = lane & 15;
    const int fk8 = (lane >> 4) << 3;
    const int g4 = (lane >> 4) << 2;

    __shared__ __align__(16) unsigned short Ksh[KVB][200];
    __shared__ __align__(16) unsigned short Ksl[KVB][200];
    __shared__ __align__(16) unsigned short Vs[128][40];
    __shared__ __align__(16) unsigned short Ps[4][16][40];

    const int wrow0 = s0 + wave * 16;
    short8 qhf[6], qlf[6];
    {
        const float* qrow = qb + (size_t)(wrow0 + frow) * 3072 + h * 192 + fk8;
#pragma unroll
        for (int ks = 0; ks < 6; ++ks) {
            float4 f0 = *(const float4*)(qrow + ks * 32);
            float4 f1 = *(const float4*)(qrow + ks * 32 + 4);
            float fv[8] = {f0.x, f0.y, f0.z, f0.w, f1.x, f1.y, f1.z, f1.w};
            unsigned short th[8], tl[8];
#pragma unroll
            for (int u = 0; u < 8; ++u) {
                th[u] = f2bf(fv[u]);
                tl[u] = f2bf(fv[u] - us2f(th[u]));
            }
            qhf[ks] = *(short8*)th;
            qlf[ks] = *(short8*)tl;
        }
    }

    f32x4 O[8] = {};
    float m_run[4] = {-1e30f, -1e30f, -1e30f, -1e30f};
    float l_run[4] = {};

    const int t_beg = z * (qt + 1);
    const int t_end = t_beg + (qt + 1);
    for (int tt = t_beg; tt < t_end; ++tt) {
        const int t0 = tt * KVB;
        __syncthreads();
        for (int i = tid; i < KVB * 24; i += 256) {
            const int r = i / 24, c = (i % 24) * 8;
            const size_t gof = ((size_t)h * 1024 + t0 + r) * 192 + c;
            *(ushort8v*)&Ksh[r][c] = *(const ushort8v*)(kh + gof);
            *(ushort8v*)&Ksl[r][c] = *(const ushort8v*)(kl + gof);
        }
        for (int i = tid; i < 128 * 4; i += 256) {
            const int d = i >> 2, c = (i & 3) * 8;
            *(ushort8v*)&Vs[d][c] =
                *(const ushort8v*)(vt + ((size_t)h * 128 + d) * 1024 + t0 + c);
        }
        __syncthreads();

        const bool active = (t0 <= wrow0 + 15);
        if (active) {
            f32x4 s[2] = {};
#pragma unroll
            for (int j = 0; j < 2; ++j) {
                const unsigned short* kb = &Ksh[j * 16 + frow][fk8];
                const unsigned short* lb = &Ksl[j * 16 + frow][fk8];
#pragma unroll
                for (int ks = 0; ks < 6; ++ks) {
                    short8 bh = *(const short8*)(kb + ks * 32);
                    short8 bl = *(const short8*)(lb + ks * 32);
                    s[j] = __builtin_amdgcn_mfma_f32_16x16x32_bf16(qhf[ks], bh, s[j], 0, 0, 0);
                    s[j] = __builtin_amdgcn_mfma_f32_16x16x32_bf16(qhf[ks], bl, s[j], 0, 0, 0);
                    s[j] = __builtin_amdgcn_mfma_f32_16x16x32_bf16(qlf[ks], bh, s[j], 0, 0, 0);
                }
            }
            const bool edge = (t0 + KVB - 1 > wrow0);
            float sv[2][4];
#pragma unroll
            for (int j = 0; j < 2; ++j)
#pragma unroll
                for (int g = 0; g < 4; ++g) {
                    float v = s[j][g] * -96.0f;
                    if (edge) {
                        const int col = t0 + j * 16 + frow;
                        const int row = wrow0 + g4 + g;
                        if (col > row) v = -1e30f;
                    }
                    sv[j][g] = v;
                }
            float alpha[4];
#pragma unroll
            for (int g = 0; g < 4; ++g) {
                float mt = fmaxf(sv[0][g], sv[1][g]);
                mt = fmaxf(mt, __shfl_xor(mt, 1));
                mt = fmaxf(mt, __shfl_xor(mt, 2));
                mt = fmaxf(mt, __shfl_xor(mt, 4));
                mt = fmaxf(mt, __shfl_xor(mt, 8));
                const float mn = fmaxf(m_run[g], mt);
                alpha[g] = __expf(m_run[g] - mn);
                m_run[g] = mn;
                const float p0 = __expf(sv[0][g] - mn);
                const float p1 = __expf(sv[1][g] - mn);
                sv[0][g] = p0; sv[1][g] = p1;
                float ps = p0 + p1;
                ps += __shfl_xor(ps, 1);
                ps += __shfl_xor(ps, 2);
                ps += __shfl_xor(ps, 4);
                ps += __shfl_xor(ps, 8);
                l_run[g] = l_run[g] * alpha[g] + ps;
            }
#pragma unroll
            for (int jt = 0; jt < 8; ++jt)
#pragma unroll
                for (int g = 0; g < 4; ++g)
                    O[jt][g] *= alpha[g];
#pragma unroll
            for (int j = 0; j < 2; ++j)
#pragma unroll
                for (int g = 0; g < 4; ++g)
                    Ps[wave][g4 + g][j * 16 + frow] = f2bf(sv[j][g]);
        }
        __syncthreads();
        if (active) {
            short8 pa = *(const short8*)&Ps[wave][frow][fk8];
#pragma unroll
            for (int jt = 0; jt < 8; ++jt) {
                short8 vb = *(const short8*)&Vs[jt * 16 + frow][fk8];
                O[jt] = __builtin_amdgcn_mfma_f32_16x16x32_bf16(pa, vb, O[jt], 0, 0, 0);
            }
        }
    }

    // epilogue: unnormalized partial (O bf16, m, l)
#pragma unroll
    for (int g = 0; g < 4; ++g) {
        const int row = wrow0 + g4 + g;
        float* rec = opart + (((size_t)z * 1024 + row) * 16 + h) * 66;
        unsigned short* ob = (unsigned short*)rec;
#pragma unroll
        for (int jt = 0; jt < 8; ++jt)
            ob[jt * 16 + frow] = f2bf(O[jt][g]);
        if ((lane & 15) == 0) { rec[64] = m_run[g]; rec[65] = l_run[g]; }
    }
}

// ---------------- attention split-KV merge -> yb ----------------
__global__ __launch_bounds__(256) void attn_merge_k(
    const float* __restrict__ opart, unsigned short* __restrict__ y)
{
    const int r = blockIdx.x;
    for (int i = threadIdx.x; i < 2048; i += 256) {
        const int h = i >> 7, d = i & 127;
        const float* r0 = opart + (((size_t)r) * 16 + h) * 66;
        const float* r1 = opart + (((size_t)1024 + r) * 16 + h) * 66;
        const float m0 = r0[64], l0 = r0[65];
        const float m1 = r1[64], l1 = r1[65];
        const float mm = fmaxf(m0, m1);
        const float a0 = __expf(m0 - mm), a1 = __expf(m1 - mm);
        const float denom = l0 * a0 + l1 * a1;
        const float o0 = us2f(((const unsigned short*)r0)[d]);
        const float o1 = us2f(((const unsigned short*)r1)[d]);
        y[(size_t)r * 2048 + h * 128 + d] = f2bf((o0 * a0 + o1 * a1) / denom);
    }
}

extern "C" void kernel_launch(void* const* d_in, const int* in_sizes, int n_in,
                              void* d_out, int out_size, void* d_ws, size_t ws_size,
                              hipStream_t stream) {
    (void)in_sizes; (void)n_in; (void)out_size;
    const void* x       = d_in[0];
    const void* fcos    = d_in[2];
    const void* fsin    = d_in[3];
    const void* attn_nw = d_in[4];
    const void* wq_a    = d_in[5];
    const void* q_nw    = d_in[6];
    const void* wq_b    = d_in[7];
    const void* wkv_a   = d_in[8];
    const void* kv_nw   = d_in[9];
    const void* wkv_b   = d_in[10];
    const void* wo      = d_in[11];
    const void* ffn_nw  = d_in[12];
    const void* w1      = d_in[13];
    const void* w2      = d_in[14];
    const void* w3      = d_in[15];

    int* flag = (int*)d_ws;
    float* a  = (float*)d_ws + 64;
    const size_t M1 = 1048576;
    // Arena (float units), peak 16M floats = 64 MiB:
    float* xf  = a;                                               // [0,2M) f32 residual
    unsigned short* hh = (unsigned short*)(a + 2 * M1);           // [2M,3M)
    unsigned short* hl = (unsigned short*)(a + 3 * M1);           // [3M,4M)
    float* qa  = a + 4 * M1;                                      // [4M,5.5M)
    float* kva = a + 4 * M1;                                      // [4M,4.5625M) (qa dead)
    unsigned short* kvnh = (unsigned short*)(a + 4 * M1 + 655360);
    unsigned short* kvnl = (unsigned short*)(a + 4 * M1 + 655360 + 262144);
    unsigned short* qah = (unsigned short*)(a + 5 * M1 + 524288); // [5.5M,6.25M)
    unsigned short* qal = (unsigned short*)(a + 6 * M1 + 262144); // [6.25M,7M)
    float* qb  = a + 7 * M1;                                      // [7M,10M)
    float* kvb = a + 10 * M1;                                     // [10M,14M); dead after kvprep
    unsigned short* kh = (unsigned short*)(a + 2 * M1);           // [2M,3.5M)
    unsigned short* kl = (unsigned short*)(a + 5 * M1 + 524288);  // [5.5M,7M)
    unsigned short* vt = (unsigned short*)(a + 14 * M1);          // [14M,15M)
    unsigned short* yb = (unsigned short*)(a + 3 * M1 + 524288);  // [3.5M,4.5M)
    unsigned short* hb  = (unsigned short*)(a + 2 * M1);          // [2M,3M)
    unsigned short* gb2 = (unsigned short*)(a + 12 * M1);         // [12M,16M)
    float* x2  = xf;
    // Split-K partial arenas (stride = M*N floats per slice):
    float* sp  = a + 10 * M1;   // score path: [10M,16M)
    float* fpo = a + 5 * M1;    // wo: 4x2M = [5M,13M)  (yb [3.5M,4.5M) untouched)
    float* fp2 = a + 2 * M1;    // w2: 4x2M = [2M,10M)  (hb dead by then)
    // Attention split-KV partials: 2 x 1024 x 16 x 66 floats = 2.16M @ [10M,~12.2M)
    float* opart = a + 10 * M1;
    // Prepared weights (beyond 16M; only if ws_size allows):
    unsigned short* wo_b  = (unsigned short*)(a + 16 * M1);       // 4M us
    unsigned short* w1_b  = (unsigned short*)(a + 18 * M1);       // 16M us
    unsigned short* w3_b  = (unsigned short*)(a + 26 * M1);       // 16M us
    unsigned short* w2_b  = (unsigned short*)(a + 34 * M1);       // 16M us
    unsigned short* wqa_h = (unsigned short*)(a + 42 * M1);
    unsigned short* wqa_l = wqa_h + 3145728u;
    unsigned short* wqb_h = (unsigned short*)(a + 45 * M1);
    unsigned short* wqb_l = wqb_h + 4718592u;
    unsigned short* wkva_h = (unsigned short*)(a + 49 * M1 + 524288);
    unsigned short* wkva_l = wkva_h + 1179648u;
    unsigned short* wkvb_h = (unsigned short*)(a + 50 * M1 + 655360);
    unsigned short* wkvb_l = wkvb_h + 2097152u;
    const size_t NEED = 256 + (size_t)(52 * M1 + 655360) * 4;     // ~220.7 MB
    const int prep = (ws_size >= NEED) ? 1 : 0;

    detect_k<<<1, 64, 0, stream>>>(x, flag);

    if (prep) {
        cvt_bf_k<<<1024, 256, 0, stream>>>(wo, wo_b, (size_t)2048 * 2048, flag);
        cvt_bf_k<<<2048, 256, 0, stream>>>(w1, w1_b, (size_t)8192 * 2048, flag);
        cvt_bf_k<<<2048, 256, 0, stream>>>(w3, w3_b, (size_t)8192 * 2048, flag);
        cvt_bf_k<<<2048, 256, 0, stream>>>(w2, w2_b, (size_t)2048 * 8192, flag);
        cvt_hl_k<<<1024, 256, 0, stream>>>(wq_a, wqa_h, wqa_l, (size_t)1536 * 2048, flag);
        cvt_hl_k<<<1024, 256, 0, stream>>>(wq_b, wqb_h, wqb_l, (size_t)3072 * 1536, flag);
        cvt_hl_k<<<512, 256, 0, stream>>>(wkv_a, wkva_h, wkva_l, (size_t)576 * 2048, flag);
        cvt_hl_k<<<1024, 256, 0, stream>>>(wkv_b, wkvb_h, wkvb_l, (size_t)4096 * 512, flag);
    }
    const void* Wqa = prep ? (const void*)wqa_h : wq_a;
    const void* Wqb = prep ? (const void*)wqb_h : wq_b;
    const void* Wkva = prep ? (const void*)wkva_h : wkv_a;
    const void* Wkvb = prep ? (const void*)wkvb_h : wkv_b;
    const unsigned short* WqaL = prep ? wqa_l : nullptr;
    const unsigned short* WqbL = prep ? wqb_l : nullptr;
    const unsigned short* WkvaL = prep ? wkva_l : nullptr;
    const unsigned short* WkvbL = prep ? wkvb_l : nullptr;
    const void* WoP = prep ? (const void*)wo_b : wo;
    const void* W1P = prep ? (const void*)w1_b : w1;
    const void* W3P = prep ? (const void*)w3_b : w3;
    const void* W2P = prep ? (const void*)w2_b : w2;

    for (int b = 0; b < 2; ++b) {
        const size_t eoff = (size_t)b * TT * DD;
        float* outb = (float*)d_out + eoff;

        // --- attention path (split-bf16 MFMA score chain, single-launch split-K) ---
        rmsnorm_x_hl_k<<<TT, 256, 0, stream>>>(x, eoff, attn_nw, hh, hl, xf, flag);
        gemm_mfma3_k<<<dim3(12, 8, 4), 256, 0, stream>>>(hh, hl, Wqa, WqaL, sp, 1536, 2048, 512, prep, flag);
        combine_k<4, 0><<<1024, 256, 0, stream>>>(sp, nullptr, qa, 393216);
        rmsnorm_hl_k<<<TT, 256, 0, stream>>>(qa, q_nw, qah, qal, 1536, 1536, flag);
        gemm_mfma3_k<<<dim3(24, 8, 2), 256, 0, stream>>>(qah, qal, Wqb, WqbL, sp, 3072, 1536, 768, prep, flag);
        combine_k<2, 0><<<1024, 256, 0, stream>>>(sp, nullptr, qb, 786432);
        gemm_mfma3_k<<<dim3(5, 8, 8), 256, 0, stream>>>(hh, hl, Wkva, WkvaL, sp, 576, 2048, 256, prep, flag);
        combine_k<8, 0><<<1024, 256, 0, stream>>>(sp, nullptr, kva, 147456);
        rmsnorm_hl_k<<<TT, 256, 0, stream>>>(kva, kv_nw, kvnh, kvnl, 512, 576, flag);
        rope_k<<<TT, 256, 0, stream>>>(qb, kva, fcos, fsin, flag);
        gemm_mfma3_k<<<dim3(32, 8, 1), 256, 0, stream>>>(kvnh, kvnl, Wkvb, WkvbL, kvb, 4096, 512, 512, prep, flag);
        kvprep_k<<<dim3(16, 16), 256, 0, stream>>>(kvb, kva, kh, kl, vt);
        // flash attention, split-KV z=2 (kvb dead -> opart at [10M,~12.2M))
        attn_mfma_k<<<dim3(TT / QBLK, 16, 2), 256, 0, stream>>>(qb, kh, kl, vt, opart);
        attn_merge_k<<<TT, 256, 0, stream>>>(opart, yb);

        // --- FFN MFMA bf16 GEMMs ---
        // x2 = xf + yb @ wo^T   (N=2048, K=2048, S=4 -> 512 blocks)
        gemm_mfma_k<0><<<dim3(16, 8, 4), 256, 0, stream>>>(yb, WoP, nullptr, fpo, 2048, 2048, 512, prep, flag);
        combine_k<4, 1><<<1024, 256, 0, stream>>>(fpo, xf, x2, 524288);
        rmsnorm_bf_k<<<TT, 256, 0, stream>>>(x2, ffn_nw, hb, 2048, flag);
        // gb2 = bf16(silu(hb@w1^T) * (hb@w3^T))   (N=8192, K=2048, 512 blocks)
        gemm_swiglu_k<<<dim3(64, 8), 256, 0, stream>>>(hb, W1P, W3P, gb2, 8192, 2048, prep, flag);
        // outb = x2 + gb2 @ w2^T   (N=2048, K=8192, S=4 -> 512 blocks)
        gemm_mfma_k<0><<<dim3(16, 8, 4), 256, 0, stream>>>(gb2, W2P, nullptr, fp2, 2048, 8192, 2048, prep, flag);
        combine_k<4, 1><<<1024, 256, 0, stream>>>(fp2, x2, outb, 524288);
    }
}

// Round 9
// 1181.289 us; speedup vs baseline: 2.8550x; 1.1213x over previous
//
#include <hip/hip_runtime.h>
#include <hip/hip_bf16.h>
#include <cstddef>

// DeepSeekBlock: B=2 T=1024 D=2048 H=16 NOPE=128 ROPE=64 QKD=192
// QLORA=1536 KVLORA=512 VHD=128 INTER=8192
// Round 14 (on passing round-13 @1324us): BATCH FUSION — both batches in one pass,
// M=2048 everywhere (x/out are contiguous [2048][2048]).
//  - All GEMM grids double in y; dispatches 51 -> ~29; swiglu/attn at 4 blocks/CU.
//  - kvprep deleted: wkv_b epilogue writes kh/kl (hi/lo k_nope) + vt (V^T) directly
//    (epikv path); rope writes roped k_pe hi/lo into kh/kl for all heads.
//  - Attention: batch = qt>>4, causal in local coords, KV base = batch*1024.
// Arena (floats): xf[0,4M) hh[4,6M) hl[6,8M) sp[8,14M) qa[14,17M) qah/qal[8,11M)
//  qb[17,23M) wkv_a parts[8,12.5M) kva[12.5,13.625M) kvn[13.625,14.625M)
//  kh[4,7M) kl[7,10M) vt[10,12M) opart[12.5,16.625M) yb[4,6M) fpo[6,14M)
//  hb[4,6M) gb2[6,14M) fp2[14,22M). Peak 23M. Weights [23M,59.625M). NEED~238.6MB.

#define TT 1024
#define DD 2048
#define QBLK 64
#define KVB 32

using bf16 = __hip_bfloat16;
typedef __attribute__((ext_vector_type(8))) short short8;
typedef __attribute__((ext_vector_type(8))) unsigned short ushort8v;
typedef __attribute__((ext_vector_type(4))) float f32x4;

__device__ __forceinline__ float us2f(unsigned short u) {
    return __uint_as_float(((unsigned int)u) << 16);
}
__device__ __forceinline__ float ldf(const void* p, size_t i, int isbf) {
    return isbf ? us2f(((const unsigned short*)p)[i]) : ((const float*)p)[i];
}
__device__ __forceinline__ unsigned short f2bf(float f) {
    __hip_bfloat16 b = __float2bfloat16(f);
    return *reinterpret_cast<unsigned short*>(&b);
}
// async global->LDS, 16B per lane; lds dest = wave-uniform base + lane*16B
__device__ __forceinline__ void gld16(const unsigned short* g, unsigned short* l) {
    __builtin_amdgcn_global_load_lds(
        (const __attribute__((address_space(1))) void*)g,
        (__attribute__((address_space(3))) void*)l, 16, 0, 0);
}

// ---------------- input dtype detection ----------------
__global__ __launch_bounds__(64) void detect_k(const void* __restrict__ x,
                                               int* __restrict__ flag)
{
    __shared__ int cnt;
    if (threadIdx.x == 0) cnt = 0;
    __syncthreads();
    const unsigned short* u = (const unsigned short*)x;
    int bad = 0;
    for (int i = threadIdx.x; i < 512; i += 64) {
        const float v = us2f(u[i]);
        const float a = fabsf(v);
        if (!(a < 1e6f) || (v != 0.0f && a < 1e-30f)) bad++;
    }
    atomicAdd(&cnt, bad);
    __syncthreads();
    if (threadIdx.x == 0) *flag = (cnt > 32) ? 0 : 1;   // 0 = f32, 1 = bf16
}

// ---------------- weight prep: any -> bf16 ----------------
__global__ __launch_bounds__(256) void cvt_bf_k(
    const void* __restrict__ src, unsigned short* __restrict__ dst,
    size_t n, const int* __restrict__ flag)
{
    const int isbf = *flag;
    const size_t stride = (size_t)gridDim.x * 2048;
    for (size_t i = ((size_t)blockIdx.x * 256 + threadIdx.x) * 8; i < n; i += stride) {
        if (isbf) {
            *(ushort8v*)(dst + i) = *(const ushort8v*)((const unsigned short*)src + i);
        } else {
            const float* s = (const float*)src + i;
            float4 f0 = *(const float4*)s, f1 = *(const float4*)(s + 4);
            unsigned short t[8] = {f2bf(f0.x), f2bf(f0.y), f2bf(f0.z), f2bf(f0.w),
                                   f2bf(f1.x), f2bf(f1.y), f2bf(f1.z), f2bf(f1.w)};
            *(ushort8v*)(dst + i) = *(const ushort8v*)t;
        }
    }
}

// ---------------- weight prep: any -> hi/lo bf16 pair ----------------
__global__ __launch_bounds__(256) void cvt_hl_k(
    const void* __restrict__ src, unsigned short* __restrict__ dh,
    unsigned short* __restrict__ dl, size_t n, const int* __restrict__ flag)
{
    const int isbf = *flag;
    const size_t stride = (size_t)gridDim.x * 2048;
    for (size_t i = ((size_t)blockIdx.x * 256 + threadIdx.x) * 8; i < n; i += stride) {
        unsigned short th[8], tl[8];
        if (isbf) {
            const unsigned short* s = (const unsigned short*)src + i;
#pragma unroll
            for (int u = 0; u < 8; ++u) { th[u] = s[u]; tl[u] = 0; }
        } else {
            const float* s = (const float*)src + i;
#pragma unroll
            for (int u = 0; u < 8; ++u) {
                const float v = s[u];
                th[u] = f2bf(v);
                tl[u] = f2bf(v - us2f(th[u]));
            }
        }
        *(ushort8v*)(dh + i) = *(const ushort8v*)th;
        *(ushort8v*)(dl + i) = *(const ushort8v*)tl;
    }
}

// ---------------- split-K combine: out = sum_{s<S} p[s] (+ R) ----------------
template <int S, int HASR>
__global__ __launch_bounds__(256) void combine_k(
    const float* __restrict__ p, const float* __restrict__ R,
    float* __restrict__ out, int n4)
{
    const int stride = gridDim.x * 256;
    const float4* pp = (const float4*)p;
    for (int i = blockIdx.x * 256 + threadIdx.x; i < n4; i += stride) {
        float4 o = pp[i];
#pragma unroll
        for (int s = 1; s < S; ++s) {
            const float4 b4 = pp[(size_t)s * n4 + i];
            o.x += b4.x; o.y += b4.y; o.z += b4.z; o.w += b4.w;
        }
        if (HASR) {
            const float4 r4 = ((const float4*)R)[i];
            o.x += r4.x; o.y += r4.y; o.z += r4.z; o.w += r4.w;
        }
        ((float4*)out)[i] = o;
    }
}

// ---------------- rmsnorm f32 -> hi/lo bf16 pair ----------------
__global__ __launch_bounds__(256) void rmsnorm_hl_k(
    const float* __restrict__ in, const void* __restrict__ w,
    unsigned short* __restrict__ oh, unsigned short* __restrict__ ol,
    int L, int istride, const int* __restrict__ flag)
{
    const int isbf = *flag;
    const int m = blockIdx.x, tid = threadIdx.x;
    const float* row = in + (size_t)m * istride;
    float ss = 0.f;
    for (int i = tid; i < L; i += 256) { float v = row[i]; ss += v * v; }
    __shared__ float red[256];
    red[tid] = ss; __syncthreads();
    for (int s = 128; s > 0; s >>= 1) {
        if (tid < s) red[tid] += red[tid + s];
        __syncthreads();
    }
    const float scale = 1.0f / sqrtf(red[0] / (float)L + 1e-6f);
    unsigned short* hrow = oh + (size_t)m * L;
    unsigned short* lrow = ol + (size_t)m * L;
    for (int i = tid; i < L; i += 256) {
        const float v = row[i] * scale * ldf(w, i, isbf);
        const unsigned short hi = f2bf(v);
        hrow[i] = hi;
        lrow[i] = f2bf(v - us2f(hi));
    }
}

// ---------------- rmsnorm f32->bf16 (FFN input) ----------------
__global__ __launch_bounds__(256) void rmsnorm_bf_k(
    const float* __restrict__ in, const void* __restrict__ w,
    unsigned short* __restrict__ out, int L,
    const int* __restrict__ flag)
{
    const int isbf = *flag;
    const int m = blockIdx.x, tid = threadIdx.x;
    const float* row = in + (size_t)m * L;
    float ss = 0.f;
    for (int i = tid; i < L; i += 256) { float v = row[i]; ss += v * v; }
    __shared__ float red[256];
    red[tid] = ss; __syncthreads();
    for (int s = 128; s > 0; s >>= 1) {
        if (tid < s) red[tid] += red[tid + s];
        __syncthreads();
    }
    const float scale = 1.0f / sqrtf(red[0] / (float)L + 1e-6f);
    unsigned short* orow = out + (size_t)m * L;
    for (int i = tid; i < L; i += 256)
        orow[i] = f2bf(row[i] * scale * ldf(w, i, isbf));
}

// rmsnorm on input x (M=2048 rows): writes hi/lo bf16 h and f32 residual copy
__global__ __launch_bounds__(256) void rmsnorm_x_hl_k(
    const void* __restrict__ x, const void* __restrict__ w,
    unsigned short* __restrict__ hh, unsigned short* __restrict__ hl,
    float* __restrict__ xf, const int* __restrict__ flag)
{
    const int isbf = *flag;
    const int m = blockIdx.x, tid = threadIdx.x;
    const size_t base = (size_t)m * DD;
    float* xrow = xf + (size_t)m * DD;
    float ss = 0.f;
    float vals[8];
    for (int i = 0; i < 8; ++i) {
        float v = ldf(x, base + tid + 256 * i, isbf);
        vals[i] = v; ss += v * v;
        xrow[tid + 256 * i] = v;
    }
    __shared__ float red[256];
    red[tid] = ss; __syncthreads();
    for (int s = 128; s > 0; s >>= 1) {
        if (tid < s) red[tid] += red[tid + s];
        __syncthreads();
    }
    const float scale = 1.0f / sqrtf(red[0] / (float)DD + 1e-6f);
    unsigned short* hrow = hh + (size_t)m * DD;
    unsigned short* lrow = hl + (size_t)m * DD;
    for (int i = 0; i < 8; ++i) {
        const float v = vals[i] * scale * ldf(w, tid + 256 * i, isbf);
        const unsigned short hi = f2bf(v);
        hrow[tid + 256 * i] = hi;
        lrow[tid + 256 * i] = f2bf(v - us2f(hi));
    }
}

// ---------------- split-bf16 MFMA GEMM: C(M=2048,N) f32 = (Ah+Al)(Wh+Wl)^T -------
// presplit=1: global_load_lds staging, linear [128][32] LDS, slot^(row&3) swizzle.
// Split-K via gridDim.z (partial stride 2048*N). epikv=1 (wkv_b): epilogue writes
// kh/kl hi/lo for cols<128 of each head-block and V^T bf16 for cols>=128.
__global__ __launch_bounds__(256) void gemm_mfma3_k(
    const unsigned short* __restrict__ Ah, const unsigned short* __restrict__ Al,
    const void* __restrict__ Wv, const unsigned short* __restrict__ Wlo,
    float* __restrict__ C, int N, int K, int klen,
    int presplit, const int* __restrict__ flag,
    int epikv, unsigned short* __restrict__ okh,
    unsigned short* __restrict__ okl, unsigned short* __restrict__ ovt)
{
    __shared__ __align__(16) unsigned short lds[20480];
    const int tid = threadIdx.x;
    const int lane = tid & 63;
    const int wave = tid >> 6;
    const int wm = (wave >> 1) << 6, wn = (wave & 1) << 6;
    const int bm = blockIdx.y << 7, bn = blockIdx.x << 7;
    const int k0 = blockIdx.z * klen;
    const size_t zoff = (size_t)blockIdx.z * 2048 * N;
    const int frow = lane & 15;
    const int fk = (lane >> 4) << 3;
    const int kend = k0 + klen;

    f32x4 acc[4][4] = {};

    if (presplit) {
        unsigned short* Lah = lds;
        unsigned short* Lal = lds + 4096;
        unsigned short* Lwh = lds + 8192;
        unsigned short* Lwl = lds + 12288;
        const unsigned short* Whp = (const unsigned short*)Wv;
        const int lrow = lane >> 2;
        const int sp8 = ((lane & 3) ^ (lrow & 3)) << 3;
        const int rA0 = wave * 32 + lrow;
        const int rA1 = wave * 32 + 16 + lrow;
        const int wr0 = (bn + rA0 < N) ? bn + rA0 : N - 1;
        const int wr1 = (bn + rA1 < N) ? bn + rA1 : N - 1;
        const size_t gA0 = (size_t)(bm + rA0) * K + sp8;
        const size_t gA1 = (size_t)(bm + rA1) * K + sp8;
        const size_t gW0 = (size_t)wr0 * K + sp8;
        const size_t gW1 = (size_t)wr1 * K + sp8;
        const int xa = ((fk >> 3) ^ (frow & 3)) << 3;

        for (int kt = k0; kt < kend; kt += 32) {
            gld16(Ah + gA0 + kt, Lah + wave * 1024);
            gld16(Ah + gA1 + kt, Lah + wave * 1024 + 512);
            gld16(Al + gA0 + kt, Lal + wave * 1024);
            gld16(Al + gA1 + kt, Lal + wave * 1024 + 512);
            gld16(Whp + gW0 + kt, Lwh + wave * 1024);
            gld16(Whp + gW1 + kt, Lwh + wave * 1024 + 512);
            gld16(Wlo + gW0 + kt, Lwl + wave * 1024);
            gld16(Wlo + gW1 + kt, Lwl + wave * 1024 + 512);
            __syncthreads();

            short8 afh[4], afl[4], bfh[4], bfl[4];
#pragma unroll
            for (int i = 0; i < 4; ++i) {
                afh[i] = *(const short8*)&Lah[(wm + i * 16 + frow) * 32 + xa];
                afl[i] = *(const short8*)&Lal[(wm + i * 16 + frow) * 32 + xa];
            }
#pragma unroll
            for (int j = 0; j < 4; ++j) {
                bfh[j] = *(const short8*)&Lwh[(wn + j * 16 + frow) * 32 + xa];
                bfl[j] = *(const short8*)&Lwl[(wn + j * 16 + frow) * 32 + xa];
            }
#pragma unroll
            for (int i = 0; i < 4; ++i)
#pragma unroll
                for (int j = 0; j < 4; ++j) {
                    acc[i][j] = __builtin_amdgcn_mfma_f32_16x16x32_bf16(
                        afh[i], bfh[j], acc[i][j], 0, 0, 0);
                    acc[i][j] = __builtin_amdgcn_mfma_f32_16x16x32_bf16(
                        afh[i], bfl[j], acc[i][j], 0, 0, 0);
                    acc[i][j] = __builtin_amdgcn_mfma_f32_16x16x32_bf16(
                        afl[i], bfh[j], acc[i][j], 0, 0, 0);
                }
            __syncthreads();
        }
    } else {
        unsigned short* Ash = lds;
        unsigned short* Asl = lds + 5120;
        unsigned short* Wsh = lds + 10240;
        unsigned short* Wsl = lds + 15360;
        const int isbf = *flag;
        const int srow = tid >> 1, scol = (tid & 1) << 4;
        const unsigned short* Ahld = Ah + (size_t)(bm + srow) * K + scol;
        const unsigned short* Alld = Al + (size_t)(bm + srow) * K + scol;
        const int wrow = bn + srow;
        const size_t wldbase = (size_t)((wrow < N) ? wrow : (N - 1)) * K + scol;
        unsigned short* Ahdst = &Ash[srow * 40 + scol];
        unsigned short* Aldst = &Asl[srow * 40 + scol];
        unsigned short* Whdst = &Wsh[srow * 40 + scol];
        unsigned short* Wldst = &Wsl[srow * 40 + scol];
        for (int kt = k0; kt < kend; kt += 32) {
            ushort8v a0h = *(const ushort8v*)(Ahld + kt);
            ushort8v a1h = *(const ushort8v*)(Ahld + kt + 8);
            ushort8v a0l = *(const ushort8v*)(Alld + kt);
            ushort8v a1l = *(const ushort8v*)(Alld + kt + 8);
            ushort8v w0h, w1h, w0l, w1l;
            if (isbf) {
                const unsigned short* Wp = (const unsigned short*)Wv + wldbase + kt;
                w0h = *(const ushort8v*)(Wp);
                w1h = *(const ushort8v*)(Wp + 8);
                w0l = w0h ^ w0h;
                w1l = w0l;
            } else {
                const float* Wp = (const float*)Wv + wldbase + kt;
                unsigned short th[16], tl[16];
#pragma unroll
                for (int t4 = 0; t4 < 4; ++t4) {
                    float4 f = *(const float4*)(Wp + 4 * t4);
                    float fv[4] = {f.x, f.y, f.z, f.w};
#pragma unroll
                    for (int u = 0; u < 4; ++u) {
                        const unsigned short hi = f2bf(fv[u]);
                        th[4 * t4 + u] = hi;
                        tl[4 * t4 + u] = f2bf(fv[u] - us2f(hi));
                    }
                }
                w0h = *(ushort8v*)&th[0]; w1h = *(ushort8v*)&th[8];
                w0l = *(ushort8v*)&tl[0]; w1l = *(ushort8v*)&tl[8];
            }
            __syncthreads();
            *(ushort8v*)Ahdst = a0h; *(ushort8v*)(Ahdst + 8) = a1h;
            *(ushort8v*)Aldst = a0l; *(ushort8v*)(Aldst + 8) = a1l;
            *(ushort8v*)Whdst = w0h; *(ushort8v*)(Whdst + 8) = w1h;
            *(ushort8v*)Wldst = w0l; *(ushort8v*)(Wldst + 8) = w1l;
            __syncthreads();

            short8 afh[4], afl[4], bfh[4], bfl[4];
#pragma unroll
            for (int i = 0; i < 4; ++i) {
                afh[i] = *(const short8*)&Ash[(wm + i * 16 + frow) * 40 + fk];
                afl[i] = *(const short8*)&Asl[(wm + i * 16 + frow) * 40 + fk];
            }
#pragma unroll
            for (int j = 0; j < 4; ++j) {
                bfh[j] = *(const short8*)&Wsh[(wn + j * 16 + frow) * 40 + fk];
                bfl[j] = *(const short8*)&Wsl[(wn + j * 16 + frow) * 40 + fk];
            }
#pragma unroll
            for (int i = 0; i < 4; ++i)
#pragma unroll
                for (int j = 0; j < 4; ++j) {
                    acc[i][j] = __builtin_amdgcn_mfma_f32_16x16x32_bf16(
                        afh[i], bfh[j], acc[i][j], 0, 0, 0);
                    acc[i][j] = __builtin_amdgcn_mfma_f32_16x16x32_bf16(
                        afh[i], bfl[j], acc[i][j], 0, 0, 0);
                    acc[i][j] = __builtin_amdgcn_mfma_f32_16x16x32_bf16(
                        afl[i], bfh[j], acc[i][j], 0, 0, 0);
                }
        }
    }

    if (!epikv) {
#pragma unroll
        for (int i = 0; i < 4; ++i) {
            const int r0 = bm + wm + i * 16 + ((lane >> 4) << 2);
#pragma unroll
            for (int j = 0; j < 4; ++j) {
                const int c = bn + wn + j * 16 + (lane & 15);
                if (c < N) {
#pragma unroll
                    for (int g = 0; g < 4; ++g)
                        C[zoff + (size_t)(r0 + g) * N + c] = acc[i][j][g];
                }
            }
        }
    } else {
        // wkv_b: col = h*256 + cc; cc<128 -> k_nope hi/lo; cc>=128 -> V^T bf16
#pragma unroll
        for (int i = 0; i < 4; ++i) {
            const int r0 = bm + wm + i * 16 + ((lane >> 4) << 2);
#pragma unroll
            for (int j = 0; j < 4; ++j) {
                const int c = bn + wn + j * 16 + (lane & 15);
                const int h = c >> 8, cc = c & 255;
#pragma unroll
                for (int g = 0; g < 4; ++g) {
                    const int t = r0 + g;
                    const float v = acc[i][j][g];
                    if (cc < 128) {
                        const size_t o = ((size_t)h * 2048 + t) * 192 + cc;
                        const unsigned short hi = f2bf(v);
                        okh[o] = hi;
                        okl[o] = f2bf(v - us2f(hi));
                    } else {
                        ovt[((size_t)h * 128 + (cc - 128)) * 2048 + t] = f2bf(v);
                    }
                }
            }
        }
    }
}

// ---------------- bf16 MFMA GEMM (FFN path) ----------------
template <int EPI>
__global__ __launch_bounds__(256) void gemm_mfma_k(
    const unsigned short* __restrict__ A, const void* __restrict__ Wv,
    const float* __restrict__ R, void* __restrict__ outp,
    int N, int K, int klen, int wready, const int* __restrict__ flag)
{
    __shared__ __align__(16) unsigned short lds[10240];
    const int tid = threadIdx.x;
    const int lane = tid & 63;
    const int wave = tid >> 6;
    const int wm = (wave >> 1) << 6, wn = (wave & 1) << 6;
    const int bm = blockIdx.y << 7, bn = blockIdx.x << 7;
    const int k0 = blockIdx.z * klen;
    const size_t zoff = (size_t)blockIdx.z * 2048 * N;
    const int frow = lane & 15;
    const int fk = (lane >> 4) << 3;
    const int kend = k0 + klen;

    f32x4 acc[4][4] = {};

    if (wready) {
        unsigned short* As = lds;
        unsigned short* Ws = lds + 4096;
        const unsigned short* Wp = (const unsigned short*)Wv;
        const int lrow = lane >> 2;
        const int sp8 = ((lane & 3) ^ (lrow & 3)) << 3;
        const int rA0 = wave * 32 + lrow;
        const int rA1 = wave * 32 + 16 + lrow;
        const size_t gA0 = (size_t)(bm + rA0) * K + sp8;
        const size_t gA1 = (size_t)(bm + rA1) * K + sp8;
        const size_t gW0 = (size_t)(bn + rA0) * K + sp8;
        const size_t gW1 = (size_t)(bn + rA1) * K + sp8;
        const int xa = ((fk >> 3) ^ (frow & 3)) << 3;

        for (int kt = k0; kt < kend; kt += 32) {
            gld16(A + gA0 + kt, As + wave * 1024);
            gld16(A + gA1 + kt, As + wave * 1024 + 512);
            gld16(Wp + gW0 + kt, Ws + wave * 1024);
            gld16(Wp + gW1 + kt, Ws + wave * 1024 + 512);
            __syncthreads();

            short8 af[4], bfr[4];
#pragma unroll
            for (int i = 0; i < 4; ++i)
                af[i] = *(const short8*)&As[(wm + i * 16 + frow) * 32 + xa];
#pragma unroll
            for (int j = 0; j < 4; ++j)
                bfr[j] = *(const short8*)&Ws[(wn + j * 16 + frow) * 32 + xa];
#pragma unroll
            for (int i = 0; i < 4; ++i)
#pragma unroll
                for (int j = 0; j < 4; ++j)
                    acc[i][j] = __builtin_amdgcn_mfma_f32_16x16x32_bf16(
                        af[i], bfr[j], acc[i][j], 0, 0, 0);
            __syncthreads();
        }
    } else {
        unsigned short* As = lds;
        unsigned short* Ws = lds + 5120;
        const int isbf = *flag;
        const int srow = tid >> 1, scol = (tid & 1) << 4;
        const unsigned short* Ald = A + (size_t)(bm + srow) * K + scol;
        const size_t wldbase = (size_t)(bn + srow) * K + scol;
        unsigned short* Adst = &As[srow * 40 + scol];
        unsigned short* Wdst = &Ws[srow * 40 + scol];
        for (int kt = k0; kt < kend; kt += 32) {
            ushort8v a0 = *(const ushort8v*)(Ald + kt);
            ushort8v a1 = *(const ushort8v*)(Ald + kt + 8);
            ushort8v w0, w1;
            if (isbf) {
                const unsigned short* Wpp = (const unsigned short*)Wv + wldbase + kt;
                w0 = *(const ushort8v*)(Wpp);
                w1 = *(const ushort8v*)(Wpp + 8);
            } else {
                const float* Wpp = (const float*)Wv + wldbase + kt;
                float4 f0 = *(const float4*)(Wpp);
                float4 f1 = *(const float4*)(Wpp + 4);
                float4 f2 = *(const float4*)(Wpp + 8);
                float4 f3 = *(const float4*)(Wpp + 12);
                unsigned short wt[16];
                wt[0] = f2bf(f0.x); wt[1] = f2bf(f0.y); wt[2]  = f2bf(f0.z); wt[3]  = f2bf(f0.w);
                wt[4] = f2bf(f1.x); wt[5] = f2bf(f1.y); wt[6]  = f2bf(f1.z); wt[7]  = f2bf(f1.w);
                wt[8] = f2bf(f2.x); wt[9] = f2bf(f2.y); wt[10] = f2bf(f2.z); wt[11] = f2bf(f2.w);
                wt[12] = f2bf(f3.x); wt[13] = f2bf(f3.y); wt[14] = f2bf(f3.z); wt[15] = f2bf(f3.w);
                w0 = *(const ushort8v*)&wt[0];
                w1 = *(const ushort8v*)&wt[8];
            }
            __syncthreads();
            *(ushort8v*)Adst = a0; *(ushort8v*)(Adst + 8) = a1;
            *(ushort8v*)Wdst = w0; *(ushort8v*)(Wdst + 8) = w1;
            __syncthreads();

            short8 af[4], bfr[4];
#pragma unroll
            for (int i = 0; i < 4; ++i)
                af[i] = *(const short8*)&As[(wm + i * 16 + frow) * 40 + fk];
#pragma unroll
            for (int j = 0; j < 4; ++j)
                bfr[j] = *(const short8*)&Ws[(wn + j * 16 + frow) * 40 + fk];
#pragma unroll
            for (int i = 0; i < 4; ++i)
#pragma unroll
                for (int j = 0; j < 4; ++j)
                    acc[i][j] = __builtin_amdgcn_mfma_f32_16x16x32_bf16(
                        af[i], bfr[j], acc[i][j], 0, 0, 0);
        }
    }

#pragma unroll
    for (int i = 0; i < 4; ++i) {
        const int r0 = bm + wm + i * 16 + ((lane >> 4) << 2);
#pragma unroll
        for (int j = 0; j < 4; ++j) {
            const int c = bn + wn + j * 16 + (lane & 15);
#pragma unroll
            for (int g = 0; g < 4; ++g) {
                const size_t idx = zoff + (size_t)(r0 + g) * N + c;
                const float v = acc[i][j][g];
                if (EPI == 0) {
                    ((float*)outp)[idx] = v;
                } else if (EPI == 1) {
                    ((float*)outp)[idx] = v + R[idx];
                } else {
                    const float gv = R[idx];
                    const float sg = 1.0f / (1.0f + __expf(-gv));
                    ((unsigned short*)outp)[idx] = f2bf(gv * sg * v);
                }
            }
        }
    }
}

// ---------------- fused swiglu GEMM: out = bf16(silu(A@W1^T) * (A@W3^T)) --------
__global__ __launch_bounds__(256) void gemm_swiglu_k(
    const unsigned short* __restrict__ A, const void* __restrict__ W1v,
    const void* __restrict__ W3v, unsigned short* __restrict__ outp,
    int N, int K, int wready, const int* __restrict__ flag)
{
    __shared__ __align__(16) unsigned short lds[15360];
    const int tid = threadIdx.x;
    const int lane = tid & 63;
    const int wave = tid >> 6;
    const int wm = (wave >> 1) << 6, wn = (wave & 1) << 6;
    const int bm = blockIdx.y << 7, bn = blockIdx.x << 7;
    const int frow = lane & 15;
    const int fk = (lane >> 4) << 3;

    f32x4 acc1[4][4] = {};
    f32x4 acc3[4][4] = {};

    if (wready) {
        unsigned short* As = lds;
        unsigned short* L1 = lds + 4096;
        unsigned short* L3 = lds + 8192;
        const unsigned short* W1p = (const unsigned short*)W1v;
        const unsigned short* W3p = (const unsigned short*)W3v;
        const int lrow = lane >> 2;
        const int sp8 = ((lane & 3) ^ (lrow & 3)) << 3;
        const int rA0 = wave * 32 + lrow;
        const int rA1 = wave * 32 + 16 + lrow;
        const size_t gA0 = (size_t)(bm + rA0) * K + sp8;
        const size_t gA1 = (size_t)(bm + rA1) * K + sp8;
        const size_t gW0 = (size_t)(bn + rA0) * K + sp8;
        const size_t gW1 = (size_t)(bn + rA1) * K + sp8;
        const int xa = ((fk >> 3) ^ (frow & 3)) << 3;

        for (int kt = 0; kt < K; kt += 32) {
            gld16(A + gA0 + kt, As + wave * 1024);
            gld16(A + gA1 + kt, As + wave * 1024 + 512);
            gld16(W1p + gW0 + kt, L1 + wave * 1024);
            gld16(W1p + gW1 + kt, L1 + wave * 1024 + 512);
            gld16(W3p + gW0 + kt, L3 + wave * 1024);
            gld16(W3p + gW1 + kt, L3 + wave * 1024 + 512);
            __syncthreads();

            short8 af[4], b1[4], b3[4];
#pragma unroll
            for (int i = 0; i < 4; ++i)
                af[i] = *(const short8*)&As[(wm + i * 16 + frow) * 32 + xa];
#pragma unroll
            for (int j = 0; j < 4; ++j) {
                b1[j] = *(const short8*)&L1[(wn + j * 16 + frow) * 32 + xa];
                b3[j] = *(const short8*)&L3[(wn + j * 16 + frow) * 32 + xa];
            }
#pragma unroll
            for (int i = 0; i < 4; ++i)
#pragma unroll
                for (int j = 0; j < 4; ++j) {
                    acc1[i][j] = __builtin_amdgcn_mfma_f32_16x16x32_bf16(
                        af[i], b1[j], acc1[i][j], 0, 0, 0);
                    acc3[i][j] = __builtin_amdgcn_mfma_f32_16x16x32_bf16(
                        af[i], b3[j], acc3[i][j], 0, 0, 0);
                }
            __syncthreads();
        }
    } else {
        unsigned short* As = lds;
        unsigned short* Ws1 = lds + 5120;
        unsigned short* Ws3 = lds + 10240;
        const int isbf = *flag;
        const int srow = tid >> 1, scol = (tid & 1) << 4;
        const unsigned short* Ald = A + (size_t)(bm + srow) * K + scol;
        const size_t wldbase = (size_t)(bn + srow) * K + scol;
        unsigned short* Adst = &As[srow * 40 + scol];
        unsigned short* W1dst = &Ws1[srow * 40 + scol];
        unsigned short* W3dst = &Ws3[srow * 40 + scol];
        for (int kt = 0; kt < K; kt += 32) {
            ushort8v a0 = *(const ushort8v*)(Ald + kt);
            ushort8v a1 = *(const ushort8v*)(Ald + kt + 8);
            ushort8v w10, w11, w30, w31;
            if (isbf) {
                const unsigned short* W1p = (const unsigned short*)W1v + wldbase + kt;
                const unsigned short* W3p = (const unsigned short*)W3v + wldbase + kt;
                w10 = *(const ushort8v*)(W1p); w11 = *(const ushort8v*)(W1p + 8);
                w30 = *(const ushort8v*)(W3p); w31 = *(const ushort8v*)(W3p + 8);
            } else {
                const float* W1p = (const float*)W1v + wldbase + kt;
                const float* W3p = (const float*)W3v + wldbase + kt;
                unsigned short t1[16], t3[16];
#pragma unroll
                for (int t4 = 0; t4 < 4; ++t4) {
                    float4 f1 = *(const float4*)(W1p + 4 * t4);
                    float4 f3 = *(const float4*)(W3p + 4 * t4);
                    float v1[4] = {f1.x, f1.y, f1.z, f1.w};
                    float v3[4] = {f3.x, f3.y, f3.z, f3.w};
#pragma unroll
                    for (int u = 0; u < 4; ++u) {
                        t1[4 * t4 + u] = f2bf(v1[u]);
                        t3[4 * t4 + u] = f2bf(v3[u]);
                    }
                }
                w10 = *(ushort8v*)&t1[0]; w11 = *(ushort8v*)&t1[8];
                w30 = *(ushort8v*)&t3[0]; w31 = *(ushort8v*)&t3[8];
            }
            __syncthreads();
            *(ushort8v*)Adst = a0; *(ushort8v*)(Adst + 8) = a1;
            *(ushort8v*)W1dst = w10; *(ushort8v*)(W1dst + 8) = w11;
            *(ushort8v*)W3dst = w30; *(ushort8v*)(W3dst + 8) = w31;
            __syncthreads();

            short8 af[4], b1[4], b3[4];
#pragma unroll
            for (int i = 0; i < 4; ++i)
                af[i] = *(const short8*)&As[(wm + i * 16 + frow) * 40 + fk];
#pragma unroll
            for (int j = 0; j < 4; ++j) {
                b1[j] = *(const short8*)&Ws1[(wn + j * 16 + frow) * 40 + fk];
                b3[j] = *(const short8*)&Ws3[(wn + j * 16 + frow) * 40 + fk];
            }
#pragma unroll
            for (int i = 0; i < 4; ++i)
#pragma unroll
                for (int j = 0; j < 4; ++j) {
                    acc1[i][j] = __builtin_amdgcn_mfma_f32_16x16x32_bf16(
                        af[i], b1[j], acc1[i][j], 0, 0, 0);
                    acc3[i][j] = __builtin_amdgcn_mfma_f32_16x16x32_bf16(
                        af[i], b3[j], acc3[i][j], 0, 0, 0);
                }
        }
    }

#pragma unroll
    for (int i = 0; i < 4; ++i) {
        const int r0 = bm + wm + i * 16 + ((lane >> 4) << 2);
#pragma unroll
        for (int j = 0; j < 4; ++j) {
            const int c = bn + wn + j * 16 + (lane & 15);
#pragma unroll
            for (int g = 0; g < 4; ++g) {
                const float gv = acc1[i][j][g];
                const float sg = 1.0f / (1.0f + __expf(-gv));
                outp[(size_t)(r0 + g) * N + c] = f2bf(gv * sg * acc3[i][j][g]);
            }
        }
    }
}

// ---------------- RoPE (M=2048 rows): q + k_pe in place; k_pe hi/lo -> kh/kl ----
__global__ __launch_bounds__(256) void rope_k(
    float* __restrict__ qb, float* __restrict__ kva,
    unsigned short* __restrict__ kh, unsigned short* __restrict__ kl,
    const void* __restrict__ fc, const void* __restrict__ fs,
    const int* __restrict__ flag)
{
    const int isbf = *flag;
    const int r = blockIdx.x;
    const int t = r & 1023;
    const int tid = threadIdx.x;
    __shared__ float c[32], s[32];
    if (tid < 32) {
        c[tid] = ldf(fc, t * 32 + tid, isbf);
        s[tid] = ldf(fs, t * 32 + tid, isbf);
    }
    __syncthreads();
    for (int p = tid; p < 512; p += 256) {
        const int h = p >> 5, i = p & 31;
        float* base = qb + (size_t)r * 3072 + h * 192 + 128 + 2 * i;
        const float x0 = base[0], x1 = base[1];
        base[0] = x0 * c[i] - x1 * s[i];
        base[1] = x0 * s[i] + x1 * c[i];
    }
    if (tid < 32) {
        float* base = kva + (size_t)r * 576 + 512 + 2 * tid;
        const float x0 = base[0], x1 = base[1];
        const float r0 = x0 * c[tid] - x1 * s[tid];
        const float r1 = x0 * s[tid] + x1 * c[tid];
        base[0] = r0;
        base[1] = r1;
        const unsigned short h0 = f2bf(r0), h1 = f2bf(r1);
        const unsigned short l0 = f2bf(r0 - us2f(h0)), l1 = f2bf(r1 - us2f(h1));
#pragma unroll
        for (int h = 0; h < 16; ++h) {
            const size_t o = ((size_t)h * 2048 + r) * 192 + 128 + 2 * tid;
            kh[o] = h0; kh[o + 1] = h1;
            kl[o] = l0; kl[o + 1] = l1;
        }
    }
}

// ---------------- MFMA flash attention, batch via qt>>4, split-KV via z ---------
__global__ __launch_bounds__(256) void attn_mfma_k(
    const float* __restrict__ qb,
    const unsigned short* __restrict__ kh,
    const unsigned short* __restrict__ kl,
    const unsigned short* __restrict__ vt,
    float* __restrict__ opart)
{
    const int qtg = blockIdx.x, h = blockIdx.y, z = blockIdx.z;
    const int batch = qtg >> 4;
    const int lqt = qtg & 15;
    const int tb = batch << 10;
    const int tid = threadIdx.x;
    const int lane = tid & 63, wave = tid >> 6;
    const int frow = lane & 15;
    const int fk8 = (lane >> 4) << 3;
    const int g4 = (lane >> 4) << 2;

    __shared__ __align__(16) unsigned short Ksh[KVB][200];
    __shared__ __align__(16) unsigned short Ksl[KVB][200];
    __shared__ __align__(16) unsigned short Vs[128][40];
    __shared__ __align__(16) unsigned short Ps[4][16][40];

    const int wrow0l = lqt * QBLK + wave * 16;      // local
    const int wrow0g = qtg * QBLK + wave * 16;      // global
    short8 qhf[6], qlf[6];
    {
        const float* qrow = qb + (size_t)(wrow0g + frow) * 3072 + h * 192 + fk8;
#pragma unroll
        for (int ks = 0; ks < 6; ++ks) {
            float4 f0 = *(const float4*)(qrow + ks * 32);
            float4 f1 = *(const float4*)(qrow + ks * 32 + 4);
            float fv[8] = {f0.x, f0.y, f0.z, f0.w, f1.x, f1.y, f1.z, f1.w};
            unsigned short th[8], tl[8];
#pragma unroll
            for (int u = 0; u < 8; ++u) {
                th[u] = f2bf(fv[u]);
                tl[u] = f2bf(fv[u] - us2f(th[u]));
            }
            qhf[ks] = *(short8*)th;
            qlf[ks] = *(short8*)tl;
        }
    }

    f32x4 O[8] = {};
    float m_run[4] = {-1e30f, -1e30f, -1e30f, -1e30f};
    float l_run[4] = {};

    const int t_beg = z * (lqt + 1);
    const int t_end = t_beg + (lqt + 1);
    for (int tt = t_beg; tt < t_end; ++tt) {
        const int t0l = tt * KVB;
        const int t0g = tb + t0l;
        __syncthreads();
        for (int i = tid; i < KVB * 24; i += 256) {
            const int r = i / 24, c = (i % 24) * 8;
            const size_t gof = ((size_t)h * 2048 + t0g + r) * 192 + c;
            *(ushort8v*)&Ksh[r][c] = *(const ushort8v*)(kh + gof);
            *(ushort8v*)&Ksl[r][c] = *(const ushort8v*)(kl + gof);
        }
        for (int i = tid; i < 128 * 4; i += 256) {
            const int d = i >> 2, c = (i & 3) * 8;
            *(ushort8v*)&Vs[d][c] =
                *(const ushort8v*)(vt + ((size_t)h * 128 + d) * 2048 + t0g + c);
        }
        __syncthreads();

        const bool active = (t0l <= wrow0l + 15);
        if (active) {
            f32x4 s[2] = {};
#pragma unroll
            for (int j = 0; j < 2; ++j) {
                const unsigned short* kb = &Ksh[j * 16 + frow][fk8];
                const unsigned short* lb = &Ksl[j * 16 + frow][fk8];
#pragma unroll
                for (int ks = 0; ks < 6; ++ks) {
                    short8 bh = *(const short8*)(kb + ks * 32);
                    short8 bl = *(const short8*)(lb + ks * 32);
                    s[j] = __builtin_amdgcn_mfma_f32_16x16x32_bf16(qhf[ks], bh, s[j], 0, 0, 0);
                    s[j] = __builtin_amdgcn_mfma_f32_16x16x32_bf16(qhf[ks], bl, s[j], 0, 0, 0);
                    s[j] = __builtin_amdgcn_mfma_f32_16x16x32_bf16(qlf[ks], bh, s[j], 0, 0, 0);
                }
            }
            const bool edge = (t0l + KVB - 1 > wrow0l);
            float sv[2][4];
#pragma unroll
            for (int j = 0; j < 2; ++j)
#pragma unroll
                for (int g = 0; g < 4; ++g) {
                    float v = s[j][g] * -96.0f;
                    if (edge) {
                        const int col = t0l + j * 16 + frow;
                        const int row = wrow0l + g4 + g;
                        if (col > row) v = -1e30f;
                    }
                    sv[j][g] = v;
                }
            float alpha[4];
#pragma unroll
            for (int g = 0; g < 4; ++g) {
                float mt = fmaxf(sv[0][g], sv[1][g]);
                mt = fmaxf(mt, __shfl_xor(mt, 1));
                mt = fmaxf(mt, __shfl_xor(mt, 2));
                mt = fmaxf(mt, __shfl_xor(mt, 4));
                mt = fmaxf(mt, __shfl_xor(mt, 8));
                const float mn = fmaxf(m_run[g], mt);
                alpha[g] = __expf(m_run[g] - mn);
                m_run[g] = mn;
                const float p0 = __expf(sv[0][g] - mn);
                const float p1 = __expf(sv[1][g] - mn);
                sv[0][g] = p0; sv[1][g] = p1;
                float ps = p0 + p1;
                ps += __shfl_xor(ps, 1);
                ps += __shfl_xor(ps, 2);
                ps += __shfl_xor(ps, 4);
                ps += __shfl_xor(ps, 8);
                l_run[g] = l_run[g] * alpha[g] + ps;
            }
#pragma unroll
            for (int jt = 0; jt < 8; ++jt)
#pragma unroll
                for (int g = 0; g < 4; ++g)
                    O[jt][g] *= alpha[g];
#pragma unroll
            for (int j = 0; j < 2; ++j)
#pragma unroll
                for (int g = 0; g < 4; ++g)
                    Ps[wave][g4 + g][j * 16 + frow] = f2bf(sv[j][g]);
        }
        __syncthreads();
        if (active) {
            short8 pa = *(const short8*)&Ps[wave][frow][fk8];
#pragma unroll
            for (int jt = 0; jt < 8; ++jt) {
                short8 vb = *(const short8*)&Vs[jt * 16 + frow][fk8];
                O[jt] = __builtin_amdgcn_mfma_f32_16x16x32_bf16(pa, vb, O[jt], 0, 0, 0);
            }
        }
    }

    // epilogue: unnormalized partial (O bf16, m, l)
#pragma unroll
    for (int g = 0; g < 4; ++g) {
        const int row = wrow0g + g4 + g;
        float* rec = opart + (((size_t)z * 2048 + row) * 16 + h) * 66;
        unsigned short* ob = (unsigned short*)rec;
#pragma unroll
        for (int jt = 0; jt < 8; ++jt)
            ob[jt * 16 + frow] = f2bf(O[jt][g]);
        if ((lane & 15) == 0) { rec[64] = m_run[g]; rec[65] = l_run[g]; }
    }
}

// ---------------- attention split-KV merge -> yb (M=2048 rows) ----------------
__global__ __launch_bounds__(256) void attn_merge_k(
    const float* __restrict__ opart, unsigned short* __restrict__ y)
{
    const int r = blockIdx.x;
    for (int i = threadIdx.x; i < 2048; i += 256) {
        const int h = i >> 7, d = i & 127;
        const float* r0 = opart + (((size_t)r) * 16 + h) * 66;
        const float* r1 = opart + (((size_t)2048 + r) * 16 + h) * 66;
        const float m0 = r0[64], l0 = r0[65];
        const float m1 = r1[64], l1 = r1[65];
        const float mm = fmaxf(m0, m1);
        const float a0 = __expf(m0 - mm), a1 = __expf(m1 - mm);
        const float denom = l0 * a0 + l1 * a1;
        const float o0 = us2f(((const unsigned short*)r0)[d]);
        const float o1 = us2f(((const unsigned short*)r1)[d]);
        y[(size_t)r * 2048 + h * 128 + d] = f2bf((o0 * a0 + o1 * a1) / denom);
    }
}

extern "C" void kernel_launch(void* const* d_in, const int* in_sizes, int n_in,
                              void* d_out, int out_size, void* d_ws, size_t ws_size,
                              hipStream_t stream) {
    (void)in_sizes; (void)n_in; (void)out_size;
    const void* x       = d_in[0];
    const void* fcos    = d_in[2];
    const void* fsin    = d_in[3];
    const void* attn_nw = d_in[4];
    const void* wq_a    = d_in[5];
    const void* q_nw    = d_in[6];
    const void* wq_b    = d_in[7];
    const void* wkv_a   = d_in[8];
    const void* kv_nw   = d_in[9];
    const void* wkv_b   = d_in[10];
    const void* wo      = d_in[11];
    const void* ffn_nw  = d_in[12];
    const void* w1      = d_in[13];
    const void* w2      = d_in[14];
    const void* w3      = d_in[15];

    int* flag = (int*)d_ws;
    float* a  = (float*)d_ws + 64;
    const size_t M1 = 1048576;
    // Activation arena (floats), peak 23M = 92 MiB; see header comment for liveness.
    float* xf  = a;                                               // [0,4M)
    unsigned short* hh = (unsigned short*)(a + 4 * M1);           // [4M,6M)
    unsigned short* hl = (unsigned short*)(a + 6 * M1);           // [6M,8M)
    float* sp  = a + 8 * M1;                                      // partials [8M,14M)
    float* qa  = a + 14 * M1;                                     // [14M,17M)
    unsigned short* qah = (unsigned short*)(a + 8 * M1);          // [8M,9.5M)
    unsigned short* qal = (unsigned short*)(a + 9 * M1 + 524288); // [9.5M,11M)
    float* qb  = a + 17 * M1;                                     // [17M,23M)
    float* kva = a + 12 * M1 + 524288;                            // [12.5M,13.625M)
    unsigned short* kvnh = (unsigned short*)(a + 13 * M1 + 655360);
    unsigned short* kvnl = kvnh + 1048576;
    unsigned short* kh = (unsigned short*)(a + 4 * M1);           // [4M,7M)
    unsigned short* kl = (unsigned short*)(a + 7 * M1);           // [7M,10M)
    unsigned short* vt = (unsigned short*)(a + 10 * M1);          // [10M,12M)
    float* opart = a + 12 * M1 + 524288;                          // [12.5M,16.625M)
    unsigned short* yb = (unsigned short*)(a + 4 * M1);           // [4M,6M)
    float* fpo = a + 6 * M1;                                      // [6M,14M)
    unsigned short* hb  = (unsigned short*)(a + 4 * M1);          // [4M,6M)
    unsigned short* gb2 = (unsigned short*)(a + 6 * M1);          // [6M,14M)
    float* fp2 = a + 14 * M1;                                     // [14M,22M)
    float* x2  = xf;
    // Prepared weights [23M, 59.625M):
    unsigned short* wo_b  = (unsigned short*)(a + 23 * M1);       // 2M fl
    unsigned short* w1_b  = (unsigned short*)(a + 25 * M1);       // 8M fl
    unsigned short* w3_b  = (unsigned short*)(a + 33 * M1);       // 8M fl
    unsigned short* w2_b  = (unsigned short*)(a + 41 * M1);       // 8M fl
    unsigned short* wqa_h = (unsigned short*)(a + 49 * M1);
    unsigned short* wqa_l = wqa_h + 3145728u;
    unsigned short* wqb_h = (unsigned short*)(a + 52 * M1);
    unsigned short* wqb_l = wqb_h + 4718592u;
    unsigned short* wkva_h = (unsigned short*)(a + 56 * M1 + 524288);
    unsigned short* wkva_l = wkva_h + 1179648u;
    unsigned short* wkvb_h = (unsigned short*)(a + 57 * M1 + 655360);
    unsigned short* wkvb_l = wkvb_h + 2097152u;
    const size_t NEED = 256 + (size_t)(59 * M1 + 655360) * 4;     // ~238.5 MB
    const int prep = (ws_size >= NEED) ? 1 : 0;

    detect_k<<<1, 64, 0, stream>>>(x, flag);

    if (prep) {
        cvt_bf_k<<<1024, 256, 0, stream>>>(wo, wo_b, (size_t)2048 * 2048, flag);
        cvt_bf_k<<<2048, 256, 0, stream>>>(w1, w1_b, (size_t)8192 * 2048, flag);
        cvt_bf_k<<<2048, 256, 0, stream>>>(w3, w3_b, (size_t)8192 * 2048, flag);
        cvt_bf_k<<<2048, 256, 0, stream>>>(w2, w2_b, (size_t)2048 * 8192, flag);
        cvt_hl_k<<<1024, 256, 0, stream>>>(wq_a, wqa_h, wqa_l, (size_t)1536 * 2048, flag);
        cvt_hl_k<<<1024, 256, 0, stream>>>(wq_b, wqb_h, wqb_l, (size_t)3072 * 1536, flag);
        cvt_hl_k<<<512, 256, 0, stream>>>(wkv_a, wkva_h, wkva_l, (size_t)576 * 2048, flag);
        cvt_hl_k<<<1024, 256, 0, stream>>>(wkv_b, wkvb_h, wkvb_l, (size_t)4096 * 512, flag);
    }
    const void* Wqa = prep ? (const void*)wqa_h : wq_a;
    const void* Wqb = prep ? (const void*)wqb_h : wq_b;
    const void* Wkva = prep ? (const void*)wkva_h : wkv_a;
    const void* Wkvb = prep ? (const void*)wkvb_h : wkv_b;
    const unsigned short* WqaL = prep ? wqa_l : nullptr;
    const unsigned short* WqbL = prep ? wqb_l : nullptr;
    const unsigned short* WkvaL = prep ? wkva_l : nullptr;
    const unsigned short* WkvbL = prep ? wkvb_l : nullptr;
    const void* WoP = prep ? (const void*)wo_b : wo;
    const void* W1P = prep ? (const void*)w1_b : w1;
    const void* W3P = prep ? (const void*)w3_b : w3;
    const void* W2P = prep ? (const void*)w2_b : w2;

    // --- attention path (both batches fused, M=2048) ---
    rmsnorm_x_hl_k<<<2048, 256, 0, stream>>>(x, attn_nw, hh, hl, xf, flag);
    // qa = rms(h) @ wq_a^T   (N=1536, K=2048, z=2 -> 384 blocks)
    gemm_mfma3_k<<<dim3(12, 16, 2), 256, 0, stream>>>(hh, hl, Wqa, WqaL, sp, 1536, 2048, 1024, prep, flag, 0, nullptr, nullptr, nullptr);
    combine_k<2, 0><<<2048, 256, 0, stream>>>(sp, nullptr, qa, 786432);
    rmsnorm_hl_k<<<2048, 256, 0, stream>>>(qa, q_nw, qah, qal, 1536, 1536, flag);
    // qb = q @ wq_b^T   (N=3072, K=1536, 384 blocks, direct)
    gemm_mfma3_k<<<dim3(24, 16, 1), 256, 0, stream>>>(qah, qal, Wqb, WqbL, qb, 3072, 1536, 1536, prep, flag, 0, nullptr, nullptr, nullptr);
    // kva = h @ wkv_a^T   (N=576, K=2048, z=4 -> 320 blocks)
    gemm_mfma3_k<<<dim3(5, 16, 4), 256, 0, stream>>>(hh, hl, Wkva, WkvaL, sp, 576, 2048, 512, prep, flag, 0, nullptr, nullptr, nullptr);
    combine_k<4, 0><<<2048, 256, 0, stream>>>(sp, nullptr, kva, 294912);
    rmsnorm_hl_k<<<2048, 256, 0, stream>>>(kva, kv_nw, kvnh, kvnl, 512, 576, flag);
    rope_k<<<2048, 256, 0, stream>>>(qb, kva, kh, kl, fcos, fsin, flag);
    // kh/kl (k_nope hi/lo) + vt (V^T) directly from wkv_b epilogue (512 blocks)
    gemm_mfma3_k<<<dim3(32, 16, 1), 256, 0, stream>>>(kvnh, kvnl, Wkvb, WkvbL, nullptr, 4096, 512, 512, prep, flag, 1, kh, kl, vt);
    // flash attention: (qt 0..31, h, z) = 1024 blocks
    attn_mfma_k<<<dim3(32, 16, 2), 256, 0, stream>>>(qb, kh, kl, vt, opart);
    attn_merge_k<<<2048, 256, 0, stream>>>(opart, yb);

    // --- FFN ---
    // x2 = xf + yb @ wo^T   (N=2048, K=2048, z=2 -> 512 blocks)
    gemm_mfma_k<0><<<dim3(16, 16, 2), 256, 0, stream>>>(yb, WoP, nullptr, fpo, 2048, 2048, 1024, prep, flag);
    combine_k<2, 1><<<2048, 256, 0, stream>>>(fpo, xf, x2, 1048576);
    rmsnorm_bf_k<<<2048, 256, 0, stream>>>(x2, ffn_nw, hb, 2048, flag);
    // gb2 = bf16(silu(hb@w1^T) * (hb@w3^T))   (N=8192, K=2048, 1024 blocks)
    gemm_swiglu_k<<<dim3(64, 16), 256, 0, stream>>>(hb, W1P, W3P, gb2, 8192, 2048, prep, flag);
    // out = x2 + gb2 @ w2^T   (N=2048, K=8192, z=2 -> 512 blocks)
    gemm_mfma_k<0><<<dim3(16, 16, 2), 256, 0, stream>>>(gb2, W2P, nullptr, fp2, 2048, 8192, 4096, prep, flag);
    combine_k<2, 1><<<2048, 256, 0, stream>>>(fp2, x2, (float*)d_out, 1048576);
}